// Round 1
// baseline (568.824 us; speedup 1.0000x reference)
//
#include <hip/hip_runtime.h>
#include <math.h>

#define B_     2
#define L_     512
#define DM     768
#define DS     128
#define HD     64
#define DI     1536
#define NH     24
#define CONVD  1792
#define DPROJ  3352
#define ML     (B_*L_)

__device__ __forceinline__ float sigmoidf_(float x){ return 1.f/(1.f+__expf(-x)); }

// ---------------- GEMM: C[m][n] = sum_k A[m][k] * Bw[n][k] ----------------
// A: MxK row-major, Bw: NxK row-major (i.e. B^T layout), C: MxN row-major.
template<int BM,int BN,int BK>
__launch_bounds__(256)
__global__ void gemm_nt(const float* __restrict__ A, const float* __restrict__ Bw,
                        float* __restrict__ C, int M, int N, int K) {
  __shared__ float As[BK][BM+4];
  __shared__ float Bs[BK][BN+4];
  const int tid = threadIdx.x;
  const int bm = blockIdx.y*BM, bn = blockIdx.x*BN;
  const int ty = tid>>4, tx = tid&15;   // 16x16 thread grid, 4x4 microtile
  const int lr = tid>>2;                // loader row 0..63
  const int lk = (tid&3)*4;             // loader k-offset 0,4,8,12
  float acc[4][4] = {};

  for (int k0=0; k0<K; k0+=BK) {
    float4 a4 = make_float4(0,0,0,0), b4 = make_float4(0,0,0,0);
    int am = bm+lr;
    if (am < M) a4 = *(const float4*)&A[(size_t)am*K + k0+lk];
    int bnr = bn+lr;
    if (bnr < N) b4 = *(const float4*)&Bw[(size_t)bnr*K + k0+lk];
    __syncthreads();
    As[lk+0][lr]=a4.x; As[lk+1][lr]=a4.y; As[lk+2][lr]=a4.z; As[lk+3][lr]=a4.w;
    Bs[lk+0][lr]=b4.x; Bs[lk+1][lr]=b4.y; Bs[lk+2][lr]=b4.z; Bs[lk+3][lr]=b4.w;
    __syncthreads();
#pragma unroll
    for (int k=0;k<BK;k++){
      float4 av = *(const float4*)&As[k][ty*4];
      float4 bv = *(const float4*)&Bs[k][tx*4];
      float a[4]={av.x,av.y,av.z,av.w};
      float b[4]={bv.x,bv.y,bv.z,bv.w};
#pragma unroll
      for(int i=0;i<4;i++)
#pragma unroll
        for(int j=0;j<4;j++) acc[i][j] = fmaf(a[i], b[j], acc[i][j]);
    }
  }
#pragma unroll
  for(int i=0;i<4;i++){
    int m = bm + ty*4 + i;
    if (m>=M) continue;
#pragma unroll
    for(int j=0;j<4;j++){
      int n = bn + tx*4 + j;
      if (n<N) C[(size_t)m*N+n] = acc[i][j];
    }
  }
}

// ---------------- causal depthwise conv (width 4) + SiLU ----------------
__launch_bounds__(256)
__global__ void conv_kernel(const float* __restrict__ zx,
                            const float* __restrict__ conv_w,
                            const float* __restrict__ conv_b,
                            float* __restrict__ xbc) {
  int idx = blockIdx.x*blockDim.x + threadIdx.x;  // over ML*CONVD
  if (idx >= ML*CONVD) return;
  int c = idx % CONVD;
  int m = idx / CONVD;     // b*L + t
  int t = m % L_;
  float w0=conv_w[c*4+0], w1=conv_w[c*4+1], w2=conv_w[c*4+2], w3=conv_w[c*4+3];
  const float* src = zx + DI + c;
  float acc = conv_b[c];
  acc = fmaf(w3, src[(size_t)m*DPROJ], acc);
  if (t>=1) acc = fmaf(w2, src[(size_t)(m-1)*DPROJ], acc);
  if (t>=2) acc = fmaf(w1, src[(size_t)(m-2)*DPROJ], acc);
  if (t>=3) acc = fmaf(w0, src[(size_t)(m-3)*DPROJ], acc);
  xbc[idx] = acc * sigmoidf_(acc);
}

// ---------------- dt = softplus(raw + bias); dA = exp(dt*A) ----------------
__launch_bounds__(256)
__global__ void dt_kernel(const float* __restrict__ zx,
                          const float* __restrict__ dt_bias,
                          const float* __restrict__ A_log,
                          float* __restrict__ dts, float* __restrict__ dAs){
  int idx = blockIdx.x*blockDim.x + threadIdx.x; // (b*NH+h)*L + t
  if (idx >= B_*NH*L_) return;
  int t = idx % L_; int h = (idx/L_) % NH; int b = idx/(L_*NH);
  float raw = zx[(size_t)(b*L_+t)*DPROJ + DI + CONVD + h] + dt_bias[h];
  float dtv = raw > 20.f ? raw : log1pf(expf(raw));
  float A = -expf(A_log[h]);
  dts[idx] = dtv;
  dAs[idx] = expf(dtv*A);
}

// ---------------- sequential SSM scan ----------------
// grid: B*NH*(HD/4) blocks of 64 threads. Each block: one (b,h) and 4 p's.
// lane = pi*16 + ng ; pi in 0..3 -> p = pq*4+pi ; ng in 0..15 -> n0 = ng*8.
__launch_bounds__(64)
__global__ void scan_kernel(const float* __restrict__ zx,
                            const float* __restrict__ xbc,
                            const float* __restrict__ dts,
                            const float* __restrict__ dAs,
                            const float* __restrict__ Dp,
                            float* __restrict__ y) {
  int blk = blockIdx.x;
  int pq = blk & 15; int h = (blk>>4) % NH; int b = blk/(16*NH);
  int lane = threadIdx.x;
  int pi = lane>>4, ng = lane&15;
  int p = pq*4 + pi;
  int n0 = ng*8;
  const float Dh = Dp[h];
  float s[8];
#pragma unroll
  for(int j=0;j<8;j++) s[j]=0.f;

  const float* xbase = xbc + h*HD + p;
  const float* Bbase = xbc + DI + n0;
  const float* Cbase = xbc + DI + DS + n0;
  const float* dtb = dts + (b*NH+h)*L_;
  const float* dAb = dAs + (b*NH+h)*L_;
  const float* zbase = zx + h*HD + p;
  float* ybase = y + h*HD + p;

  size_t row = (size_t)(b*L_)*CONVD;
  float4 Bv0 = *(const float4*)&Bbase[row];
  float4 Bv1 = *(const float4*)&Bbase[row+4];
  float4 Cv0 = *(const float4*)&Cbase[row];
  float4 Cv1 = *(const float4*)&Cbase[row+4];
  float xv = xbase[row];
  float dtv = dtb[0], dAv = dAb[0];

  for (int t=0;t<L_;t++){
    float4 nB0=make_float4(0,0,0,0), nB1=nB0, nC0=nB0, nC1=nB0;
    float nx=0.f, ndt=0.f, ndA=0.f;
    if (t+1 < L_) {
      size_t nrow = (size_t)(b*L_ + t+1)*CONVD;
      nB0 = *(const float4*)&Bbase[nrow];
      nB1 = *(const float4*)&Bbase[nrow+4];
      nC0 = *(const float4*)&Cbase[nrow];
      nC1 = *(const float4*)&Cbase[nrow+4];
      nx  = xbase[nrow];
      ndt = dtb[t+1]; ndA = dAb[t+1];
    }
    float dtx = dtv * xv;
    float Bv[8] = {Bv0.x,Bv0.y,Bv0.z,Bv0.w,Bv1.x,Bv1.y,Bv1.z,Bv1.w};
    float Cv[8] = {Cv0.x,Cv0.y,Cv0.z,Cv0.w,Cv1.x,Cv1.y,Cv1.z,Cv1.w};
    float acc = 0.f;
#pragma unroll
    for (int j=0;j<8;j++){
      s[j] = fmaf(s[j], dAv, dtx*Bv[j]);
      acc  = fmaf(s[j], Cv[j], acc);
    }
    acc += __shfl_xor(acc, 1);
    acc += __shfl_xor(acc, 2);
    acc += __shfl_xor(acc, 4);
    acc += __shfl_xor(acc, 8);
    if (ng==0) {
      size_t prow = (size_t)(b*L_+t);
      float z  = zbase[prow*DPROJ];
      float yv = fmaf(Dh, xv, acc);
      ybase[prow*DI] = yv * (z * sigmoidf_(z));
    }
    Bv0=nB0;Bv1=nB1;Cv0=nC0;Cv1=nC1; xv=nx; dtv=ndt; dAv=ndA;
  }
}

extern "C" void kernel_launch(void* const* d_in, const int* in_sizes, int n_in,
                              void* d_out, int out_size, void* d_ws, size_t ws_size,
                              hipStream_t stream) {
  const float* u       = (const float*)d_in[0];
  const float* W_in    = (const float*)d_in[1];
  const float* conv_w  = (const float*)d_in[2];
  const float* conv_b  = (const float*)d_in[3];
  const float* dt_bias = (const float*)d_in[4];
  const float* A_log   = (const float*)d_in[5];
  const float* D_param = (const float*)d_in[6];
  const float* W_out   = (const float*)d_in[7];
  float* out = (float*)d_out;

  float* ws = (float*)d_ws;
  float* zx   = ws;                                   // ML*DPROJ
  float* xbc  = zx  + (size_t)ML*DPROJ;               // ML*CONVD
  float* dts  = xbc + (size_t)ML*CONVD;               // B*NH*L
  float* dAs  = dts + (size_t)B_*NH*L_;               // B*NH*L
  float* yy   = dAs + (size_t)B_*NH*L_;               // ML*DI

  // 1) in-projection GEMM: zx[m][j] = u[m][:] . W_in[j][:]
  {
    dim3 grid((DPROJ+63)/64, ML/64);
    gemm_nt<64,64,16><<<grid, 256, 0, stream>>>(u, W_in, zx, ML, DPROJ, DM);
  }
  // 2) conv + SiLU
  {
    int n = ML*CONVD;
    conv_kernel<<<(n+255)/256, 256, 0, stream>>>(zx, conv_w, conv_b, xbc);
  }
  // 3) dt/dA
  {
    int n = B_*NH*L_;
    dt_kernel<<<(n+255)/256, 256, 0, stream>>>(zx, dt_bias, A_log, dts, dAs);
  }
  // 4) scan (fuses +D*x and *silu(z))
  {
    scan_kernel<<<B_*NH*(HD/4), 64, 0, stream>>>(zx, xbc, dts, dAs, D_param, yy);
  }
  // 5) out-projection GEMM: out[m][d] = yy[m][:] . W_out[d][:]
  {
    dim3 grid((DM+63)/64, ML/64);
    gemm_nt<64,64,16><<<grid, 256, 0, stream>>>(yy, W_out, out, ML, DM, DI);
  }
}

// Round 2
// 300.814 us; speedup vs baseline: 1.8909x; 1.8909x over previous
//
#include <hip/hip_runtime.h>
#include <math.h>

#define B_     2
#define L_     512
#define DM     768
#define DS     128
#define HD     64
#define DI     1536
#define NH     24
#define CONVD  1792
#define DPROJ  3352
#define ML     (B_*L_)
#define Q      64
#define NC     (L_/Q)

__device__ __forceinline__ float sigmoidf_(float x){ return 1.f/(1.f+__expf(-x)); }

// ---------------- GEMM: C[m][n] = sum_k A[m][k] * Bw[n][k] ----------------
template<int BM,int BN,int BK>
__launch_bounds__(256)
__global__ void gemm_nt(const float* __restrict__ A, const float* __restrict__ Bw,
                        float* __restrict__ C, int M, int N, int K) {
  __shared__ float As[BK][BM+4];
  __shared__ float Bs[BK][BN+4];
  const int tid = threadIdx.x;
  const int bm = blockIdx.y*BM, bn = blockIdx.x*BN;
  const int ty = tid>>4, tx = tid&15;
  const int lr = tid>>2;
  const int lk = (tid&3)*4;
  float acc[4][4] = {};

  for (int k0=0; k0<K; k0+=BK) {
    float4 a4 = make_float4(0,0,0,0), b4 = make_float4(0,0,0,0);
    int am = bm+lr;
    if (am < M) a4 = *(const float4*)&A[(size_t)am*K + k0+lk];
    int bnr = bn+lr;
    if (bnr < N) b4 = *(const float4*)&Bw[(size_t)bnr*K + k0+lk];
    __syncthreads();
    As[lk+0][lr]=a4.x; As[lk+1][lr]=a4.y; As[lk+2][lr]=a4.z; As[lk+3][lr]=a4.w;
    Bs[lk+0][lr]=b4.x; Bs[lk+1][lr]=b4.y; Bs[lk+2][lr]=b4.z; Bs[lk+3][lr]=b4.w;
    __syncthreads();
#pragma unroll
    for (int k=0;k<BK;k++){
      float4 av = *(const float4*)&As[k][ty*4];
      float4 bv = *(const float4*)&Bs[k][tx*4];
      float a[4]={av.x,av.y,av.z,av.w};
      float b[4]={bv.x,bv.y,bv.z,bv.w};
#pragma unroll
      for(int i=0;i<4;i++)
#pragma unroll
        for(int j=0;j<4;j++) acc[i][j] = fmaf(a[i], b[j], acc[i][j]);
    }
  }
#pragma unroll
  for(int i=0;i<4;i++){
    int m = bm + ty*4 + i;
    if (m>=M) continue;
#pragma unroll
    for(int j=0;j<4;j++){
      int n = bn + tx*4 + j;
      if (n<N) C[(size_t)m*N+n] = acc[i][j];
    }
  }
}

// ---------------- causal depthwise conv (width 4) + SiLU ----------------
__launch_bounds__(256)
__global__ void conv_kernel(const float* __restrict__ zx,
                            const float* __restrict__ conv_w,
                            const float* __restrict__ conv_b,
                            float* __restrict__ xbc) {
  int idx = blockIdx.x*blockDim.x + threadIdx.x;
  if (idx >= ML*CONVD) return;
  int c = idx % CONVD;
  int m = idx / CONVD;
  int t = m % L_;
  float w0=conv_w[c*4+0], w1=conv_w[c*4+1], w2=conv_w[c*4+2], w3=conv_w[c*4+3];
  const float* src = zx + DI + c;
  float acc = conv_b[c];
  acc = fmaf(w3, src[(size_t)m*DPROJ], acc);
  if (t>=1) acc = fmaf(w2, src[(size_t)(m-1)*DPROJ], acc);
  if (t>=2) acc = fmaf(w1, src[(size_t)(m-2)*DPROJ], acc);
  if (t>=3) acc = fmaf(w0, src[(size_t)(m-3)*DPROJ], acc);
  xbc[idx] = acc * sigmoidf_(acc);
}

// -------- dt = softplus(raw+bias); la = chunk-local cumsum(dt*A) --------
__launch_bounds__(64)
__global__ void dt_kernel(const float* __restrict__ zx,
                          const float* __restrict__ dt_bias,
                          const float* __restrict__ A_log,
                          float* __restrict__ dts, float* __restrict__ las){
  int blk = blockIdx.x;             // b*NH*NC + h*NC + c
  int c = blk % NC; int h = (blk/NC)%NH; int b = blk/(NC*NH);
  int lane = threadIdx.x;
  int t = c*Q + lane;
  float raw = zx[(size_t)(b*L_+t)*DPROJ + DI + CONVD + h] + dt_bias[h];
  float dtv = raw > 20.f ? raw : log1pf(__expf(raw));
  float A = -__expf(A_log[h]);
  float la = dtv * A;
#pragma unroll
  for (int off=1; off<64; off<<=1){
    float v = __shfl_up(la, off);
    if (lane >= off) la += v;
  }
  int idx = (b*NH+h)*L_ + t;
  dts[idx] = dtv;
  las[idx] = la;
}

// -------- K1: per-chunk state  S_chunk[p][n] = sum_s w[s] x[s][p] B[s][n] --------
__launch_bounds__(256)
__global__ void chunk_state_kernel(const float* __restrict__ xbc,
                                   const float* __restrict__ dts,
                                   const float* __restrict__ las,
                                   float* __restrict__ Schunk){
  __shared__ float Xw[Q][68];    // w[s] * x[s][p]
  __shared__ float Bs[Q][132];
  int c = blockIdx.x, h = blockIdx.y, b = blockIdx.z;
  int tid = threadIdx.x;
  int bh = b*NH + h;
  const int tbase = bh*L_ + c*Q;
  float la63 = las[tbase + 63];

  for (int it = tid; it < Q*16; it += 256){     // X: 64 rows x 16 float4
    int s = it >> 4, p4 = (it & 15) << 2;
    float4 v = *(const float4*)&xbc[(size_t)(b*L_ + c*Q + s)*CONVD + h*HD + p4];
    float w = __expf(la63 - las[tbase + s]) * dts[tbase + s];
    Xw[s][p4+0]=v.x*w; Xw[s][p4+1]=v.y*w; Xw[s][p4+2]=v.z*w; Xw[s][p4+3]=v.w*w;
  }
  for (int it = tid; it < Q*32; it += 256){     // B: 64 rows x 32 float4
    int s = it >> 5, n4 = (it & 31) << 2;
    float4 v = *(const float4*)&xbc[(size_t)(b*L_ + c*Q + s)*CONVD + DI + n4];
    Bs[s][n4+0]=v.x; Bs[s][n4+1]=v.y; Bs[s][n4+2]=v.z; Bs[s][n4+3]=v.w;
  }
  __syncthreads();

  int ty = tid >> 4, tx = tid & 15;
  int p0 = ty*4;
  float acc[4][8] = {};
#pragma unroll 4
  for (int k=0;k<Q;k++){
    float4 a4 = *(const float4*)&Xw[k][p0];
    float4 b0 = *(const float4*)&Bs[k][tx*4];
    float4 b1 = *(const float4*)&Bs[k][64 + tx*4];
    float a[4]={a4.x,a4.y,a4.z,a4.w};
    float bb[8]={b0.x,b0.y,b0.z,b0.w,b1.x,b1.y,b1.z,b1.w};
#pragma unroll
    for(int i=0;i<4;i++)
#pragma unroll
      for(int j=0;j<8;j++) acc[i][j] = fmaf(a[i], bb[j], acc[i][j]);
  }
  float* Sb = Schunk + ((size_t)bh*NC + c)*(HD*DS);
#pragma unroll
  for(int i=0;i<4;i++){
    int p = p0+i;
    *(float4*)&Sb[p*DS + tx*4]      = make_float4(acc[i][0],acc[i][1],acc[i][2],acc[i][3]);
    *(float4*)&Sb[p*DS + 64 + tx*4] = make_float4(acc[i][4],acc[i][5],acc[i][6],acc[i][7]);
  }
}

// -------- K2: inter-chunk scan (in-place: Schunk -> S_start) --------
__launch_bounds__(256)
__global__ void interchunk_kernel(float* __restrict__ S, const float* __restrict__ las){
  int blk = blockIdx.x;           // bh*8 + slice
  int slice = blk & 7; int bh = blk >> 3;
  size_t base = (size_t)bh*NC*(HD*DS) + slice*1024 + threadIdx.x*4;
  float4 run = make_float4(0,0,0,0);
#pragma unroll
  for (int c=0;c<NC;c++){
    float dec = __expf(las[bh*L_ + c*Q + 63]);
    float4 ch = *(float4*)(S + base + c*(HD*DS));
    *(float4*)(S + base + c*(HD*DS)) = run;
    run.x = fmaf(run.x, dec, ch.x);
    run.y = fmaf(run.y, dec, ch.y);
    run.z = fmaf(run.z, dec, ch.z);
    run.w = fmaf(run.w, dec, ch.w);
  }
}

// -------- K3: per-chunk outputs --------
// y[t][p] = exp(la[t])*(C[t]·Sstart[p,:]) + sum_{s<=t} exp(la[t]-la[s])dt[s](C[t]·B[s]) x[s][p]
//           + D*x[t][p];  out = y * silu(z)
__launch_bounds__(256)
__global__ void chunk_out_kernel(const float* __restrict__ zx,
                                 const float* __restrict__ xbc,
                                 const float* __restrict__ dts,
                                 const float* __restrict__ las,
                                 const float* __restrict__ Sstart,
                                 const float* __restrict__ Dp,
                                 float* __restrict__ yy){
  __shared__ float R1[8192];   // Ct[128][64]  -> later G[64][65]
  __shared__ float R2[8192];   // Spt[128][64] -> Bt[128][64] -> X[64][64]
  int c = blockIdx.x, h = blockIdx.y, b = blockIdx.z;
  int tid = threadIdx.x;
  int bh = b*NH + h;
  const int tbase = bh*L_ + c*Q;
  const float Dh = Dp[h];
  int ty = tid >> 4, tx = tid & 15;
  int t0 = ty*4, p0 = tx*4;

  // stage Ct[n][t] (transposed)
  for (int it = tid; it < 64*32; it += 256){    // 2048 float4 = 128n x 64t
    int t = it & 63, n4 = (it >> 6) << 2;
    float4 v = *(const float4*)&xbc[(size_t)(b*L_ + c*Q + t)*CONVD + DI + DS + n4];
    R1[(n4+0)*64 + t]=v.x; R1[(n4+1)*64 + t]=v.y; R1[(n4+2)*64 + t]=v.z; R1[(n4+3)*64 + t]=v.w;
  }
  // stage Spt[n][p] (transposed)
  const float* Sb = Sstart + ((size_t)bh*NC + c)*(HD*DS);
  for (int it = tid; it < 64*32; it += 256){
    int p = it & 63, n4 = (it >> 6) << 2;
    float4 v = *(const float4*)&Sb[p*DS + n4];
    R2[(n4+0)*64 + p]=v.x; R2[(n4+1)*64 + p]=v.y; R2[(n4+2)*64 + p]=v.z; R2[(n4+3)*64 + p]=v.w;
  }
  __syncthreads();

  // Yinter_raw[t][p] = sum_n C[t][n] * Sstart[p][n]
  float Yi[4][4] = {};
#pragma unroll 4
  for (int k=0;k<DS;k++){
    float4 a4 = *(const float4*)&R1[k*64 + t0];
    float4 b4 = *(const float4*)&R2[k*64 + p0];
    float a[4]={a4.x,a4.y,a4.z,a4.w}, bb[4]={b4.x,b4.y,b4.z,b4.w};
#pragma unroll
    for(int i=0;i<4;i++)
#pragma unroll
      for(int j=0;j<4;j++) Yi[i][j] = fmaf(a[i], bb[j], Yi[i][j]);
  }
  __syncthreads();

  // restage R2 <- Bt[n][s]
  for (int it = tid; it < 64*32; it += 256){
    int s = it & 63, n4 = (it >> 6) << 2;
    float4 v = *(const float4*)&xbc[(size_t)(b*L_ + c*Q + s)*CONVD + DI + n4];
    R2[(n4+0)*64 + s]=v.x; R2[(n4+1)*64 + s]=v.y; R2[(n4+2)*64 + s]=v.z; R2[(n4+3)*64 + s]=v.w;
  }
  __syncthreads();

  // E[t][s] = C[t]·B[s]
  float E[4][4] = {};
#pragma unroll 4
  for (int k=0;k<DS;k++){
    float4 a4 = *(const float4*)&R1[k*64 + t0];
    float4 b4 = *(const float4*)&R2[k*64 + p0];   // p0 doubles as s0
    float a[4]={a4.x,a4.y,a4.z,a4.w}, bb[4]={b4.x,b4.y,b4.z,b4.w};
#pragma unroll
    for(int i=0;i<4;i++)
#pragma unroll
      for(int j=0;j<4;j++) E[i][j] = fmaf(a[i], bb[j], E[i][j]);
  }
  __syncthreads();   // Ct dead, Bt dead after this point for all threads

  // G[t][s] = (s<=t) ? exp(la[t]-la[s])*dt[s]*E : 0   -> R1 as [64][65]
  {
    float lat[4], lass[4], dtv[4];
#pragma unroll
    for(int i=0;i<4;i++) lat[i]  = las[tbase + t0 + i];
#pragma unroll
    for(int j=0;j<4;j++){ lass[j] = las[tbase + p0 + j]; dtv[j] = dts[tbase + p0 + j]; }
#pragma unroll
    for(int i=0;i<4;i++)
#pragma unroll
      for(int j=0;j<4;j++){
        int t = t0+i, s = p0+j;
        float g = 0.f;
        if (s <= t) g = __expf(lat[i] - lass[j]) * dtv[j] * E[i][j];
        R1[t*65 + s] = g;
      }
  }
  // stage X[s][p] row-major into R2
  for (int it = tid; it < 64*16; it += 256){
    int s = it >> 4, p4 = (it & 15) << 2;
    float4 v = *(const float4*)&xbc[(size_t)(b*L_ + c*Q + s)*CONVD + h*HD + p4];
    *(float4*)&R2[s*64 + p4] = v;
  }
  __syncthreads();

  // Yintra[t][p] = sum_s G[t][s] X[s][p]
  float Yv[4][4] = {};
#pragma unroll 4
  for (int k=0;k<Q;k++){
    float g[4];
#pragma unroll
    for(int i=0;i<4;i++) g[i] = R1[(t0+i)*65 + k];
    float4 x4 = *(const float4*)&R2[k*64 + p0];
    float xx[4]={x4.x,x4.y,x4.z,x4.w};
#pragma unroll
    for(int i=0;i<4;i++)
#pragma unroll
      for(int j=0;j<4;j++) Yv[i][j] = fmaf(g[i], xx[j], Yv[i][j]);
  }

  // epilogue
#pragma unroll
  for(int i=0;i<4;i++){
    int t = t0 + i;
    float cp = __expf(las[tbase + t]);
    size_t row = (size_t)(b*L_ + c*Q + t);
    float4 z4 = *(const float4*)&zx[row*DPROJ + h*HD + p0];
    float zz[4]={z4.x,z4.y,z4.z,z4.w};
    float o[4];
#pragma unroll
    for(int j=0;j<4;j++){
      float xv = R2[t*64 + p0 + j];
      float y = fmaf(cp, Yi[i][j], Yv[i][j]) + Dh*xv;
      o[j] = y * (zz[j] * sigmoidf_(zz[j]));
    }
    *(float4*)&yy[row*DI + h*HD + p0] = make_float4(o[0],o[1],o[2],o[3]);
  }
}

extern "C" void kernel_launch(void* const* d_in, const int* in_sizes, int n_in,
                              void* d_out, int out_size, void* d_ws, size_t ws_size,
                              hipStream_t stream) {
  const float* u       = (const float*)d_in[0];
  const float* W_in    = (const float*)d_in[1];
  const float* conv_w  = (const float*)d_in[2];
  const float* conv_b  = (const float*)d_in[3];
  const float* dt_bias = (const float*)d_in[4];
  const float* A_log   = (const float*)d_in[5];
  const float* D_param = (const float*)d_in[6];
  const float* W_out   = (const float*)d_in[7];
  float* out = (float*)d_out;

  float* ws = (float*)d_ws;
  float* zx     = ws;                                   // ML*DPROJ
  float* xbc    = zx   + (size_t)ML*DPROJ;              // ML*CONVD
  float* dts    = xbc  + (size_t)ML*CONVD;              // B*NH*L
  float* las    = dts  + (size_t)B_*NH*L_;              // B*NH*L
  float* yy     = las  + (size_t)B_*NH*L_;              // ML*DI
  float* Schunk = yy   + (size_t)ML*DI;                 // B*NH*NC*HD*DS (in-place -> Sstart)

  // 1) in-projection GEMM
  {
    dim3 grid((DPROJ+63)/64, ML/64);
    gemm_nt<64,64,16><<<grid, 256, 0, stream>>>(u, W_in, zx, ML, DPROJ, DM);
  }
  // 2) conv + SiLU
  {
    int n = ML*CONVD;
    conv_kernel<<<(n+255)/256, 256, 0, stream>>>(zx, conv_w, conv_b, xbc);
  }
  // 3) dt + chunk-local cumsum(dt*A)
  dt_kernel<<<B_*NH*NC, 64, 0, stream>>>(zx, dt_bias, A_log, dts, las);
  // 4) chunk states
  {
    dim3 grid(NC, NH, B_);
    chunk_state_kernel<<<grid, 256, 0, stream>>>(xbc, dts, las, Schunk);
  }
  // 5) inter-chunk scan (in-place)
  interchunk_kernel<<<B_*NH*8, 256, 0, stream>>>(Schunk, las);
  // 6) chunk outputs (fuses Yinter+Yintra+D*x and *silu(z))
  {
    dim3 grid(NC, NH, B_);
    chunk_out_kernel<<<grid, 256, 0, stream>>>(zx, xbc, dts, las, Schunk, D_param, yy);
  }
  // 7) out-projection GEMM
  {
    dim3 grid((DM+63)/64, ML/64);
    gemm_nt<64,64,16><<<grid, 256, 0, stream>>>(yy, W_out, out, ML, DM, DI);
  }
}

// Round 3
// 254.988 us; speedup vs baseline: 2.2308x; 1.1797x over previous
//
#include <hip/hip_runtime.h>
#include <math.h>

#define B_     2
#define L_     512
#define DM     768
#define DS     128
#define HD     64
#define DI     1536
#define NH     24
#define CONVD  1792
#define DPROJ  3352
#define ML     (B_*L_)
#define Q      64
#define NC     (L_/Q)

typedef __bf16 bf16x8 __attribute__((ext_vector_type(8)));
typedef float f32x4 __attribute__((ext_vector_type(4)));

__device__ __forceinline__ float sigmoidf_(float x){ return 1.f/(1.f+__expf(-x)); }

__device__ __forceinline__ ushort bf16rn(float x){
  uint u = __float_as_uint(x);
  u += 0x7fff + ((u>>16)&1);
  return (ushort)(u>>16);
}

// ---------- MFMA GEMM, split-bf16 (hi/lo): C[m][n] = sum_k A[m][k]*Bw[n][k] ----------
// A: MxK row-major fp32; Bw: NxK row-major fp32. K % 32 == 0, M % BM == 0.
template<int BM, int BN>
__launch_bounds__(256, 2)
__global__ void gemm_mfma_nt(const float* __restrict__ A, const float* __restrict__ Bw,
                             float* __restrict__ C, int M, int N, int K) {
  constexpr int WM = BM/2, WN = BN/2, FM = WM/16, FN = WN/16;
  constexpr int STR = 40;  // ushorts per row: 32 data + 8 pad (80B, 20-bank stride)
  __shared__ ushort Ah[BM*STR], Al[BM*STR], Bh[BN*STR], Bl[BN*STR];
  const int tid = threadIdx.x;
  const int bm = blockIdx.y*BM, bn = blockIdx.x*BN;
  const int lane = tid & 63, w = tid >> 6;
  const int wr = w >> 1, wc = w & 1;
  const int lrow = lane & 15, lk = (lane >> 4) * 8;

  f32x4 acc[FM][FN] = {};

  for (int k0 = 0; k0 < K; k0 += 32) {
    // ---- stage: fp32 -> (hi,lo) bf16 into LDS ----
    for (int it = tid; it < (BM+BN)*2; it += 256) {
      bool isA = it < BM*2;
      int li = isA ? it : it - BM*2;
      int r = li >> 1, hh = li & 1;          // half-row: 16 floats
      const float* src;
      bool valid;
      ushort *dsth, *dstl;
      if (isA) {
        src = &A[(size_t)(bm + r)*K + k0 + hh*16];
        valid = true;
        dsth = &Ah[r*STR + hh*16]; dstl = &Al[r*STR + hh*16];
      } else {
        int n = bn + r;
        valid = (n < N);
        src = &Bw[(size_t)(valid ? n : 0)*K + k0 + hh*16];
        dsth = &Bh[r*STR + hh*16]; dstl = &Bl[r*STR + hh*16];
      }
      float xv[16];
#pragma unroll
      for (int q = 0; q < 4; q++) {
        float4 v = valid ? *(const float4*)(src + q*4) : make_float4(0,0,0,0);
        xv[q*4+0]=v.x; xv[q*4+1]=v.y; xv[q*4+2]=v.z; xv[q*4+3]=v.w;
      }
      uint ph[8], pl[8];
#pragma unroll
      for (int q = 0; q < 8; q++) {
        float a0 = xv[2*q], a1 = xv[2*q+1];
        ushort h0 = bf16rn(a0), h1 = bf16rn(a1);
        float f0 = __uint_as_float(((uint)h0)<<16);
        float f1 = __uint_as_float(((uint)h1)<<16);
        ushort l0 = bf16rn(a0 - f0), l1 = bf16rn(a1 - f1);
        ph[q] = (uint)h0 | ((uint)h1<<16);
        pl[q] = (uint)l0 | ((uint)l1<<16);
      }
      *(uint4*)dsth       = make_uint4(ph[0],ph[1],ph[2],ph[3]);
      *((uint4*)dsth + 1) = make_uint4(ph[4],ph[5],ph[6],ph[7]);
      *(uint4*)dstl       = make_uint4(pl[0],pl[1],pl[2],pl[3]);
      *((uint4*)dstl + 1) = make_uint4(pl[4],pl[5],pl[6],pl[7]);
    }
    __syncthreads();

    // ---- fragments + MFMA ----
    bf16x8 ah[FM], al[FM], bh[FN], bl[FN];
#pragma unroll
    for (int i = 0; i < FM; i++) {
      int ro = (wr*WM + i*16 + lrow)*STR + lk;
      ah[i] = *(const bf16x8*)&Ah[ro];
      al[i] = *(const bf16x8*)&Al[ro];
    }
#pragma unroll
    for (int j = 0; j < FN; j++) {
      int ro = (wc*WN + j*16 + lrow)*STR + lk;
      bh[j] = *(const bf16x8*)&Bh[ro];
      bl[j] = *(const bf16x8*)&Bl[ro];
    }
#pragma unroll
    for (int i = 0; i < FM; i++)
#pragma unroll
      for (int j = 0; j < FN; j++) {
        acc[i][j] = __builtin_amdgcn_mfma_f32_16x16x32_bf16(ah[i], bh[j], acc[i][j], 0,0,0);
        acc[i][j] = __builtin_amdgcn_mfma_f32_16x16x32_bf16(ah[i], bl[j], acc[i][j], 0,0,0);
        acc[i][j] = __builtin_amdgcn_mfma_f32_16x16x32_bf16(al[i], bh[j], acc[i][j], 0,0,0);
      }
    __syncthreads();
  }

  // ---- epilogue: C[row=(lane>>4)*4+e][col=lane&15] per fragment ----
#pragma unroll
  for (int i = 0; i < FM; i++)
#pragma unroll
    for (int j = 0; j < FN; j++) {
      int n = bn + wc*WN + j*16 + lrow;
      if (n < N) {
#pragma unroll
        for (int e = 0; e < 4; e++) {
          int m = bm + wr*WM + i*16 + (lane>>4)*4 + e;
          C[(size_t)m*N + n] = acc[i][j][e];
        }
      }
    }
}

// ---------------- causal depthwise conv (width 4) + SiLU ----------------
__launch_bounds__(256)
__global__ void conv_kernel(const float* __restrict__ zx,
                            const float* __restrict__ conv_w,
                            const float* __restrict__ conv_b,
                            float* __restrict__ xbc) {
  int idx = blockIdx.x*blockDim.x + threadIdx.x;
  if (idx >= ML*CONVD) return;
  int c = idx % CONVD;
  int m = idx / CONVD;
  int t = m % L_;
  float w0=conv_w[c*4+0], w1=conv_w[c*4+1], w2=conv_w[c*4+2], w3=conv_w[c*4+3];
  const float* src = zx + DI + c;
  float acc = conv_b[c];
  acc = fmaf(w3, src[(size_t)m*DPROJ], acc);
  if (t>=1) acc = fmaf(w2, src[(size_t)(m-1)*DPROJ], acc);
  if (t>=2) acc = fmaf(w1, src[(size_t)(m-2)*DPROJ], acc);
  if (t>=3) acc = fmaf(w0, src[(size_t)(m-3)*DPROJ], acc);
  xbc[idx] = acc * sigmoidf_(acc);
}

// -------- dt = softplus(raw+bias); la = chunk-local cumsum(dt*A) --------
__launch_bounds__(64)
__global__ void dt_kernel(const float* __restrict__ zx,
                          const float* __restrict__ dt_bias,
                          const float* __restrict__ A_log,
                          float* __restrict__ dts, float* __restrict__ las){
  int blk = blockIdx.x;             // b*NH*NC + h*NC + c
  int c = blk % NC; int h = (blk/NC)%NH; int b = blk/(NC*NH);
  int lane = threadIdx.x;
  int t = c*Q + lane;
  float raw = zx[(size_t)(b*L_+t)*DPROJ + DI + CONVD + h] + dt_bias[h];
  float dtv = raw > 20.f ? raw : log1pf(__expf(raw));
  float A = -__expf(A_log[h]);
  float la = dtv * A;
#pragma unroll
  for (int off=1; off<64; off<<=1){
    float v = __shfl_up(la, off);
    if (lane >= off) la += v;
  }
  int idx = (b*NH+h)*L_ + t;
  dts[idx] = dtv;
  las[idx] = la;
}

// -------- K1: per-chunk state  S_chunk[p][n] = sum_s w[s] x[s][p] B[s][n] --------
__launch_bounds__(256)
__global__ void chunk_state_kernel(const float* __restrict__ xbc,
                                   const float* __restrict__ dts,
                                   const float* __restrict__ las,
                                   float* __restrict__ Schunk){
  __shared__ float Xw[Q][68];
  __shared__ float Bs[Q][132];
  int c = blockIdx.x, h = blockIdx.y, b = blockIdx.z;
  int tid = threadIdx.x;
  int bh = b*NH + h;
  const int tbase = bh*L_ + c*Q;
  float la63 = las[tbase + 63];

  for (int it = tid; it < Q*16; it += 256){
    int s = it >> 4, p4 = (it & 15) << 2;
    float4 v = *(const float4*)&xbc[(size_t)(b*L_ + c*Q + s)*CONVD + h*HD + p4];
    float w = __expf(la63 - las[tbase + s]) * dts[tbase + s];
    Xw[s][p4+0]=v.x*w; Xw[s][p4+1]=v.y*w; Xw[s][p4+2]=v.z*w; Xw[s][p4+3]=v.w*w;
  }
  for (int it = tid; it < Q*32; it += 256){
    int s = it >> 5, n4 = (it & 31) << 2;
    float4 v = *(const float4*)&xbc[(size_t)(b*L_ + c*Q + s)*CONVD + DI + n4];
    Bs[s][n4+0]=v.x; Bs[s][n4+1]=v.y; Bs[s][n4+2]=v.z; Bs[s][n4+3]=v.w;
  }
  __syncthreads();

  int ty = tid >> 4, tx = tid & 15;
  int p0 = ty*4;
  float acc[4][8] = {};
#pragma unroll 4
  for (int k=0;k<Q;k++){
    float4 a4 = *(const float4*)&Xw[k][p0];
    float4 b0 = *(const float4*)&Bs[k][tx*4];
    float4 b1 = *(const float4*)&Bs[k][64 + tx*4];
    float a[4]={a4.x,a4.y,a4.z,a4.w};
    float bb[8]={b0.x,b0.y,b0.z,b0.w,b1.x,b1.y,b1.z,b1.w};
#pragma unroll
    for(int i=0;i<4;i++)
#pragma unroll
      for(int j=0;j<8;j++) acc[i][j] = fmaf(a[i], bb[j], acc[i][j]);
  }
  float* Sb = Schunk + ((size_t)bh*NC + c)*(HD*DS);
#pragma unroll
  for(int i=0;i<4;i++){
    int p = p0+i;
    *(float4*)&Sb[p*DS + tx*4]      = make_float4(acc[i][0],acc[i][1],acc[i][2],acc[i][3]);
    *(float4*)&Sb[p*DS + 64 + tx*4] = make_float4(acc[i][4],acc[i][5],acc[i][6],acc[i][7]);
  }
}

// -------- K2: inter-chunk scan (in-place: Schunk -> S_start) --------
__launch_bounds__(256)
__global__ void interchunk_kernel(float* __restrict__ S, const float* __restrict__ las){
  int blk = blockIdx.x;
  int slice = blk & 7; int bh = blk >> 3;
  size_t base = (size_t)bh*NC*(HD*DS) + slice*1024 + threadIdx.x*4;
  float4 run = make_float4(0,0,0,0);
#pragma unroll
  for (int c=0;c<NC;c++){
    float dec = __expf(las[bh*L_ + c*Q + 63]);
    float4 ch = *(float4*)(S + base + c*(HD*DS));
    *(float4*)(S + base + c*(HD*DS)) = run;
    run.x = fmaf(run.x, dec, ch.x);
    run.y = fmaf(run.y, dec, ch.y);
    run.z = fmaf(run.z, dec, ch.z);
    run.w = fmaf(run.w, dec, ch.w);
  }
}

// -------- K3: per-chunk outputs --------
__launch_bounds__(256)
__global__ void chunk_out_kernel(const float* __restrict__ zx,
                                 const float* __restrict__ xbc,
                                 const float* __restrict__ dts,
                                 const float* __restrict__ las,
                                 const float* __restrict__ Sstart,
                                 const float* __restrict__ Dp,
                                 float* __restrict__ yy){
  __shared__ float R1[8192];
  __shared__ float R2[8192];
  int c = blockIdx.x, h = blockIdx.y, b = blockIdx.z;
  int tid = threadIdx.x;
  int bh = b*NH + h;
  const int tbase = bh*L_ + c*Q;
  const float Dh = Dp[h];
  int ty = tid >> 4, tx = tid & 15;
  int t0 = ty*4, p0 = tx*4;

  for (int it = tid; it < 64*32; it += 256){
    int t = it & 63, n4 = (it >> 6) << 2;
    float4 v = *(const float4*)&xbc[(size_t)(b*L_ + c*Q + t)*CONVD + DI + DS + n4];
    R1[(n4+0)*64 + t]=v.x; R1[(n4+1)*64 + t]=v.y; R1[(n4+2)*64 + t]=v.z; R1[(n4+3)*64 + t]=v.w;
  }
  const float* Sb = Sstart + ((size_t)bh*NC + c)*(HD*DS);
  for (int it = tid; it < 64*32; it += 256){
    int p = it & 63, n4 = (it >> 6) << 2;
    float4 v = *(const float4*)&Sb[p*DS + n4];
    R2[(n4+0)*64 + p]=v.x; R2[(n4+1)*64 + p]=v.y; R2[(n4+2)*64 + p]=v.z; R2[(n4+3)*64 + p]=v.w;
  }
  __syncthreads();

  float Yi[4][4] = {};
#pragma unroll 4
  for (int k=0;k<DS;k++){
    float4 a4 = *(const float4*)&R1[k*64 + t0];
    float4 b4 = *(const float4*)&R2[k*64 + p0];
    float a[4]={a4.x,a4.y,a4.z,a4.w}, bb[4]={b4.x,b4.y,b4.z,b4.w};
#pragma unroll
    for(int i=0;i<4;i++)
#pragma unroll
      for(int j=0;j<4;j++) Yi[i][j] = fmaf(a[i], bb[j], Yi[i][j]);
  }
  __syncthreads();

  for (int it = tid; it < 64*32; it += 256){
    int s = it & 63, n4 = (it >> 6) << 2;
    float4 v = *(const float4*)&xbc[(size_t)(b*L_ + c*Q + s)*CONVD + DI + n4];
    R2[(n4+0)*64 + s]=v.x; R2[(n4+1)*64 + s]=v.y; R2[(n4+2)*64 + s]=v.z; R2[(n4+3)*64 + s]=v.w;
  }
  __syncthreads();

  float E[4][4] = {};
#pragma unroll 4
  for (int k=0;k<DS;k++){
    float4 a4 = *(const float4*)&R1[k*64 + t0];
    float4 b4 = *(const float4*)&R2[k*64 + p0];
    float a[4]={a4.x,a4.y,a4.z,a4.w}, bb[4]={b4.x,b4.y,b4.z,b4.w};
#pragma unroll
    for(int i=0;i<4;i++)
#pragma unroll
      for(int j=0;j<4;j++) E[i][j] = fmaf(a[i], bb[j], E[i][j]);
  }
  __syncthreads();

  {
    float lat[4], lass[4], dtv[4];
#pragma unroll
    for(int i=0;i<4;i++) lat[i]  = las[tbase + t0 + i];
#pragma unroll
    for(int j=0;j<4;j++){ lass[j] = las[tbase + p0 + j]; dtv[j] = dts[tbase + p0 + j]; }
#pragma unroll
    for(int i=0;i<4;i++)
#pragma unroll
      for(int j=0;j<4;j++){
        int t = t0+i, s = p0+j;
        float g = 0.f;
        if (s <= t) g = __expf(lat[i] - lass[j]) * dtv[j] * E[i][j];
        R1[t*65 + s] = g;
      }
  }
  for (int it = tid; it < 64*16; it += 256){
    int s = it >> 4, p4 = (it & 15) << 2;
    float4 v = *(const float4*)&xbc[(size_t)(b*L_ + c*Q + s)*CONVD + h*HD + p4];
    *(float4*)&R2[s*64 + p4] = v;
  }
  __syncthreads();

  float Yv[4][4] = {};
#pragma unroll 4
  for (int k=0;k<Q;k++){
    float g[4];
#pragma unroll
    for(int i=0;i<4;i++) g[i] = R1[(t0+i)*65 + k];
    float4 x4 = *(const float4*)&R2[k*64 + p0];
    float xx[4]={x4.x,x4.y,x4.z,x4.w};
#pragma unroll
    for(int i=0;i<4;i++)
#pragma unroll
      for(int j=0;j<4;j++) Yv[i][j] = fmaf(g[i], xx[j], Yv[i][j]);
  }

#pragma unroll
  for(int i=0;i<4;i++){
    int t = t0 + i;
    float cp = __expf(las[tbase + t]);
    size_t row = (size_t)(b*L_ + c*Q + t);
    float4 z4 = *(const float4*)&zx[row*DPROJ + h*HD + p0];
    float zz[4]={z4.x,z4.y,z4.z,z4.w};
    float o[4];
#pragma unroll
    for(int j=0;j<4;j++){
      float xv = R2[t*64 + p0 + j];
      float y = fmaf(cp, Yi[i][j], Yv[i][j]) + Dh*xv;
      o[j] = y * (zz[j] * sigmoidf_(zz[j]));
    }
    *(float4*)&yy[row*DI + h*HD + p0] = make_float4(o[0],o[1],o[2],o[3]);
  }
}

extern "C" void kernel_launch(void* const* d_in, const int* in_sizes, int n_in,
                              void* d_out, int out_size, void* d_ws, size_t ws_size,
                              hipStream_t stream) {
  const float* u       = (const float*)d_in[0];
  const float* W_in    = (const float*)d_in[1];
  const float* conv_w  = (const float*)d_in[2];
  const float* conv_b  = (const float*)d_in[3];
  const float* dt_bias = (const float*)d_in[4];
  const float* A_log   = (const float*)d_in[5];
  const float* D_param = (const float*)d_in[6];
  const float* W_out   = (const float*)d_in[7];
  float* out = (float*)d_out;

  float* ws = (float*)d_ws;
  float* zx     = ws;
  float* xbc    = zx   + (size_t)ML*DPROJ;
  float* dts    = xbc  + (size_t)ML*CONVD;
  float* las    = dts  + (size_t)B_*NH*L_;
  float* yy     = las  + (size_t)B_*NH*L_;
  float* Schunk = yy   + (size_t)ML*DI;

  // 1) in-projection GEMM (MFMA split-bf16)
  {
    dim3 grid((DPROJ+127)/128, ML/128);
    gemm_mfma_nt<128,128><<<grid, 256, 0, stream>>>(u, W_in, zx, ML, DPROJ, DM);
  }
  // 2) conv + SiLU
  {
    int n = ML*CONVD;
    conv_kernel<<<(n+255)/256, 256, 0, stream>>>(zx, conv_w, conv_b, xbc);
  }
  // 3) dt + chunk-local cumsum(dt*A)
  dt_kernel<<<B_*NH*NC, 64, 0, stream>>>(zx, dt_bias, A_log, dts, las);
  // 4) chunk states
  {
    dim3 grid(NC, NH, B_);
    chunk_state_kernel<<<grid, 256, 0, stream>>>(xbc, dts, las, Schunk);
  }
  // 5) inter-chunk scan
  interchunk_kernel<<<B_*NH*8, 256, 0, stream>>>(Schunk, las);
  // 6) chunk outputs
  {
    dim3 grid(NC, NH, B_);
    chunk_out_kernel<<<grid, 256, 0, stream>>>(zx, xbc, dts, las, Schunk, D_param, yy);
  }
  // 7) out-projection GEMM (MFMA split-bf16)
  {
    dim3 grid(DM/64, ML/64);
    gemm_mfma_nt<64,64><<<grid, 256, 0, stream>>>(yy, W_out, out, ML, DM, DI);
  }
}

// Round 4
// 246.432 us; speedup vs baseline: 2.3082x; 1.0347x over previous
//
#include <hip/hip_runtime.h>
#include <math.h>

#define B_     2
#define L_     512
#define DM     768
#define DS     128
#define HD     64
#define DI     1536
#define NH     24
#define CONVD  1792
#define DPROJ  3352
#define ML     (B_*L_)
#define Q      64
#define NC     (L_/Q)
#define NPAD1  3456

typedef __bf16 bf16x8 __attribute__((ext_vector_type(8)));
typedef float f32x4 __attribute__((ext_vector_type(4)));

__device__ __forceinline__ float sigmoidf_(float x){ return 1.f/(1.f+__expf(-x)); }
__device__ __forceinline__ ushort bf16rn(float x){
  uint u = __float_as_uint(x);
  u += 0x7fff + ((u>>16)&1);
  return (ushort)(u>>16);
}
__device__ __forceinline__ float bf2f(ushort h){ return __uint_as_float(((uint)h)<<16); }
__device__ __forceinline__ void gll16(const void* g, void* l){
  __builtin_amdgcn_global_load_lds((const __attribute__((address_space(1))) void*)g,
                                   (__attribute__((address_space(3))) void*)l, 16, 0, 0);
}

// ---- convert fp32 MxK -> bf16 planes [hi | lo] stored as Rdst x 2K (zero-pad rows) ----
__launch_bounds__(256)
__global__ void cvt_split(const float* __restrict__ src, ushort* __restrict__ dst,
                          int Rsrc, int Rdst, int K){
  int idx = blockIdx.x*256 + threadIdx.x;
  int K4 = K>>2;
  if (idx >= Rdst*K4) return;
  int r = idx / K4, c = (idx - r*K4)<<2;
  float4 v = make_float4(0,0,0,0);
  if (r < Rsrc) v = *(const float4*)&src[(size_t)r*K + c];
  float xv[4] = {v.x,v.y,v.z,v.w};
  uint hp[2], lp[2];
  ushort h[4], l[4];
#pragma unroll
  for (int j=0;j<4;j++){ h[j]=bf16rn(xv[j]); l[j]=bf16rn(xv[j]-bf2f(h[j])); }
  hp[0] = (uint)h[0] | ((uint)h[1]<<16); hp[1] = (uint)h[2] | ((uint)h[3]<<16);
  lp[0] = (uint)l[0] | ((uint)l[1]<<16); lp[1] = (uint)l[2] | ((uint)l[3]<<16);
  *(uint2*)&dst[(size_t)r*2*K + c]     = make_uint2(hp[0],hp[1]);
  *(uint2*)&dst[(size_t)r*2*K + K + c] = make_uint2(lp[0],lp[1]);
}

// ---- bf16 GEMM with K''=3K segment remap (hi*hi + lo*hi + hi*lo) ----
// AS: M x 2K bf16 [hi|lo]; BS: Npad x 2K bf16 [hi|lo]; C: M x Nstore fp32.
template<int BM,int BN,int K>
__launch_bounds__(256)
__global__ void gemm3(const ushort* __restrict__ AS, const ushort* __restrict__ BS,
                      float* __restrict__ C, int Nvalid, int Nstore){
  constexpr int WM=BM/2, WN=BN/2, FM=WM/16, FN=WN/16, SPS=K/64, STEPS=3*SPS;
  __shared__ ushort Al[BM*64];
  __shared__ ushort Bl[BN*64];
  const int tid=threadIdx.x, lane=tid&63, w=tid>>6;
  const int WR=w>>1, WC=w&1;
  const int bm=blockIdx.y*BM, bn=blockIdx.x*BN;
  const int lr=lane&15, lk8=(lane>>4)*8;
  const int srow=lane>>3, scol=(lane&7)*8;
  f32x4 acc[FM][FN] = {};

  for (int ks=0; ks<STEPS; ks++){
    int seg = ks/SPS;
    int kin = (ks - seg*SPS)*64;
    int ak = kin + (seg==1 ? K : 0);
    int bk = kin + (seg==2 ? K : 0);
#pragma unroll
    for (int ci=w; ci<BM/8; ci+=4)
      gll16(&AS[(size_t)(bm + ci*8 + srow)*(2*K) + ak + scol], &Al[ci*512]);
#pragma unroll
    for (int ci=w; ci<BN/8; ci+=4)
      gll16(&BS[(size_t)(bn + ci*8 + srow)*(2*K) + bk + scol], &Bl[ci*512]);
    __syncthreads();

    bf16x8 af[2][FM], bfr[2][FN];
#pragma unroll
    for (int s2=0;s2<2;s2++){
#pragma unroll
      for (int i=0;i<FM;i++) af[s2][i]  = *(const bf16x8*)&Al[(WR*WM + i*16 + lr)*64 + s2*32 + lk8];
#pragma unroll
      for (int j=0;j<FN;j++) bfr[s2][j] = *(const bf16x8*)&Bl[(WC*WN + j*16 + lr)*64 + s2*32 + lk8];
    }
#pragma unroll
    for (int s2=0;s2<2;s2++)
#pragma unroll
      for (int i=0;i<FM;i++)
#pragma unroll
        for (int j=0;j<FN;j++)
          acc[i][j] = __builtin_amdgcn_mfma_f32_16x16x32_bf16(af[s2][i], bfr[s2][j], acc[i][j], 0,0,0);
    __syncthreads();
  }

#pragma unroll
  for (int i=0;i<FM;i++)
#pragma unroll
    for (int j=0;j<FN;j++){
      int n = bn + WC*WN + j*16 + lr;
      if (n < Nvalid){
#pragma unroll
        for (int e=0;e<4;e++){
          int m = bm + WR*WM + i*16 + (lane>>4)*4 + e;
          C[(size_t)m*Nstore + n] = acc[i][j][e];
        }
      }
    }
}

// ---- rolling-window causal conv (width 4) + SiLU ----
__launch_bounds__(256)
__global__ void conv2_kernel(const float* __restrict__ zx,
                             const float* __restrict__ cw,
                             const float* __restrict__ cb,
                             float* __restrict__ xbc){
  int g = blockIdx.x;          // 0..6 channel group of 256
  int c = blockIdx.y;          // chunk
  int b = blockIdx.z;
  int ch = g*256 + threadIdx.x;
  const float* src = zx + (size_t)(b*L_ + c*Q)*DPROJ + DI + ch;
  float* dst = xbc + (size_t)(b*L_ + c*Q)*CONVD + ch;
  float w0=cw[ch*4],w1=cw[ch*4+1],w2=cw[ch*4+2],w3=cw[ch*4+3],bias=cb[ch];
  float x0=0.f,x1=0.f,x2=0.f;
  if (c > 0){
    x0 = *(src - 3*DPROJ);
    x1 = *(src - 2*DPROJ);
    x2 = *(src - 1*DPROJ);
  }
#pragma unroll 4
  for (int tt=0; tt<Q; tt++){
    float xt = src[(size_t)tt*DPROJ];
    float a = bias;
    a = fmaf(w3, xt, a); a = fmaf(w2, x2, a); a = fmaf(w1, x1, a); a = fmaf(w0, x0, a);
    dst[(size_t)tt*CONVD] = a * sigmoidf_(a);
    x0 = x1; x1 = x2; x2 = xt;
  }
}

// -------- dt = softplus(raw+bias); la = chunk-local cumsum(dt*A) --------
__launch_bounds__(64)
__global__ void dt_kernel(const float* __restrict__ zx,
                          const float* __restrict__ dt_bias,
                          const float* __restrict__ A_log,
                          float* __restrict__ dts, float* __restrict__ las){
  int blk = blockIdx.x;             // b*NH*NC + h*NC + c
  int c = blk % NC; int h = (blk/NC)%NH; int b = blk/(NC*NH);
  int lane = threadIdx.x;
  int t = c*Q + lane;
  float raw = zx[(size_t)(b*L_+t)*DPROJ + DI + CONVD + h] + dt_bias[h];
  float dtv = raw > 20.f ? raw : log1pf(__expf(raw));
  float A = -__expf(A_log[h]);
  float la = dtv * A;
#pragma unroll
  for (int off=1; off<64; off<<=1){
    float v = __shfl_up(la, off);
    if (lane >= off) la += v;
  }
  int idx = (b*NH+h)*L_ + t;
  dts[idx] = dtv;
  las[idx] = la;
}

// -------- K1: per-chunk state  S_chunk[p][n] = sum_s w[s] x[s][p] B[s][n] --------
__launch_bounds__(256)
__global__ void chunk_state_kernel(const float* __restrict__ xbc,
                                   const float* __restrict__ dts,
                                   const float* __restrict__ las,
                                   float* __restrict__ Schunk){
  __shared__ float Xw[Q][68];
  __shared__ float Bs[Q][132];
  int c = blockIdx.x, h = blockIdx.y, b = blockIdx.z;
  int tid = threadIdx.x;
  int bh = b*NH + h;
  const int tbase = bh*L_ + c*Q;
  float la63 = las[tbase + 63];

  for (int it = tid; it < Q*16; it += 256){
    int s = it >> 4, p4 = (it & 15) << 2;
    float4 v = *(const float4*)&xbc[(size_t)(b*L_ + c*Q + s)*CONVD + h*HD + p4];
    float w = __expf(la63 - las[tbase + s]) * dts[tbase + s];
    Xw[s][p4+0]=v.x*w; Xw[s][p4+1]=v.y*w; Xw[s][p4+2]=v.z*w; Xw[s][p4+3]=v.w*w;
  }
  for (int it = tid; it < Q*32; it += 256){
    int s = it >> 5, n4 = (it & 31) << 2;
    float4 v = *(const float4*)&xbc[(size_t)(b*L_ + c*Q + s)*CONVD + DI + n4];
    Bs[s][n4+0]=v.x; Bs[s][n4+1]=v.y; Bs[s][n4+2]=v.z; Bs[s][n4+3]=v.w;
  }
  __syncthreads();

  int ty = tid >> 4, tx = tid & 15;
  int p0 = ty*4;
  float acc[4][8] = {};
#pragma unroll 4
  for (int k=0;k<Q;k++){
    float4 a4 = *(const float4*)&Xw[k][p0];
    float4 b0 = *(const float4*)&Bs[k][tx*4];
    float4 b1 = *(const float4*)&Bs[k][64 + tx*4];
    float a[4]={a4.x,a4.y,a4.z,a4.w};
    float bb[8]={b0.x,b0.y,b0.z,b0.w,b1.x,b1.y,b1.z,b1.w};
#pragma unroll
    for(int i=0;i<4;i++)
#pragma unroll
      for(int j=0;j<8;j++) acc[i][j] = fmaf(a[i], bb[j], acc[i][j]);
  }
  float* Sb = Schunk + ((size_t)bh*NC + c)*(HD*DS);
#pragma unroll
  for(int i=0;i<4;i++){
    int p = p0+i;
    *(float4*)&Sb[p*DS + tx*4]      = make_float4(acc[i][0],acc[i][1],acc[i][2],acc[i][3]);
    *(float4*)&Sb[p*DS + 64 + tx*4] = make_float4(acc[i][4],acc[i][5],acc[i][6],acc[i][7]);
  }
}

// -------- K2: inter-chunk scan (in-place: Schunk -> S_start) --------
__launch_bounds__(256)
__global__ void interchunk_kernel(float* __restrict__ S, const float* __restrict__ las){
  int blk = blockIdx.x;
  int slice = blk & 7; int bh = blk >> 3;
  size_t base = (size_t)bh*NC*(HD*DS) + slice*1024 + threadIdx.x*4;
  float4 run = make_float4(0,0,0,0);
#pragma unroll
  for (int c=0;c<NC;c++){
    float dec = __expf(las[bh*L_ + c*Q + 63]);
    float4 ch = *(float4*)(S + base + c*(HD*DS));
    *(float4*)(S + base + c*(HD*DS)) = run;
    run.x = fmaf(run.x, dec, ch.x);
    run.y = fmaf(run.y, dec, ch.y);
    run.z = fmaf(run.z, dec, ch.z);
    run.w = fmaf(run.w, dec, ch.w);
  }
}

// -------- K3: per-chunk outputs; emits y directly as split-bf16 planes --------
__launch_bounds__(256)
__global__ void chunk_out_kernel(const float* __restrict__ zx,
                                 const float* __restrict__ xbc,
                                 const float* __restrict__ dts,
                                 const float* __restrict__ las,
                                 const float* __restrict__ Sstart,
                                 const float* __restrict__ Dp,
                                 ushort* __restrict__ yS){
  __shared__ float R1[8192];
  __shared__ float R2[8192];
  int c = blockIdx.x, hh = blockIdx.y, b = blockIdx.z;
  int tid = threadIdx.x;
  int bh = b*NH + hh;
  const int tbase = bh*L_ + c*Q;
  const float Dh = Dp[hh];
  int ty = tid >> 4, tx = tid & 15;
  int t0 = ty*4, p0 = tx*4;

  for (int it = tid; it < 64*32; it += 256){
    int t = it & 63, n4 = (it >> 6) << 2;
    float4 v = *(const float4*)&xbc[(size_t)(b*L_ + c*Q + t)*CONVD + DI + DS + n4];
    R1[(n4+0)*64 + t]=v.x; R1[(n4+1)*64 + t]=v.y; R1[(n4+2)*64 + t]=v.z; R1[(n4+3)*64 + t]=v.w;
  }
  const float* Sb = Sstart + ((size_t)bh*NC + c)*(HD*DS);
  for (int it = tid; it < 64*32; it += 256){
    int p = it & 63, n4 = (it >> 6) << 2;
    float4 v = *(const float4*)&Sb[p*DS + n4];
    R2[(n4+0)*64 + p]=v.x; R2[(n4+1)*64 + p]=v.y; R2[(n4+2)*64 + p]=v.z; R2[(n4+3)*64 + p]=v.w;
  }
  __syncthreads();

  float Yi[4][4] = {};
#pragma unroll 4
  for (int k=0;k<DS;k++){
    float4 a4 = *(const float4*)&R1[k*64 + t0];
    float4 b4 = *(const float4*)&R2[k*64 + p0];
    float a[4]={a4.x,a4.y,a4.z,a4.w}, bb[4]={b4.x,b4.y,b4.z,b4.w};
#pragma unroll
    for(int i=0;i<4;i++)
#pragma unroll
      for(int j=0;j<4;j++) Yi[i][j] = fmaf(a[i], bb[j], Yi[i][j]);
  }
  __syncthreads();

  for (int it = tid; it < 64*32; it += 256){
    int s = it & 63, n4 = (it >> 6) << 2;
    float4 v = *(const float4*)&xbc[(size_t)(b*L_ + c*Q + s)*CONVD + DI + n4];
    R2[(n4+0)*64 + s]=v.x; R2[(n4+1)*64 + s]=v.y; R2[(n4+2)*64 + s]=v.z; R2[(n4+3)*64 + s]=v.w;
  }
  __syncthreads();

  float E[4][4] = {};
#pragma unroll 4
  for (int k=0;k<DS;k++){
    float4 a4 = *(const float4*)&R1[k*64 + t0];
    float4 b4 = *(const float4*)&R2[k*64 + p0];
    float a[4]={a4.x,a4.y,a4.z,a4.w}, bb[4]={b4.x,b4.y,b4.z,b4.w};
#pragma unroll
    for(int i=0;i<4;i++)
#pragma unroll
      for(int j=0;j<4;j++) E[i][j] = fmaf(a[i], bb[j], E[i][j]);
  }
  __syncthreads();

  {
    float lat[4], lass[4], dtv[4];
#pragma unroll
    for(int i=0;i<4;i++) lat[i]  = las[tbase + t0 + i];
#pragma unroll
    for(int j=0;j<4;j++){ lass[j] = las[tbase + p0 + j]; dtv[j] = dts[tbase + p0 + j]; }
#pragma unroll
    for(int i=0;i<4;i++)
#pragma unroll
      for(int j=0;j<4;j++){
        int t = t0+i, s = p0+j;
        float g = 0.f;
        if (s <= t) g = __expf(lat[i] - lass[j]) * dtv[j] * E[i][j];
        R1[t*65 + s] = g;
      }
  }
  for (int it = tid; it < 64*16; it += 256){
    int s = it >> 4, p4 = (it & 15) << 2;
    float4 v = *(const float4*)&xbc[(size_t)(b*L_ + c*Q + s)*CONVD + hh*HD + p4];
    *(float4*)&R2[s*64 + p4] = v;
  }
  __syncthreads();

  float Yv[4][4] = {};
#pragma unroll 4
  for (int k=0;k<Q;k++){
    float g[4];
#pragma unroll
    for(int i=0;i<4;i++) g[i] = R1[(t0+i)*65 + k];
    float4 x4 = *(const float4*)&R2[k*64 + p0];
    float xx[4]={x4.x,x4.y,x4.z,x4.w};
#pragma unroll
    for(int i=0;i<4;i++)
#pragma unroll
      for(int j=0;j<4;j++) Yv[i][j] = fmaf(g[i], xx[j], Yv[i][j]);
  }

#pragma unroll
  for(int i=0;i<4;i++){
    int t = t0 + i;
    float cp = __expf(las[tbase + t]);
    size_t row = (size_t)(b*L_ + c*Q + t);
    float4 z4 = *(const float4*)&zx[row*DPROJ + hh*HD + p0];
    float zz[4]={z4.x,z4.y,z4.z,z4.w};
    ushort h4[4], l4[4];
#pragma unroll
    for(int j=0;j<4;j++){
      float xv = R2[t*64 + p0 + j];
      float y = fmaf(cp, Yi[i][j], Yv[i][j]) + Dh*xv;
      float o = y * (zz[j] * sigmoidf_(zz[j]));
      h4[j] = bf16rn(o);
      l4[j] = bf16rn(o - bf2f(h4[j]));
    }
    size_t o0 = row*(size_t)(2*DI) + hh*HD + p0;
    *(uint2*)&yS[o0]      = make_uint2((uint)h4[0]|((uint)h4[1]<<16), (uint)h4[2]|((uint)h4[3]<<16));
    *(uint2*)&yS[o0 + DI] = make_uint2((uint)l4[0]|((uint)l4[1]<<16), (uint)l4[2]|((uint)l4[3]<<16));
  }
}

extern "C" void kernel_launch(void* const* d_in, const int* in_sizes, int n_in,
                              void* d_out, int out_size, void* d_ws, size_t ws_size,
                              hipStream_t stream) {
  const float* u       = (const float*)d_in[0];
  const float* W_in    = (const float*)d_in[1];
  const float* conv_w  = (const float*)d_in[2];
  const float* conv_b  = (const float*)d_in[3];
  const float* dt_bias = (const float*)d_in[4];
  const float* A_log   = (const float*)d_in[5];
  const float* D_param = (const float*)d_in[6];
  const float* W_out   = (const float*)d_in[7];
  float* out = (float*)d_out;

  float* ws = (float*)d_ws;
  float* zx     = ws;                                        // 1024*3352
  float* xbc    = zx   + (size_t)ML*DPROJ;                   // 1024*1792
  float* dts    = xbc  + (size_t)ML*CONVD;                   // 24576
  float* las    = dts  + (size_t)B_*NH*L_;                   // 24576
  float* Schunk = las  + (size_t)B_*NH*L_;                   // 48*8*8192
  // uS (1024*1536 us) aliased with yS (1024*3072 us): uS dead after gemm1
  ushort* uS    = (ushort*)(Schunk + (size_t)B_*NH*NC*HD*DS);
  ushort* yS    = uS;
  // WinS (3456*1536 us) aliased with WoutS (768*3072 us): WinS dead after gemm1
  ushort* WinS  = yS + (size_t)ML*2*DI;
  ushort* WoutS = WinS;

  // 1) split-convert u and W_in
  cvt_split<<<(ML*(DM/4)+255)/256, 256, 0, stream>>>(u, uS, ML, ML, DM);
  cvt_split<<<(NPAD1*(DM/4)+255)/256, 256, 0, stream>>>(W_in, WinS, DPROJ, NPAD1, DM);
  // 2) in-projection GEMM (bf16 3-segment split)
  {
    dim3 grid(NPAD1/64, ML/128);
    gemm3<128,64,DM><<<grid, 256, 0, stream>>>(uS, WinS, zx, DPROJ, DPROJ);
  }
  // 3) conv + SiLU (rolling window)
  {
    dim3 grid(7, NC, B_);
    conv2_kernel<<<grid, 256, 0, stream>>>(zx, conv_w, conv_b, xbc);
  }
  // 4) dt + chunk-local cumsum(dt*A)
  dt_kernel<<<B_*NH*NC, 64, 0, stream>>>(zx, dt_bias, A_log, dts, las);
  // 5) chunk states
  {
    dim3 grid(NC, NH, B_);
    chunk_state_kernel<<<grid, 256, 0, stream>>>(xbc, dts, las, Schunk);
  }
  // 6) inter-chunk scan
  interchunk_kernel<<<B_*NH*8, 256, 0, stream>>>(Schunk, las);
  // 7) chunk outputs -> yS split planes
  {
    dim3 grid(NC, NH, B_);
    chunk_out_kernel<<<grid, 256, 0, stream>>>(zx, xbc, dts, las, Schunk, D_param, yS);
  }
  // 8) split-convert W_out (into region formerly holding WinS)
  cvt_split<<<(DM*(DI/4)+255)/256, 256, 0, stream>>>(W_out, WoutS, DM, DM, DI);
  // 9) out-projection GEMM
  {
    dim3 grid(DM/64, ML/64);
    gemm3<64,64,DI><<<grid, 256, 0, stream>>>(yS, WoutS, out, DM, DM);
  }
}

// Round 5
// 230.954 us; speedup vs baseline: 2.4629x; 1.0670x over previous
//
#include <hip/hip_runtime.h>
#include <math.h>

#define B_     2
#define L_     512
#define DM     768
#define DS     128
#define HD     64
#define DI     1536
#define NH     24
#define CONVD  1792
#define DPROJ  3352
#define ML     (B_*L_)
#define Q      64
#define NC     (L_/Q)
#define NPAD1  3456

typedef __bf16 bf16x8 __attribute__((ext_vector_type(8)));
typedef float f32x4 __attribute__((ext_vector_type(4)));

__device__ __forceinline__ float sigmoidf_(float x){ return 1.f/(1.f+__expf(-x)); }
__device__ __forceinline__ ushort bf16rn(float x){
  uint u = __float_as_uint(x);
  u += 0x7fff + ((u>>16)&1);
  return (ushort)(u>>16);
}
__device__ __forceinline__ float bf2f(ushort h){ return __uint_as_float(((uint)h)<<16); }
__device__ __forceinline__ void gll16(const void* g, void* l){
  __builtin_amdgcn_global_load_lds((const __attribute__((address_space(1))) void*)g,
                                   (__attribute__((address_space(3))) void*)l, 16, 0, 0);
}

// ---- convert fp32 MxK -> bf16 planes [hi | lo] stored as Rdst x 2K (zero-pad rows) ----
__launch_bounds__(256)
__global__ void cvt_split(const float* __restrict__ src, ushort* __restrict__ dst,
                          int Rsrc, int Rdst, int K){
  int idx = blockIdx.x*256 + threadIdx.x;
  int K4 = K>>2;
  if (idx >= Rdst*K4) return;
  int r = idx / K4, c = (idx - r*K4)<<2;
  float4 v = make_float4(0,0,0,0);
  if (r < Rsrc) v = *(const float4*)&src[(size_t)r*K + c];
  float xv[4] = {v.x,v.y,v.z,v.w};
  uint hp[2], lp[2];
  ushort h[4], l[4];
#pragma unroll
  for (int j=0;j<4;j++){ h[j]=bf16rn(xv[j]); l[j]=bf16rn(xv[j]-bf2f(h[j])); }
  hp[0] = (uint)h[0] | ((uint)h[1]<<16); hp[1] = (uint)h[2] | ((uint)h[3]<<16);
  lp[0] = (uint)l[0] | ((uint)l[1]<<16); lp[1] = (uint)l[2] | ((uint)l[3]<<16);
  *(uint2*)&dst[(size_t)r*2*K + c]     = make_uint2(hp[0],hp[1]);
  *(uint2*)&dst[(size_t)r*2*K + K + c] = make_uint2(lp[0],lp[1]);
}

// ---- bf16 GEMM, K''=3K segment remap (hi*hi + lo*hi + hi*lo) ----
// Swizzled LDS (slot ^= row&7, matched on source & read) + 2-phase dbuf pipeline.
// AS: M x 2K bf16 [hi|lo]; BS: Npad x 2K bf16 [hi|lo]; C: M x Nstore fp32.
template<int BM,int BN,int K>
__launch_bounds__(256)
__global__ void gemm3(const ushort* __restrict__ AS, const ushort* __restrict__ BS,
                      float* __restrict__ C, int Nvalid, int Nstore){
  constexpr int WM=BM/2, WN=BN/2, FM=WM/16, FN=WN/16, SPS=K/64, STEPS=3*SPS;
  __shared__ ushort Al[2][BM*64];
  __shared__ ushort Bl[2][BN*64];
  const int tid=threadIdx.x, lane=tid&63, w=tid>>6;
  const int WR=w>>1, WC=w&1;
  const int bm=blockIdx.x*BM, bn=blockIdx.y*BN;
  const int lr=lane&15;
  const int srow=lane>>3;
  const int scol=(((lane&7) ^ (srow&7))*8);   // swizzled source column (ushorts)
  f32x4 acc[FM][FN] = {};

  auto stage = [&](int d, int ks){
    int seg = ks/SPS;
    int kin = (ks - seg*SPS)*64;
    int ak = kin + (seg==1 ? K : 0);
    int bk = kin + (seg==2 ? K : 0);
#pragma unroll
    for (int ci=w; ci<BM/8; ci+=4)
      gll16(&AS[(size_t)(bm + ci*8 + srow)*(2*K) + ak + scol], &Al[d][ci*512]);
#pragma unroll
    for (int ci=w; ci<BN/8; ci+=4)
      gll16(&BS[(size_t)(bn + ci*8 + srow)*(2*K) + bk + scol], &Bl[d][ci*512]);
  };

  stage(0, 0);
  __syncthreads();   // auto vmcnt(0): buf0 ready
  int cur = 0;
  for (int ks=0; ks<STEPS; ks++){
    if (ks+1 < STEPS) stage(cur^1, ks+1);   // prefetch next tile (drained at the barrier below)

    bf16x8 af[2][FM], bfr[2][FN];
#pragma unroll
    for (int s2=0;s2<2;s2++){
#pragma unroll
      for (int i=0;i<FM;i++){
        int R = WR*WM + i*16 + lr;
        int slot = (s2*4 + (lane>>4)) ^ (lr&7);
        af[s2][i] = *(const bf16x8*)&Al[cur][R*64 + slot*8];
      }
#pragma unroll
      for (int j=0;j<FN;j++){
        int R = WC*WN + j*16 + lr;
        int slot = (s2*4 + (lane>>4)) ^ (lr&7);
        bfr[s2][j] = *(const bf16x8*)&Bl[cur][R*64 + slot*8];
      }
    }
#pragma unroll
    for (int s2=0;s2<2;s2++)
#pragma unroll
      for (int i=0;i<FM;i++)
#pragma unroll
        for (int j=0;j<FN;j++)
          acc[i][j] = __builtin_amdgcn_mfma_f32_16x16x32_bf16(af[s2][i], bfr[s2][j], acc[i][j], 0,0,0);

    __syncthreads();  // drains vmcnt(0) (next tile landed) + lgkm; safe to swap
    cur ^= 1;
  }

#pragma unroll
  for (int i=0;i<FM;i++)
#pragma unroll
    for (int j=0;j<FN;j++){
      int n = bn + WC*WN + j*16 + lr;
      if (n < Nvalid){
#pragma unroll
        for (int e=0;e<4;e++){
          int m = bm + WR*WM + i*16 + (lane>>4)*4 + e;
          C[(size_t)m*Nstore + n] = acc[i][j][e];
        }
      }
    }
}

// ---- rolling-window causal conv (width 4) + SiLU ----
__launch_bounds__(256)
__global__ void conv2_kernel(const float* __restrict__ zx,
                             const float* __restrict__ cw,
                             const float* __restrict__ cb,
                             float* __restrict__ xbc){
  int g = blockIdx.x;          // 0..6 channel group of 256
  int c = blockIdx.y;          // chunk
  int b = blockIdx.z;
  int ch = g*256 + threadIdx.x;
  const float* src = zx + (size_t)(b*L_ + c*Q)*DPROJ + DI + ch;
  float* dst = xbc + (size_t)(b*L_ + c*Q)*CONVD + ch;
  float w0=cw[ch*4],w1=cw[ch*4+1],w2=cw[ch*4+2],w3=cw[ch*4+3],bias=cb[ch];
  float x0=0.f,x1=0.f,x2=0.f;
  if (c > 0){
    x0 = *(src - 3*DPROJ);
    x1 = *(src - 2*DPROJ);
    x2 = *(src - 1*DPROJ);
  }
#pragma unroll 4
  for (int tt=0; tt<Q; tt++){
    float xt = src[(size_t)tt*DPROJ];
    float a = bias;
    a = fmaf(w3, xt, a); a = fmaf(w2, x2, a); a = fmaf(w1, x1, a); a = fmaf(w0, x0, a);
    dst[(size_t)tt*CONVD] = a * sigmoidf_(a);
    x0 = x1; x1 = x2; x2 = xt;
  }
}

// -------- dt = softplus(raw+bias); la = chunk-local cumsum(dt*A) --------
__launch_bounds__(64)
__global__ void dt_kernel(const float* __restrict__ zx,
                          const float* __restrict__ dt_bias,
                          const float* __restrict__ A_log,
                          float* __restrict__ dts, float* __restrict__ las){
  int blk = blockIdx.x;             // b*NH*NC + h*NC + c
  int c = blk % NC; int h = (blk/NC)%NH; int b = blk/(NC*NH);
  int lane = threadIdx.x;
  int t = c*Q + lane;
  float raw = zx[(size_t)(b*L_+t)*DPROJ + DI + CONVD + h] + dt_bias[h];
  float dtv = raw > 20.f ? raw : log1pf(__expf(raw));
  float A = -__expf(A_log[h]);
  float la = dtv * A;
#pragma unroll
  for (int off=1; off<64; off<<=1){
    float v = __shfl_up(la, off);
    if (lane >= off) la += v;
  }
  int idx = (b*NH+h)*L_ + t;
  dts[idx] = dtv;
  las[idx] = la;
}

// -------- K1: per-chunk state  S_chunk[p][n] = sum_s w[s] x[s][p] B[s][n] --------
__launch_bounds__(256)
__global__ void chunk_state_kernel(const float* __restrict__ xbc,
                                   const float* __restrict__ dts,
                                   const float* __restrict__ las,
                                   float* __restrict__ Schunk){
  __shared__ float Xw[Q][68];
  __shared__ float Bs[Q][132];
  int c = blockIdx.x, h = blockIdx.y, b = blockIdx.z;
  int tid = threadIdx.x;
  int bh = b*NH + h;
  const int tbase = bh*L_ + c*Q;
  float la63 = las[tbase + 63];

  for (int it = tid; it < Q*16; it += 256){
    int s = it >> 4, p4 = (it & 15) << 2;
    float4 v = *(const float4*)&xbc[(size_t)(b*L_ + c*Q + s)*CONVD + h*HD + p4];
    float w = __expf(la63 - las[tbase + s]) * dts[tbase + s];
    Xw[s][p4+0]=v.x*w; Xw[s][p4+1]=v.y*w; Xw[s][p4+2]=v.z*w; Xw[s][p4+3]=v.w*w;
  }
  for (int it = tid; it < Q*32; it += 256){
    int s = it >> 5, n4 = (it & 31) << 2;
    float4 v = *(const float4*)&xbc[(size_t)(b*L_ + c*Q + s)*CONVD + DI + n4];
    Bs[s][n4+0]=v.x; Bs[s][n4+1]=v.y; Bs[s][n4+2]=v.z; Bs[s][n4+3]=v.w;
  }
  __syncthreads();

  int ty = tid >> 4, tx = tid & 15;
  int p0 = ty*4;
  float acc[4][8] = {};
#pragma unroll 4
  for (int k=0;k<Q;k++){
    float4 a4 = *(const float4*)&Xw[k][p0];
    float4 b0 = *(const float4*)&Bs[k][tx*4];
    float4 b1 = *(const float4*)&Bs[k][64 + tx*4];
    float a[4]={a4.x,a4.y,a4.z,a4.w};
    float bb[8]={b0.x,b0.y,b0.z,b0.w,b1.x,b1.y,b1.z,b1.w};
#pragma unroll
    for(int i=0;i<4;i++)
#pragma unroll
      for(int j=0;j<8;j++) acc[i][j] = fmaf(a[i], bb[j], acc[i][j]);
  }
  float* Sb = Schunk + ((size_t)bh*NC + c)*(HD*DS);
#pragma unroll
  for(int i=0;i<4;i++){
    int p = p0+i;
    *(float4*)&Sb[p*DS + tx*4]      = make_float4(acc[i][0],acc[i][1],acc[i][2],acc[i][3]);
    *(float4*)&Sb[p*DS + 64 + tx*4] = make_float4(acc[i][4],acc[i][5],acc[i][6],acc[i][7]);
  }
}

// -------- K2: inter-chunk scan (in-place: Schunk -> S_start) --------
__launch_bounds__(256)
__global__ void interchunk_kernel(float* __restrict__ S, const float* __restrict__ las){
  int blk = blockIdx.x;
  int slice = blk & 7; int bh = blk >> 3;
  size_t base = (size_t)bh*NC*(HD*DS) + slice*1024 + threadIdx.x*4;
  float4 run = make_float4(0,0,0,0);
#pragma unroll
  for (int c=0;c<NC;c++){
    float dec = __expf(las[bh*L_ + c*Q + 63]);
    float4 ch = *(float4*)(S + base + c*(HD*DS));
    *(float4*)(S + base + c*(HD*DS)) = run;
    run.x = fmaf(run.x, dec, ch.x);
    run.y = fmaf(run.y, dec, ch.y);
    run.z = fmaf(run.z, dec, ch.z);
    run.w = fmaf(run.w, dec, ch.w);
  }
}

// -------- K3: per-chunk outputs; emits y directly as split-bf16 planes --------
__launch_bounds__(256)
__global__ void chunk_out_kernel(const float* __restrict__ zx,
                                 const float* __restrict__ xbc,
                                 const float* __restrict__ dts,
                                 const float* __restrict__ las,
                                 const float* __restrict__ Sstart,
                                 const float* __restrict__ Dp,
                                 ushort* __restrict__ yS){
  __shared__ float R1[8192];
  __shared__ float R2[8192];
  int c = blockIdx.x, hh = blockIdx.y, b = blockIdx.z;
  int tid = threadIdx.x;
  int bh = b*NH + hh;
  const int tbase = bh*L_ + c*Q;
  const float Dh = Dp[hh];
  int ty = tid >> 4, tx = tid & 15;
  int t0 = ty*4, p0 = tx*4;

  for (int it = tid; it < 64*32; it += 256){
    int t = it & 63, n4 = (it >> 6) << 2;
    float4 v = *(const float4*)&xbc[(size_t)(b*L_ + c*Q + t)*CONVD + DI + DS + n4];
    R1[(n4+0)*64 + t]=v.x; R1[(n4+1)*64 + t]=v.y; R1[(n4+2)*64 + t]=v.z; R1[(n4+3)*64 + t]=v.w;
  }
  const float* Sb = Sstart + ((size_t)bh*NC + c)*(HD*DS);
  for (int it = tid; it < 64*32; it += 256){
    int p = it & 63, n4 = (it >> 6) << 2;
    float4 v = *(const float4*)&Sb[p*DS + n4];
    R2[(n4+0)*64 + p]=v.x; R2[(n4+1)*64 + p]=v.y; R2[(n4+2)*64 + p]=v.z; R2[(n4+3)*64 + p]=v.w;
  }
  __syncthreads();

  float Yi[4][4] = {};
#pragma unroll 4
  for (int k=0;k<DS;k++){
    float4 a4 = *(const float4*)&R1[k*64 + t0];
    float4 b4 = *(const float4*)&R2[k*64 + p0];
    float a[4]={a4.x,a4.y,a4.z,a4.w}, bb[4]={b4.x,b4.y,b4.z,b4.w};
#pragma unroll
    for(int i=0;i<4;i++)
#pragma unroll
      for(int j=0;j<4;j++) Yi[i][j] = fmaf(a[i], bb[j], Yi[i][j]);
  }
  __syncthreads();

  for (int it = tid; it < 64*32; it += 256){
    int s = it & 63, n4 = (it >> 6) << 2;
    float4 v = *(const float4*)&xbc[(size_t)(b*L_ + c*Q + s)*CONVD + DI + n4];
    R2[(n4+0)*64 + s]=v.x; R2[(n4+1)*64 + s]=v.y; R2[(n4+2)*64 + s]=v.z; R2[(n4+3)*64 + s]=v.w;
  }
  __syncthreads();

  float E[4][4] = {};
#pragma unroll 4
  for (int k=0;k<DS;k++){
    float4 a4 = *(const float4*)&R1[k*64 + t0];
    float4 b4 = *(const float4*)&R2[k*64 + p0];
    float a[4]={a4.x,a4.y,a4.z,a4.w}, bb[4]={b4.x,b4.y,b4.z,b4.w};
#pragma unroll
    for(int i=0;i<4;i++)
#pragma unroll
      for(int j=0;j<4;j++) E[i][j] = fmaf(a[i], bb[j], E[i][j]);
  }
  __syncthreads();

  {
    float lat[4], lass[4], dtv[4];
#pragma unroll
    for(int i=0;i<4;i++) lat[i]  = las[tbase + t0 + i];
#pragma unroll
    for(int j=0;j<4;j++){ lass[j] = las[tbase + p0 + j]; dtv[j] = dts[tbase + p0 + j]; }
#pragma unroll
    for(int i=0;i<4;i++)
#pragma unroll
      for(int j=0;j<4;j++){
        int t = t0+i, s = p0+j;
        float g = 0.f;
        if (s <= t) g = __expf(lat[i] - lass[j]) * dtv[j] * E[i][j];
        R1[t*65 + s] = g;
      }
  }
  for (int it = tid; it < 64*16; it += 256){
    int s = it >> 4, p4 = (it & 15) << 2;
    float4 v = *(const float4*)&xbc[(size_t)(b*L_ + c*Q + s)*CONVD + hh*HD + p4];
    *(float4*)&R2[s*64 + p4] = v;
  }
  __syncthreads();

  float Yv[4][4] = {};
#pragma unroll 4
  for (int k=0;k<Q;k++){
    float g[4];
#pragma unroll
    for(int i=0;i<4;i++) g[i] = R1[(t0+i)*65 + k];
    float4 x4 = *(const float4*)&R2[k*64 + p0];
    float xx[4]={x4.x,x4.y,x4.z,x4.w};
#pragma unroll
    for(int i=0;i<4;i++)
#pragma unroll
      for(int j=0;j<4;j++) Yv[i][j] = fmaf(g[i], xx[j], Yv[i][j]);
  }

#pragma unroll
  for(int i=0;i<4;i++){
    int t = t0 + i;
    float cp = __expf(las[tbase + t]);
    size_t row = (size_t)(b*L_ + c*Q + t);
    float4 z4 = *(const float4*)&zx[row*DPROJ + hh*HD + p0];
    float zz[4]={z4.x,z4.y,z4.z,z4.w};
    ushort h4[4], l4[4];
#pragma unroll
    for(int j=0;j<4;j++){
      float xv = R2[t*64 + p0 + j];
      float y = fmaf(cp, Yi[i][j], Yv[i][j]) + Dh*xv;
      float o = y * (zz[j] * sigmoidf_(zz[j]));
      h4[j] = bf16rn(o);
      l4[j] = bf16rn(o - bf2f(h4[j]));
    }
    size_t o0 = row*(size_t)(2*DI) + hh*HD + p0;
    *(uint2*)&yS[o0]      = make_uint2((uint)h4[0]|((uint)h4[1]<<16), (uint)h4[2]|((uint)h4[3]<<16));
    *(uint2*)&yS[o0 + DI] = make_uint2((uint)l4[0]|((uint)l4[1]<<16), (uint)l4[2]|((uint)l4[3]<<16));
  }
}

extern "C" void kernel_launch(void* const* d_in, const int* in_sizes, int n_in,
                              void* d_out, int out_size, void* d_ws, size_t ws_size,
                              hipStream_t stream) {
  const float* u       = (const float*)d_in[0];
  const float* W_in    = (const float*)d_in[1];
  const float* conv_w  = (const float*)d_in[2];
  const float* conv_b  = (const float*)d_in[3];
  const float* dt_bias = (const float*)d_in[4];
  const float* A_log   = (const float*)d_in[5];
  const float* D_param = (const float*)d_in[6];
  const float* W_out   = (const float*)d_in[7];
  float* out = (float*)d_out;

  float* ws = (float*)d_ws;
  float* zx     = ws;                                        // 1024*3352
  float* xbc    = zx   + (size_t)ML*DPROJ;                   // 1024*1792
  float* dts    = xbc  + (size_t)ML*CONVD;                   // 24576
  float* las    = dts  + (size_t)B_*NH*L_;                   // 24576
  float* Schunk = las  + (size_t)B_*NH*L_;                   // 48*8*8192
  ushort* uS    = (ushort*)(Schunk + (size_t)B_*NH*NC*HD*DS);
  ushort* yS    = uS;                                        // aliased (uS dead after gemm1)
  ushort* WinS  = yS + (size_t)ML*2*DI;
  ushort* WoutS = WinS;                                      // aliased (WinS dead after gemm1)

  // 1) split-convert u and W_in
  cvt_split<<<(ML*(DM/4)+255)/256, 256, 0, stream>>>(u, uS, ML, ML, DM);
  cvt_split<<<(NPAD1*(DM/4)+255)/256, 256, 0, stream>>>(W_in, WinS, DPROJ, NPAD1, DM);
  // 2) in-projection GEMM (bf16 3-segment split, swizzled+pipelined)
  {
    dim3 grid(ML/128, NPAD1/64);
    gemm3<128,64,DM><<<grid, 256, 0, stream>>>(uS, WinS, zx, DPROJ, DPROJ);
  }
  // 3) conv + SiLU (rolling window)
  {
    dim3 grid(7, NC, B_);
    conv2_kernel<<<grid, 256, 0, stream>>>(zx, conv_w, conv_b, xbc);
  }
  // 4) dt + chunk-local cumsum(dt*A)
  dt_kernel<<<B_*NH*NC, 64, 0, stream>>>(zx, dt_bias, A_log, dts, las);
  // 5) chunk states
  {
    dim3 grid(NC, NH, B_);
    chunk_state_kernel<<<grid, 256, 0, stream>>>(xbc, dts, las, Schunk);
  }
  // 6) inter-chunk scan
  interchunk_kernel<<<B_*NH*8, 256, 0, stream>>>(Schunk, las);
  // 7) chunk outputs -> yS split planes
  {
    dim3 grid(NC, NH, B_);
    chunk_out_kernel<<<grid, 256, 0, stream>>>(zx, xbc, dts, las, Schunk, D_param, yS);
  }
  // 8) split-convert W_out
  cvt_split<<<(DM*(DI/4)+255)/256, 256, 0, stream>>>(W_out, WoutS, DM, DM, DI);
  // 9) out-projection GEMM
  {
    dim3 grid(ML/64, DM/64);
    gemm3<64,64,DI><<<grid, 256, 0, stream>>>(yS, WoutS, out, DM, DM);
  }
}

// Round 7
// 200.136 us; speedup vs baseline: 2.8422x; 1.1540x over previous
//
#include <hip/hip_runtime.h>
#include <math.h>

#define B_     2
#define L_     512
#define DM     768
#define DS     128
#define HD     64
#define DI     1536
#define NH     24
#define CONVD  1792
#define DPROJ  3352
#define ML     (B_*L_)
#define Q      64
#define NC     (L_/Q)
#define NPAD1  3456

typedef __bf16 bf16x8 __attribute__((ext_vector_type(8)));
typedef float f32x4 __attribute__((ext_vector_type(4)));

__device__ __forceinline__ float sigmoidf_(float x){ return 1.f/(1.f+__expf(-x)); }
__device__ __forceinline__ ushort bf16rn(float x){
  uint u = __float_as_uint(x);
  u += 0x7fff + ((u>>16)&1);
  return (ushort)(u>>16);
}
__device__ __forceinline__ float bf2f(ushort h){ return __uint_as_float(((uint)h)<<16); }
__device__ __forceinline__ void gll16(const void* g, void* l){
  __builtin_amdgcn_global_load_lds((const __attribute__((address_space(1))) void*)g,
                                   (__attribute__((address_space(3))) void*)l, 16, 0, 0);
}

// ---- convert fp32 MxK -> bf16 planes [hi | lo] stored as Rdst x 2K (zero-pad rows) ----
__launch_bounds__(256)
__global__ void cvt_split(const float* __restrict__ src, ushort* __restrict__ dst,
                          int Rsrc, int Rdst, int K){
  int idx = blockIdx.x*256 + threadIdx.x;
  int K4 = K>>2;
  if (idx >= Rdst*K4) return;
  int r = idx / K4, c = (idx - r*K4)<<2;
  float4 v = make_float4(0,0,0,0);
  if (r < Rsrc) v = *(const float4*)&src[(size_t)r*K + c];
  float xv[4] = {v.x,v.y,v.z,v.w};
  uint hp[2], lp[2];
  ushort h[4], l[4];
#pragma unroll
  for (int j=0;j<4;j++){ h[j]=bf16rn(xv[j]); l[j]=bf16rn(xv[j]-bf2f(h[j])); }
  hp[0] = (uint)h[0] | ((uint)h[1]<<16); hp[1] = (uint)h[2] | ((uint)h[3]<<16);
  lp[0] = (uint)l[0] | ((uint)l[1]<<16); lp[1] = (uint)l[2] | ((uint)l[3]<<16);
  *(uint2*)&dst[(size_t)r*2*K + c]     = make_uint2(hp[0],hp[1]);
  *(uint2*)&dst[(size_t)r*2*K + K + c] = make_uint2(lp[0],lp[1]);
}

// ---- bf16 GEMM, fused split-planes (ah*bh + ah*bl + al*bh per K-tile) ----
// Swizzled LDS (slot ^= row&7 on source & read), 2-phase dbuf, optional split-K.
// AS: M x 2K bf16 [hi|lo]; BS: Npad x 2K bf16 [hi|lo]; C: M x Nstore fp32.
template<int BM,int BN,int K,int SPLITK,bool ATOMIC>
__launch_bounds__(256, 2)
__global__ void gemm4(const ushort* __restrict__ AS, const ushort* __restrict__ BS,
                      float* __restrict__ C, int Nvalid, int Nstore){
  constexpr int KS = K / SPLITK;
  constexpr int STEPS = KS / 64;
  constexpr int WM=BM/2, WN=BN/2, FM=WM/16, FN=WN/16;
  __shared__ ushort Ah[2][BM*64], Alo[2][BM*64], Bh[2][BN*64], Blo[2][BN*64];
  const int tid=threadIdx.x, lane=tid&63, w=tid>>6;
  const int WR=w>>1, WC=w&1;
  const int bm=blockIdx.x*BM, bn=blockIdx.y*BN;
  const int kbase = blockIdx.z*KS;
  const int lr=lane&15;
  const int srow=lane>>3;
  const int scol=(((lane&7) ^ (srow&7))*8);   // swizzled source column (ushorts)
  f32x4 acc[FM][FN] = {};

  auto stage = [&](int d, int ks){
    int k0 = kbase + ks*64;
#pragma unroll
    for (int ci=w; ci<BM/8; ci+=4){
      size_t ro = (size_t)(bm + ci*8 + srow)*(2*K);
      gll16(&AS[ro + k0 + scol],     &Ah[d][ci*512]);
      gll16(&AS[ro + K + k0 + scol], &Alo[d][ci*512]);
    }
#pragma unroll
    for (int ci=w; ci<BN/8; ci+=4){
      size_t ro = (size_t)(bn + ci*8 + srow)*(2*K);
      gll16(&BS[ro + k0 + scol],     &Bh[d][ci*512]);
      gll16(&BS[ro + K + k0 + scol], &Blo[d][ci*512]);
    }
  };

  stage(0, 0);
  __syncthreads();   // auto vmcnt(0): buf0 ready
  int cur = 0;
  for (int ks=0; ks<STEPS; ks++){
    if (ks+1 < STEPS) stage(cur^1, ks+1);   // prefetch next tile

    bf16x8 ah[2][FM], al[2][FM], bh[2][FN], bl[2][FN];
#pragma unroll
    for (int s2=0;s2<2;s2++){
      int gslot = s2*4 + (lane>>4);
#pragma unroll
      for (int i=0;i<FM;i++){
        int R = WR*WM + i*16 + lr;
        int so = (gslot ^ (lr&7))*8;
        ah[s2][i] = *(const bf16x8*)&Ah[cur][R*64 + so];
        al[s2][i] = *(const bf16x8*)&Alo[cur][R*64 + so];
      }
#pragma unroll
      for (int j=0;j<FN;j++){
        int R = WC*WN + j*16 + lr;
        int so = (gslot ^ (lr&7))*8;
        bh[s2][j] = *(const bf16x8*)&Bh[cur][R*64 + so];
        bl[s2][j] = *(const bf16x8*)&Blo[cur][R*64 + so];
      }
    }
#pragma unroll
    for (int s2=0;s2<2;s2++)
#pragma unroll
      for (int i=0;i<FM;i++)
#pragma unroll
        for (int j=0;j<FN;j++){
          acc[i][j] = __builtin_amdgcn_mfma_f32_16x16x32_bf16(ah[s2][i], bh[s2][j], acc[i][j], 0,0,0);
          acc[i][j] = __builtin_amdgcn_mfma_f32_16x16x32_bf16(ah[s2][i], bl[s2][j], acc[i][j], 0,0,0);
          acc[i][j] = __builtin_amdgcn_mfma_f32_16x16x32_bf16(al[s2][i], bh[s2][j], acc[i][j], 0,0,0);
        }

    __syncthreads();  // drains vmcnt(0) (next tile landed); safe to swap
    cur ^= 1;
  }

#pragma unroll
  for (int i=0;i<FM;i++)
#pragma unroll
    for (int j=0;j<FN;j++){
      int n = bn + WC*WN + j*16 + lr;
      if (n < Nvalid){
#pragma unroll
        for (int e=0;e<4;e++){
          int m = bm + WR*WM + i*16 + (lane>>4)*4 + e;
          if (ATOMIC) atomicAdd(&C[(size_t)m*Nstore + n], acc[i][j][e]);
          else        C[(size_t)m*Nstore + n] = acc[i][j][e];
        }
      }
    }
}

// ---- rolling-window causal conv (width 4) + SiLU ----
__launch_bounds__(256)
__global__ void conv2_kernel(const float* __restrict__ zx,
                             const float* __restrict__ cw,
                             const float* __restrict__ cb,
                             float* __restrict__ xbc){
  int g = blockIdx.x;          // 0..6 channel group of 256
  int c = blockIdx.y;          // chunk
  int b = blockIdx.z;
  int ch = g*256 + threadIdx.x;
  const float* src = zx + (size_t)(b*L_ + c*Q)*DPROJ + DI + ch;
  float* dst = xbc + (size_t)(b*L_ + c*Q)*CONVD + ch;
  float w0=cw[ch*4],w1=cw[ch*4+1],w2=cw[ch*4+2],w3=cw[ch*4+3],bias=cb[ch];
  float x0=0.f,x1=0.f,x2=0.f;
  if (c > 0){
    x0 = *(src - 3*DPROJ);
    x1 = *(src - 2*DPROJ);
    x2 = *(src - 1*DPROJ);
  }
#pragma unroll 4
  for (int tt=0; tt<Q; tt++){
    float xt = src[(size_t)tt*DPROJ];
    float a = bias;
    a = fmaf(w3, xt, a); a = fmaf(w2, x2, a); a = fmaf(w1, x1, a); a = fmaf(w0, x0, a);
    dst[(size_t)tt*CONVD] = a * sigmoidf_(a);
    x0 = x1; x1 = x2; x2 = xt;
  }
}

// -------- dt = softplus(raw+bias); la = chunk-local cumsum(dt*A) --------
__launch_bounds__(64)
__global__ void dt_kernel(const float* __restrict__ zx,
                          const float* __restrict__ dt_bias,
                          const float* __restrict__ A_log,
                          float* __restrict__ dts, float* __restrict__ las){
  int blk = blockIdx.x;             // b*NH*NC + h*NC + c
  int c = blk % NC; int h = (blk/NC)%NH; int b = blk/(NC*NH);
  int lane = threadIdx.x;
  int t = c*Q + lane;
  float raw = zx[(size_t)(b*L_+t)*DPROJ + DI + CONVD + h] + dt_bias[h];
  float dtv = raw > 20.f ? raw : log1pf(__expf(raw));
  float A = -__expf(A_log[h]);
  float la = dtv * A;
#pragma unroll
  for (int off=1; off<64; off<<=1){
    float v = __shfl_up(la, off);
    if (lane >= off) la += v;
  }
  int idx = (b*NH+h)*L_ + t;
  dts[idx] = dtv;
  las[idx] = la;
}

// -------- K1: per-chunk state  S_chunk[p][n] = sum_s w[s] x[s][p] B[s][n] --------
__launch_bounds__(256)
__global__ void chunk_state_kernel(const float* __restrict__ xbc,
                                   const float* __restrict__ dts,
                                   const float* __restrict__ las,
                                   float* __restrict__ Schunk){
  __shared__ float Xw[Q][68];
  __shared__ float Bs[Q][132];
  int c = blockIdx.x, h = blockIdx.y, b = blockIdx.z;
  int tid = threadIdx.x;
  int bh = b*NH + h;
  const int tbase = bh*L_ + c*Q;
  float la63 = las[tbase + 63];

  for (int it = tid; it < Q*16; it += 256){
    int s = it >> 4, p4 = (it & 15) << 2;
    float4 v = *(const float4*)&xbc[(size_t)(b*L_ + c*Q + s)*CONVD + h*HD + p4];
    float w = __expf(la63 - las[tbase + s]) * dts[tbase + s];
    Xw[s][p4+0]=v.x*w; Xw[s][p4+1]=v.y*w; Xw[s][p4+2]=v.z*w; Xw[s][p4+3]=v.w*w;
  }
  for (int it = tid; it < Q*32; it += 256){
    int s = it >> 5, n4 = (it & 31) << 2;
    float4 v = *(const float4*)&xbc[(size_t)(b*L_ + c*Q + s)*CONVD + DI + n4];
    Bs[s][n4+0]=v.x; Bs[s][n4+1]=v.y; Bs[s][n4+2]=v.z; Bs[s][n4+3]=v.w;
  }
  __syncthreads();

  int ty = tid >> 4, tx = tid & 15;
  int p0 = ty*4;
  float acc[4][8] = {};
#pragma unroll 4
  for (int k=0;k<Q;k++){
    float4 a4 = *(const float4*)&Xw[k][p0];
    float4 b0 = *(const float4*)&Bs[k][tx*4];
    float4 b1 = *(const float4*)&Bs[k][64 + tx*4];
    float a[4]={a4.x,a4.y,a4.z,a4.w};
    float bb[8]={b0.x,b0.y,b0.z,b0.w,b1.x,b1.y,b1.z,b1.w};
#pragma unroll
    for(int i=0;i<4;i++)
#pragma unroll
      for(int j=0;j<8;j++) acc[i][j] = fmaf(a[i], bb[j], acc[i][j]);
  }
  float* Sb = Schunk + ((size_t)bh*NC + c)*(HD*DS);
#pragma unroll
  for(int i=0;i<4;i++){
    int p = p0+i;
    *(float4*)&Sb[p*DS + tx*4]      = make_float4(acc[i][0],acc[i][1],acc[i][2],acc[i][3]);
    *(float4*)&Sb[p*DS + 64 + tx*4] = make_float4(acc[i][4],acc[i][5],acc[i][6],acc[i][7]);
  }
}

// -------- K2: inter-chunk scan (in-place: Schunk -> S_start) --------
__launch_bounds__(256)
__global__ void interchunk_kernel(float* __restrict__ S, const float* __restrict__ las){
  int blk = blockIdx.x;
  int slice = blk & 7; int bh = blk >> 3;
  size_t base = (size_t)bh*NC*(HD*DS) + slice*1024 + threadIdx.x*4;
  float4 run = make_float4(0,0,0,0);
#pragma unroll
  for (int c=0;c<NC;c++){
    float dec = __expf(las[bh*L_ + c*Q + 63]);
    float4 ch = *(float4*)(S + base + c*(HD*DS));
    *(float4*)(S + base + c*(HD*DS)) = run;
    run.x = fmaf(run.x, dec, ch.x);
    run.y = fmaf(run.y, dec, ch.y);
    run.z = fmaf(run.z, dec, ch.z);
    run.w = fmaf(run.w, dec, ch.w);
  }
}

// -------- K3: per-chunk outputs; emits y directly as split-bf16 planes --------
__launch_bounds__(256)
__global__ void chunk_out_kernel(const float* __restrict__ zx,
                                 const float* __restrict__ xbc,
                                 const float* __restrict__ dts,
                                 const float* __restrict__ las,
                                 const float* __restrict__ Sstart,
                                 const float* __restrict__ Dp,
                                 ushort* __restrict__ yS){
  __shared__ float R1[8192];
  __shared__ float R2[8192];
  int c = blockIdx.x, hh = blockIdx.y, b = blockIdx.z;
  int tid = threadIdx.x;
  int bh = b*NH + hh;
  const int tbase = bh*L_ + c*Q;
  const float Dh = Dp[hh];
  int ty = tid >> 4, tx = tid & 15;
  int t0 = ty*4, p0 = tx*4;

  for (int it = tid; it < 64*32; it += 256){
    int t = it & 63, n4 = (it >> 6) << 2;
    float4 v = *(const float4*)&xbc[(size_t)(b*L_ + c*Q + t)*CONVD + DI + DS + n4];
    R1[(n4+0)*64 + t]=v.x; R1[(n4+1)*64 + t]=v.y; R1[(n4+2)*64 + t]=v.z; R1[(n4+3)*64 + t]=v.w;
  }
  const float* Sb = Sstart + ((size_t)bh*NC + c)*(HD*DS);
  for (int it = tid; it < 64*32; it += 256){
    int p = it & 63, n4 = (it >> 6) << 2;
    float4 v = *(const float4*)&Sb[p*DS + n4];
    R2[(n4+0)*64 + p]=v.x; R2[(n4+1)*64 + p]=v.y; R2[(n4+2)*64 + p]=v.z; R2[(n4+3)*64 + p]=v.w;
  }
  __syncthreads();

  float Yi[4][4] = {};
#pragma unroll 4
  for (int k=0;k<DS;k++){
    float4 a4 = *(const float4*)&R1[k*64 + t0];
    float4 b4 = *(const float4*)&R2[k*64 + p0];
    float a[4]={a4.x,a4.y,a4.z,a4.w}, bb[4]={b4.x,b4.y,b4.z,b4.w};
#pragma unroll
    for(int i=0;i<4;i++)
#pragma unroll
      for(int j=0;j<4;j++) Yi[i][j] = fmaf(a[i], bb[j], Yi[i][j]);
  }
  __syncthreads();

  for (int it = tid; it < 64*32; it += 256){
    int s = it & 63, n4 = (it >> 6) << 2;
    float4 v = *(const float4*)&xbc[(size_t)(b*L_ + c*Q + s)*CONVD + DI + n4];
    R2[(n4+0)*64 + s]=v.x; R2[(n4+1)*64 + s]=v.y; R2[(n4+2)*64 + s]=v.z; R2[(n4+3)*64 + s]=v.w;
  }
  __syncthreads();

  float E[4][4] = {};
#pragma unroll 4
  for (int k=0;k<DS;k++){
    float4 a4 = *(const float4*)&R1[k*64 + t0];
    float4 b4 = *(const float4*)&R2[k*64 + p0];
    float a[4]={a4.x,a4.y,a4.z,a4.w}, bb[4]={b4.x,b4.y,b4.z,b4.w};
#pragma unroll
    for(int i=0;i<4;i++)
#pragma unroll
      for(int j=0;j<4;j++) E[i][j] = fmaf(a[i], bb[j], E[i][j]);
  }
  __syncthreads();

  {
    float lat[4], lass[4], dtv[4];
#pragma unroll
    for(int i=0;i<4;i++) lat[i]  = las[tbase + t0 + i];
#pragma unroll
    for(int j=0;j<4;j++){ lass[j] = las[tbase + p0 + j]; dtv[j] = dts[tbase + p0 + j]; }
#pragma unroll
    for(int i=0;i<4;i++)
#pragma unroll
      for(int j=0;j<4;j++){
        int t = t0+i, s = p0+j;
        float g = 0.f;
        if (s <= t) g = __expf(lat[i] - lass[j]) * dtv[j] * E[i][j];
        R1[t*65 + s] = g;
      }
  }
  for (int it = tid; it < 64*16; it += 256){
    int s = it >> 4, p4 = (it & 15) << 2;
    float4 v = *(const float4*)&xbc[(size_t)(b*L_ + c*Q + s)*CONVD + hh*HD + p4];
    *(float4*)&R2[s*64 + p4] = v;
  }
  __syncthreads();

  float Yv[4][4] = {};
#pragma unroll 4
  for (int k=0;k<Q;k++){
    float g[4];
#pragma unroll
    for(int i=0;i<4;i++) g[i] = R1[(t0+i)*65 + k];
    float4 x4 = *(const float4*)&R2[k*64 + p0];
    float xx[4]={x4.x,x4.y,x4.z,x4.w};
#pragma unroll
    for(int i=0;i<4;i++)
#pragma unroll
      for(int j=0;j<4;j++) Yv[i][j] = fmaf(g[i], xx[j], Yv[i][j]);
  }

#pragma unroll
  for(int i=0;i<4;i++){
    int t = t0 + i;
    float cp = __expf(las[tbase + t]);
    size_t row = (size_t)(b*L_ + c*Q + t);
    float4 z4 = *(const float4*)&zx[row*DPROJ + hh*HD + p0];
    float zz[4]={z4.x,z4.y,z4.z,z4.w};
    ushort h4[4], l4[4];
#pragma unroll
    for(int j=0;j<4;j++){
      float xv = R2[t*64 + p0 + j];
      float y = fmaf(cp, Yi[i][j], Yv[i][j]) + Dh*xv;
      float o = y * (zz[j] * sigmoidf_(zz[j]));
      h4[j] = bf16rn(o);
      l4[j] = bf16rn(o - bf2f(h4[j]));
    }
    size_t o0 = row*(size_t)(2*DI) + hh*HD + p0;
    *(uint2*)&yS[o0]      = make_uint2((uint)h4[0]|((uint)h4[1]<<16), (uint)h4[2]|((uint)h4[3]<<16));
    *(uint2*)&yS[o0 + DI] = make_uint2((uint)l4[0]|((uint)l4[1]<<16), (uint)l4[2]|((uint)l4[3]<<16));
  }
}

extern "C" void kernel_launch(void* const* d_in, const int* in_sizes, int n_in,
                              void* d_out, int out_size, void* d_ws, size_t ws_size,
                              hipStream_t stream) {
  const float* u       = (const float*)d_in[0];
  const float* W_in    = (const float*)d_in[1];
  const float* conv_w  = (const float*)d_in[2];
  const float* conv_b  = (const float*)d_in[3];
  const float* dt_bias = (const float*)d_in[4];
  const float* A_log   = (const float*)d_in[5];
  const float* D_param = (const float*)d_in[6];
  const float* W_out   = (const float*)d_in[7];
  float* out = (float*)d_out;

  float* ws = (float*)d_ws;
  float* zx     = ws;                                        // 1024*3352
  float* xbc    = zx   + (size_t)ML*DPROJ;                   // 1024*1792
  float* dts    = xbc  + (size_t)ML*CONVD;                   // 24576
  float* las    = dts  + (size_t)B_*NH*L_;                   // 24576
  float* Schunk = las  + (size_t)B_*NH*L_;                   // 48*8*8192
  ushort* uS    = (ushort*)(Schunk + (size_t)B_*NH*NC*HD*DS);
  ushort* yS    = uS;                                        // aliased (uS dead after gemm1)
  ushort* WinS  = yS + (size_t)ML*2*DI;
  ushort* WoutS = WinS;                                      // aliased (WinS dead after gemm1)

  // 1) split-convert u and W_in
  cvt_split<<<(ML*(DM/4)+255)/256, 256, 0, stream>>>(u, uS, ML, ML, DM);
  cvt_split<<<(NPAD1*(DM/4)+255)/256, 256, 0, stream>>>(W_in, WinS, DPROJ, NPAD1, DM);
  // 2) in-projection GEMM (fused split-planes)
  {
    dim3 grid(ML/64, NPAD1/64, 1);
    gemm4<64,64,DM,1,false><<<grid, 256, 0, stream>>>(uS, WinS, zx, DPROJ, DPROJ);
  }
  // 3) conv + SiLU (rolling window)
  {
    dim3 grid(7, NC, B_);
    conv2_kernel<<<grid, 256, 0, stream>>>(zx, conv_w, conv_b, xbc);
  }
  // 4) dt + chunk-local cumsum(dt*A)
  dt_kernel<<<B_*NH*NC, 64, 0, stream>>>(zx, dt_bias, A_log, dts, las);
  // 5) chunk states
  {
    dim3 grid(NC, NH, B_);
    chunk_state_kernel<<<grid, 256, 0, stream>>>(xbc, dts, las, Schunk);
  }
  // 6) inter-chunk scan
  interchunk_kernel<<<B_*NH*8, 256, 0, stream>>>(Schunk, las);
  // 7) chunk outputs -> yS split planes
  {
    dim3 grid(NC, NH, B_);
    chunk_out_kernel<<<grid, 256, 0, stream>>>(zx, xbc, dts, las, Schunk, D_param, yS);
  }
  // 8) split-convert W_out
  cvt_split<<<(DM*(DI/4)+255)/256, 256, 0, stream>>>(W_out, WoutS, DM, DM, DI);
  // 9) out-projection GEMM: zero out, then split-K=4 with atomic accumulate
  hipMemsetAsync(d_out, 0, (size_t)out_size*sizeof(float), stream);
  {
    dim3 grid(ML/64, DM/64, 4);
    gemm4<64,64,DI,4,true><<<grid, 256, 0, stream>>>(yS, WoutS, out, DM, DM);
  }
}

// Round 11
// 183.433 us; speedup vs baseline: 3.1010x; 1.0911x over previous
//
#include <hip/hip_runtime.h>
#include <math.h>

#define B_     2
#define L_     512
#define DM     768
#define DS     128
#define HD     64
#define DI     1536
#define NH     24
#define CONVD  1792
#define DPROJ  3352
#define ML     (B_*L_)
#define Q      64
#define NC     (L_/Q)
#define NPAD1  3456

typedef __bf16 bf16x8 __attribute__((ext_vector_type(8)));
typedef float f32x4 __attribute__((ext_vector_type(4)));

__device__ __forceinline__ float sigmoidf_(float x){ return 1.f/(1.f+__expf(-x)); }
__device__ __forceinline__ ushort bf16rn(float x){
  uint u = __float_as_uint(x);
  u += 0x7fff + ((u>>16)&1);
  return (ushort)(u>>16);
}
__device__ __forceinline__ float bf2f(ushort h){ return __uint_as_float(((uint)h)<<16); }
__device__ __forceinline__ void gll16(const void* g, void* l){
  __builtin_amdgcn_global_load_lds((const __attribute__((address_space(1))) void*)g,
                                   (__attribute__((address_space(3))) void*)l, 16, 0, 0);
}

// ---- convert fp32 MxK -> bf16 planes [hi | lo] stored as Rdst x 2K (zero-pad rows) ----
__launch_bounds__(256)
__global__ void cvt_split(const float* __restrict__ src, ushort* __restrict__ dst,
                          int Rsrc, int Rdst, int K){
  int idx = blockIdx.x*256 + threadIdx.x;
  int K4 = K>>2;
  if (idx >= Rdst*K4) return;
  int r = idx / K4, c = (idx - r*K4)<<2;
  float4 v = make_float4(0,0,0,0);
  if (r < Rsrc) v = *(const float4*)&src[(size_t)r*K + c];
  float xv[4] = {v.x,v.y,v.z,v.w};
  uint hp[2], lp[2];
  ushort h[4], l[4];
#pragma unroll
  for (int j=0;j<4;j++){ h[j]=bf16rn(xv[j]); l[j]=bf16rn(xv[j]-bf2f(h[j])); }
  hp[0] = (uint)h[0] | ((uint)h[1]<<16); hp[1] = (uint)h[2] | ((uint)h[3]<<16);
  lp[0] = (uint)l[0] | ((uint)l[1]<<16); lp[1] = (uint)l[2] | ((uint)l[3]<<16);
  *(uint2*)&dst[(size_t)r*2*K + c]     = make_uint2(hp[0],hp[1]);
  *(uint2*)&dst[(size_t)r*2*K + K + c] = make_uint2(lp[0],lp[1]);
}

// ---- bf16 GEMM, fused split-planes (ah*bh + ah*bl + al*bh per K-tile) ----
template<int BM,int BN,int K,int SPLITK,bool ATOMIC>
__launch_bounds__(256, 2)
__global__ void gemm4(const ushort* __restrict__ AS, const ushort* __restrict__ BS,
                      float* __restrict__ C, int Nvalid, int Nstore){
  constexpr int KS = K / SPLITK;
  constexpr int STEPS = KS / 64;
  constexpr int WM=BM/2, WN=BN/2, FM=WM/16, FN=WN/16;
  __shared__ ushort Ah[2][BM*64], Alo[2][BM*64], Bh[2][BN*64], Blo[2][BN*64];
  const int tid=threadIdx.x, lane=tid&63, w=tid>>6;
  const int WR=w>>1, WC=w&1;
  const int bm=blockIdx.x*BM, bn=blockIdx.y*BN;
  const int kbase = blockIdx.z*KS;
  const int lr=lane&15;
  const int srow=lane>>3;
  const int scol=(((lane&7) ^ (srow&7))*8);
  f32x4 acc[FM][FN] = {};

  auto stage = [&](int d, int ks){
    int k0 = kbase + ks*64;
#pragma unroll
    for (int ci=w; ci<BM/8; ci+=4){
      size_t ro = (size_t)(bm + ci*8 + srow)*(2*K);
      gll16(&AS[ro + k0 + scol],     &Ah[d][ci*512]);
      gll16(&AS[ro + K + k0 + scol], &Alo[d][ci*512]);
    }
#pragma unroll
    for (int ci=w; ci<BN/8; ci+=4){
      size_t ro = (size_t)(bn + ci*8 + srow)*(2*K);
      gll16(&BS[ro + k0 + scol],     &Bh[d][ci*512]);
      gll16(&BS[ro + K + k0 + scol], &Blo[d][ci*512]);
    }
  };

  stage(0, 0);
  __syncthreads();
  int cur = 0;
  for (int ks=0; ks<STEPS; ks++){
    if (ks+1 < STEPS) stage(cur^1, ks+1);

    bf16x8 ah[2][FM], al[2][FM], bh[2][FN], bl[2][FN];
#pragma unroll
    for (int s2=0;s2<2;s2++){
      int gslot = s2*4 + (lane>>4);
#pragma unroll
      for (int i=0;i<FM;i++){
        int R = WR*WM + i*16 + lr;
        int so = (gslot ^ (lr&7))*8;
        ah[s2][i] = *(const bf16x8*)&Ah[cur][R*64 + so];
        al[s2][i] = *(const bf16x8*)&Alo[cur][R*64 + so];
      }
#pragma unroll
      for (int j=0;j<FN;j++){
        int R = WC*WN + j*16 + lr;
        int so = (gslot ^ (lr&7))*8;
        bh[s2][j] = *(const bf16x8*)&Bh[cur][R*64 + so];
        bl[s2][j] = *(const bf16x8*)&Blo[cur][R*64 + so];
      }
    }
#pragma unroll
    for (int s2=0;s2<2;s2++)
#pragma unroll
      for (int i=0;i<FM;i++)
#pragma unroll
        for (int j=0;j<FN;j++){
          acc[i][j] = __builtin_amdgcn_mfma_f32_16x16x32_bf16(ah[s2][i], bh[s2][j], acc[i][j], 0,0,0);
          acc[i][j] = __builtin_amdgcn_mfma_f32_16x16x32_bf16(ah[s2][i], bl[s2][j], acc[i][j], 0,0,0);
          acc[i][j] = __builtin_amdgcn_mfma_f32_16x16x32_bf16(al[s2][i], bh[s2][j], acc[i][j], 0,0,0);
        }

    __syncthreads();
    cur ^= 1;
  }

#pragma unroll
  for (int i=0;i<FM;i++)
#pragma unroll
    for (int j=0;j<FN;j++){
      int n = bn + WC*WN + j*16 + lr;
      if (n < Nvalid){
#pragma unroll
        for (int e=0;e<4;e++){
          int m = bm + WR*WM + i*16 + (lane>>4)*4 + e;
          if (ATOMIC) atomicAdd(&C[(size_t)m*Nstore + n], acc[i][j][e]);
          else        C[(size_t)m*Nstore + n] = acc[i][j][e];
        }
      }
    }
}

// ---- rolling-window causal conv (width 4) + SiLU; 32 timesteps per block ----
__launch_bounds__(256)
__global__ void conv2_kernel(const float* __restrict__ zx,
                             const float* __restrict__ cw,
                             const float* __restrict__ cb,
                             float* __restrict__ xbc){
  int g = blockIdx.x;          // 0..6 channel group of 256
  int c2 = blockIdx.y;         // half-chunk (32 t)
  int b = blockIdx.z;
  int t0g = c2*32;
  int ch = g*256 + threadIdx.x;
  const float* src = zx + (size_t)(b*L_ + t0g)*DPROJ + DI + ch;
  float* dst = xbc + (size_t)(b*L_ + t0g)*CONVD + ch;
  float w0=cw[ch*4],w1=cw[ch*4+1],w2=cw[ch*4+2],w3=cw[ch*4+3],bias=cb[ch];
  float x0=0.f,x1=0.f,x2=0.f;
  if (t0g > 0){
    x0 = *(src - 3*DPROJ);
    x1 = *(src - 2*DPROJ);
    x2 = *(src - 1*DPROJ);
  }
#pragma unroll 4
  for (int tt=0; tt<32; tt++){
    float xt = src[(size_t)tt*DPROJ];
    float a = bias;
    a = fmaf(w3, xt, a); a = fmaf(w2, x2, a); a = fmaf(w1, x1, a); a = fmaf(w0, x0, a);
    dst[(size_t)tt*CONVD] = a * sigmoidf_(a);
    x0 = x1; x1 = x2; x2 = xt;
  }
}

// -------- dt = softplus(raw+bias); la = chunk-local cumsum(dt*A) --------
__launch_bounds__(64)
__global__ void dt_kernel(const float* __restrict__ zx,
                          const float* __restrict__ dt_bias,
                          const float* __restrict__ A_log,
                          float* __restrict__ dts, float* __restrict__ las){
  int blk = blockIdx.x;
  int c = blk % NC; int h = (blk/NC)%NH; int b = blk/(NC*NH);
  int lane = threadIdx.x;
  int t = c*Q + lane;
  float raw = zx[(size_t)(b*L_+t)*DPROJ + DI + CONVD + h] + dt_bias[h];
  float dtv = raw > 20.f ? raw : log1pf(__expf(raw));
  float A = -__expf(A_log[h]);
  float la = dtv * A;
#pragma unroll
  for (int off=1; off<64; off<<=1){
    float v = __shfl_up(la, off);
    if (lane >= off) la += v;
  }
  int idx = (b*NH+h)*L_ + t;
  dts[idx] = dtv;
  las[idx] = la;
}

// -------- K1: per-chunk state  S_chunk[p][n] = sum_s w[s] x[s][p] B[s][n] --------
__launch_bounds__(256)
__global__ void chunk_state_kernel(const float* __restrict__ xbc,
                                   const float* __restrict__ dts,
                                   const float* __restrict__ las,
                                   float* __restrict__ Schunk){
  __shared__ float Xw[Q][68];
  __shared__ float Bs[Q][132];
  int c = blockIdx.x, h = blockIdx.y, b = blockIdx.z;
  int tid = threadIdx.x;
  int bh = b*NH + h;
  const int tbase = bh*L_ + c*Q;
  float la63 = las[tbase + 63];

  for (int it = tid; it < Q*16; it += 256){
    int s = it >> 4, p4 = (it & 15) << 2;
    float4 v = *(const float4*)&xbc[(size_t)(b*L_ + c*Q + s)*CONVD + h*HD + p4];
    float w = __expf(la63 - las[tbase + s]) * dts[tbase + s];
    Xw[s][p4+0]=v.x*w; Xw[s][p4+1]=v.y*w; Xw[s][p4+2]=v.z*w; Xw[s][p4+3]=v.w*w;
  }
  for (int it = tid; it < Q*32; it += 256){
    int s = it >> 5, n4 = (it & 31) << 2;
    float4 v = *(const float4*)&xbc[(size_t)(b*L_ + c*Q + s)*CONVD + DI + n4];
    Bs[s][n4+0]=v.x; Bs[s][n4+1]=v.y; Bs[s][n4+2]=v.z; Bs[s][n4+3]=v.w;
  }
  __syncthreads();

  int ty = tid >> 4, tx = tid & 15;
  int p0 = ty*4;
  float acc[4][8] = {};
#pragma unroll 4
  for (int k=0;k<Q;k++){
    float4 a4 = *(const float4*)&Xw[k][p0];
    float4 b0 = *(const float4*)&Bs[k][tx*4];
    float4 b1 = *(const float4*)&Bs[k][64 + tx*4];
    float a[4]={a4.x,a4.y,a4.z,a4.w};
    float bb[8]={b0.x,b0.y,b0.z,b0.w,b1.x,b1.y,b1.z,b1.w};
#pragma unroll
    for(int i=0;i<4;i++)
#pragma unroll
      for(int j=0;j<8;j++) acc[i][j] = fmaf(a[i], bb[j], acc[i][j]);
  }
  float* Sb = Schunk + ((size_t)bh*NC + c)*(HD*DS);
#pragma unroll
  for(int i=0;i<4;i++){
    int p = p0+i;
    *(float4*)&Sb[p*DS + tx*4]      = make_float4(acc[i][0],acc[i][1],acc[i][2],acc[i][3]);
    *(float4*)&Sb[p*DS + 64 + tx*4] = make_float4(acc[i][4],acc[i][5],acc[i][6],acc[i][7]);
  }
}

// -------- K2: inter-chunk scan (in-place: Schunk -> S_start) --------
__launch_bounds__(256)
__global__ void interchunk_kernel(float* __restrict__ S, const float* __restrict__ las){
  int blk = blockIdx.x;
  int slice = blk & 7; int bh = blk >> 3;
  size_t base = (size_t)bh*NC*(HD*DS) + slice*1024 + threadIdx.x*4;
  float4 run = make_float4(0,0,0,0);
#pragma unroll
  for (int c=0;c<NC;c++){
    float dec = __expf(las[bh*L_ + c*Q + 63]);
    float4 ch = *(float4*)(S + base + c*(HD*DS));
    *(float4*)(S + base + c*(HD*DS)) = run;
    run.x = fmaf(run.x, dec, ch.x);
    run.y = fmaf(run.y, dec, ch.y);
    run.z = fmaf(run.z, dec, ch.z);
    run.w = fmaf(run.w, dec, ch.w);
  }
}

// -------- K3 (MFMA): per-chunk outputs via split-bf16 matrix cores --------
// Yinter = C.S^T (K=n contiguous), E = C.B^T (K=n contiguous), G=mask*exp*dt*E,
// Yintra = G.X via transposed-X staging. Swizzle slot^=(row&7) on all tiles.
__launch_bounds__(512)
__global__ void chunk_out_mfma(const float* __restrict__ zx,
                               const float* __restrict__ xbc,
                               const float* __restrict__ dts,
                               const float* __restrict__ las,
                               const float* __restrict__ Sstart,
                               const float* __restrict__ Dp,
                               ushort* __restrict__ yS){
  // ushort offsets into the 96KB LDS pool
  constexpr int OC_HI = 0,      OC_LO = 8192;    // C~  64x128
  constexpr int OP_HI = 16384,  OP_LO = 24576;   // S~ then B~  64x128
  constexpr int OX_HI = 32768,  OX_LO = 36864;   // XT~ 64x64 ([p][s])
  constexpr int OG_HI = 40960,  OG_LO = 45056;   // G~  64x64 ([t][s]) -> reused as Yf f32
  __shared__ ushort LDSU[49152];
  __shared__ float La[64], Dt[64];

  int c = blockIdx.x, hh = blockIdx.y, b = blockIdx.z;
  int tid = threadIdx.x;
  int bh = b*NH + hh;
  const int tbase = bh*L_ + c*Q;
  const float Dh = Dp[hh];
  const int lane = tid & 63, w = tid >> 6;
  const int wr = w >> 2, wc = w & 3;      // 2 x 4 wave grid over 64t x 64p
  const int lr = lane & 15, lk = lane >> 4;

  // ---- phase 1 staging: C~, S~, XT~, La, Dt ----
  for (int it = tid; it < 64*32; it += 512){   // C: 64 rows x 32 float4
    int t = it >> 5, n4 = (it & 31) << 2;
    float4 v = *(const float4*)&xbc[(size_t)(b*L_ + c*Q + t)*CONVD + DI + DS + n4];
    float xv[4] = {v.x,v.y,v.z,v.w};
    ushort h[4], l[4];
#pragma unroll
    for (int j=0;j<4;j++){ h[j]=bf16rn(xv[j]); l[j]=bf16rn(xv[j]-bf2f(h[j])); }
    int idx = t*128 + (((n4>>3) ^ (t&7))<<3) + (n4&7);
    *(uint2*)&LDSU[OC_HI + idx] = make_uint2((uint)h[0]|((uint)h[1]<<16), (uint)h[2]|((uint)h[3]<<16));
    *(uint2*)&LDSU[OC_LO + idx] = make_uint2((uint)l[0]|((uint)l[1]<<16), (uint)l[2]|((uint)l[3]<<16));
  }
  const float* Sb = Sstart + ((size_t)bh*NC + c)*(HD*DS);
  for (int it = tid; it < 64*32; it += 512){   // S: 64 rows x 32 float4
    int p = it >> 5, n4 = (it & 31) << 2;
    float4 v = *(const float4*)&Sb[p*DS + n4];
    float xv[4] = {v.x,v.y,v.z,v.w};
    ushort h[4], l[4];
#pragma unroll
    for (int j=0;j<4;j++){ h[j]=bf16rn(xv[j]); l[j]=bf16rn(xv[j]-bf2f(h[j])); }
    int idx = p*128 + (((n4>>3) ^ (p&7))<<3) + (n4&7);
    *(uint2*)&LDSU[OP_HI + idx] = make_uint2((uint)h[0]|((uint)h[1]<<16), (uint)h[2]|((uint)h[3]<<16));
    *(uint2*)&LDSU[OP_LO + idx] = make_uint2((uint)l[0]|((uint)l[1]<<16), (uint)l[2]|((uint)l[3]<<16));
  }
  for (int it = tid; it < 64*16; it += 512){   // X transposed: XT[p][s]
    int s = it >> 4, p4 = (it & 15) << 2;
    float4 v = *(const float4*)&xbc[(size_t)(b*L_ + c*Q + s)*CONVD + hh*HD + p4];
    float xv[4] = {v.x,v.y,v.z,v.w};
#pragma unroll
    for (int j=0;j<4;j++){
      int p = p4 + j;
      ushort h = bf16rn(xv[j]);
      ushort l = bf16rn(xv[j] - bf2f(h));
      int idx = p*64 + (((s>>3) ^ (p&7))<<3) + (s&7);
      LDSU[OX_HI + idx] = h; LDSU[OX_LO + idx] = l;
    }
  }
  if (tid < 64){ La[tid] = las[tbase + tid]; Dt[tid] = dts[tbase + tid]; }
  __syncthreads();

  f32x4 yi[2] = {}, ev[2] = {}, yv[2] = {};

  // ---- Yinter: A=C~[t][n], B=S~[p][n], K=128 ----
#pragma unroll
  for (int ks=0; ks<4; ks++){
    bf16x8 ah[2], al[2], bh, bl;
#pragma unroll
    for (int fi=0; fi<2; fi++){
      int R = wr*32 + fi*16 + lr;
      int idx = R*128 + (((ks*4 + lk) ^ (R&7))<<3);
      ah[fi] = *(const bf16x8*)&LDSU[OC_HI + idx];
      al[fi] = *(const bf16x8*)&LDSU[OC_LO + idx];
    }
    { int Rb = wc*16 + lr;
      int idx = Rb*128 + (((ks*4 + lk) ^ (Rb&7))<<3);
      bh = *(const bf16x8*)&LDSU[OP_HI + idx];
      bl = *(const bf16x8*)&LDSU[OP_LO + idx]; }
#pragma unroll
    for (int fi=0; fi<2; fi++){
      yi[fi] = __builtin_amdgcn_mfma_f32_16x16x32_bf16(ah[fi], bh, yi[fi], 0,0,0);
      yi[fi] = __builtin_amdgcn_mfma_f32_16x16x32_bf16(ah[fi], bl, yi[fi], 0,0,0);
      yi[fi] = __builtin_amdgcn_mfma_f32_16x16x32_bf16(al[fi], bh, yi[fi], 0,0,0);
    }
  }
  __syncthreads();

  // ---- restage P~ <- B-tile ----
  for (int it = tid; it < 64*32; it += 512){
    int s = it >> 5, n4 = (it & 31) << 2;
    float4 v = *(const float4*)&xbc[(size_t)(b*L_ + c*Q + s)*CONVD + DI + n4];
    float xv[4] = {v.x,v.y,v.z,v.w};
    ushort h[4], l[4];
#pragma unroll
    for (int j=0;j<4;j++){ h[j]=bf16rn(xv[j]); l[j]=bf16rn(xv[j]-bf2f(h[j])); }
    int idx = s*128 + (((n4>>3) ^ (s&7))<<3) + (n4&7);
    *(uint2*)&LDSU[OP_HI + idx] = make_uint2((uint)h[0]|((uint)h[1]<<16), (uint)h[2]|((uint)h[3]<<16));
    *(uint2*)&LDSU[OP_LO + idx] = make_uint2((uint)l[0]|((uint)l[1]<<16), (uint)l[2]|((uint)l[3]<<16));
  }
  __syncthreads();

  // ---- E: A=C~[t][n], B=B~[s][n], K=128 ----
#pragma unroll
  for (int ks=0; ks<4; ks++){
    bf16x8 ah[2], al[2], bh, bl;
#pragma unroll
    for (int fi=0; fi<2; fi++){
      int R = wr*32 + fi*16 + lr;
      int idx = R*128 + (((ks*4 + lk) ^ (R&7))<<3);
      ah[fi] = *(const bf16x8*)&LDSU[OC_HI + idx];
      al[fi] = *(const bf16x8*)&LDSU[OC_LO + idx];
    }
    { int Rb = wc*16 + lr;
      int idx = Rb*128 + (((ks*4 + lk) ^ (Rb&7))<<3);
      bh = *(const bf16x8*)&LDSU[OP_HI + idx];
      bl = *(const bf16x8*)&LDSU[OP_LO + idx]; }
#pragma unroll
    for (int fi=0; fi<2; fi++){
      ev[fi] = __builtin_amdgcn_mfma_f32_16x16x32_bf16(ah[fi], bh, ev[fi], 0,0,0);
      ev[fi] = __builtin_amdgcn_mfma_f32_16x16x32_bf16(ah[fi], bl, ev[fi], 0,0,0);
      ev[fi] = __builtin_amdgcn_mfma_f32_16x16x32_bf16(al[fi], bh, ev[fi], 0,0,0);
    }
  }

  // ---- G = mask * exp(la_t - la_s) * dt_s * E -> split-bf16 in LDS [t][s] ----
  {
    int s_col = wc*16 + lr;
    float las_s = La[s_col], dt_s = Dt[s_col];
#pragma unroll
    for (int fi=0; fi<2; fi++)
#pragma unroll
      for (int e=0; e<4; e++){
        int t = wr*32 + fi*16 + lk*4 + e;
        float g = 0.f;
        if (s_col <= t) g = __expf(La[t] - las_s) * dt_s * ev[fi][e];
        ushort hg = bf16rn(g);
        ushort lg = bf16rn(g - bf2f(hg));
        int idx = t*64 + (((s_col>>3) ^ (t&7))<<3) + (s_col&7);
        LDSU[OG_HI + idx] = hg; LDSU[OG_LO + idx] = lg;
      }
  }
  __syncthreads();

  // ---- Yintra: A=G~[t][s], B=XT~[p][s], K=64 ----
#pragma unroll
  for (int ks=0; ks<2; ks++){
    bf16x8 ah[2], al[2], bh, bl;
#pragma unroll
    for (int fi=0; fi<2; fi++){
      int R = wr*32 + fi*16 + lr;
      int idx = R*64 + (((ks*4 + lk) ^ (R&7))<<3);
      ah[fi] = *(const bf16x8*)&LDSU[OG_HI + idx];
      al[fi] = *(const bf16x8*)&LDSU[OG_LO + idx];
    }
    { int Rb = wc*16 + lr;
      int idx = Rb*64 + (((ks*4 + lk) ^ (Rb&7))<<3);
      bh = *(const bf16x8*)&LDSU[OX_HI + idx];
      bl = *(const bf16x8*)&LDSU[OX_LO + idx]; }
#pragma unroll
    for (int fi=0; fi<2; fi++){
      yv[fi] = __builtin_amdgcn_mfma_f32_16x16x32_bf16(ah[fi], bh, yv[fi], 0,0,0);
      yv[fi] = __builtin_amdgcn_mfma_f32_16x16x32_bf16(ah[fi], bl, yv[fi], 0,0,0);
      yv[fi] = __builtin_amdgcn_mfma_f32_16x16x32_bf16(al[fi], bh, yv[fi], 0,0,0);
    }
  }
  __syncthreads();   // all waves done reading G~ -> safe to overwrite with Yf

  // ---- Yf[t][p] = exp(la_t)*Yinter + Yintra (f32, reuses G~ region) ----
  {
    float* Yf = (float*)&LDSU[OG_HI];
    int p = wc*16 + lr;
#pragma unroll
    for (int fi=0; fi<2; fi++)
#pragma unroll
      for (int e=0; e<4; e++){
        int t = wr*32 + fi*16 + lk*4 + e;
        Yf[t*64 + p] = __expf(La[t])*yi[fi][e] + yv[fi][e];
      }
  }
  __syncthreads();

  // ---- epilogue: + D*x, * silu(z), split-bf16 write to yS ----
  {
    const float* Yf = (const float*)&LDSU[OG_HI];
    for (int it = tid; it < 64*16; it += 512){
      int t = it >> 4, p4 = (it & 15) << 2;
      size_t row = (size_t)(b*L_ + c*Q + t);
      float4 x4 = *(const float4*)&xbc[row*CONVD + hh*HD + p4];
      float4 z4 = *(const float4*)&zx[row*DPROJ + hh*HD + p4];
      float xx[4] = {x4.x,x4.y,x4.z,x4.w};
      float zz[4] = {z4.x,z4.y,z4.z,z4.w};
      ushort h4[4], l4[4];
#pragma unroll
      for (int j=0;j<4;j++){
        float y = Yf[t*64 + p4 + j] + Dh*xx[j];
        float o = y * (zz[j] * sigmoidf_(zz[j]));
        h4[j] = bf16rn(o);
        l4[j] = bf16rn(o - bf2f(h4[j]));
      }
      size_t o0 = row*(size_t)(2*DI) + hh*HD + p4;
      *(uint2*)&yS[o0]      = make_uint2((uint)h4[0]|((uint)h4[1]<<16), (uint)h4[2]|((uint)h4[3]<<16));
      *(uint2*)&yS[o0 + DI] = make_uint2((uint)l4[0]|((uint)l4[1]<<16), (uint)l4[2]|((uint)l4[3]<<16));
    }
  }
}

extern "C" void kernel_launch(void* const* d_in, const int* in_sizes, int n_in,
                              void* d_out, int out_size, void* d_ws, size_t ws_size,
                              hipStream_t stream) {
  const float* u       = (const float*)d_in[0];
  const float* W_in    = (const float*)d_in[1];
  const float* conv_w  = (const float*)d_in[2];
  const float* conv_b  = (const float*)d_in[3];
  const float* dt_bias = (const float*)d_in[4];
  const float* A_log   = (const float*)d_in[5];
  const float* D_param = (const float*)d_in[6];
  const float* W_out   = (const float*)d_in[7];
  float* out = (float*)d_out;

  float* ws = (float*)d_ws;
  float* zx     = ws;                                        // 1024*3352
  float* xbc    = zx   + (size_t)ML*DPROJ;                   // 1024*1792
  float* dts    = xbc  + (size_t)ML*CONVD;                   // 24576
  float* las    = dts  + (size_t)B_*NH*L_;                   // 24576
  float* Schunk = las  + (size_t)B_*NH*L_;                   // 48*8*8192
  ushort* uS    = (ushort*)(Schunk + (size_t)B_*NH*NC*HD*DS);
  ushort* yS    = uS;                                        // aliased (uS dead after gemm1)
  ushort* WinS  = yS + (size_t)ML*2*DI;
  ushort* WoutS = WinS;                                      // aliased (WinS dead after gemm1)

  // 1) split-convert u and W_in
  cvt_split<<<(ML*(DM/4)+255)/256, 256, 0, stream>>>(u, uS, ML, ML, DM);
  cvt_split<<<(NPAD1*(DM/4)+255)/256, 256, 0, stream>>>(W_in, WinS, DPROJ, NPAD1, DM);
  // 2) in-projection GEMM (fused split-planes)
  {
    dim3 grid(ML/64, NPAD1/64, 1);
    gemm4<64,64,DM,1,false><<<grid, 256, 0, stream>>>(uS, WinS, zx, DPROJ, DPROJ);
  }
  // 3) conv + SiLU (rolling window, 32-t blocks)
  {
    dim3 grid(7, L_/32, B_);
    conv2_kernel<<<grid, 256, 0, stream>>>(zx, conv_w, conv_b, xbc);
  }
  // 4) dt + chunk-local cumsum(dt*A)
  dt_kernel<<<B_*NH*NC, 64, 0, stream>>>(zx, dt_bias, A_log, dts, las);
  // 5) chunk states
  {
    dim3 grid(NC, NH, B_);
    chunk_state_kernel<<<grid, 256, 0, stream>>>(xbc, dts, las, Schunk);
  }
  // 6) inter-chunk scan
  interchunk_kernel<<<B_*NH*8, 256, 0, stream>>>(Schunk, las);
  // 7) chunk outputs (MFMA) -> yS split planes
  {
    dim3 grid(NC, NH, B_);
    chunk_out_mfma<<<grid, 512, 0, stream>>>(zx, xbc, dts, las, Schunk, D_param, yS);
  }
  // 8) split-convert W_out
  cvt_split<<<(DM*(DI/4)+255)/256, 256, 0, stream>>>(W_out, WoutS, DM, DM, DI);
  // 9) out-projection GEMM: zero out, then split-K=4 with atomic accumulate
  hipMemsetAsync(d_out, 0, (size_t)out_size*sizeof(float), stream);
  {
    dim3 grid(ML/64, DM/64, 4);
    gemm4<64,64,DI,4,true><<<grid, 256, 0, stream>>>(yS, WoutS, out, DM, DM);
  }
}

// Round 13
// 175.319 us; speedup vs baseline: 3.2445x; 1.0463x over previous
//
#include <hip/hip_runtime.h>
#include <math.h>

#define B_     2
#define L_     512
#define DM     768
#define DS     128
#define HD     64
#define DI     1536
#define NH     24
#define CONVD  1792
#define DPROJ  3352
#define ML     (B_*L_)
#define Q      64
#define NC     (L_/Q)
#define NPAD1  3456

typedef __bf16 bf16x8 __attribute__((ext_vector_type(8)));
typedef float f32x4 __attribute__((ext_vector_type(4)));

__device__ __forceinline__ float sigmoidf_(float x){ return 1.f/(1.f+__expf(-x)); }
__device__ __forceinline__ ushort bf16rn(float x){
  uint u = __float_as_uint(x);
  u += 0x7fff + ((u>>16)&1);
  return (ushort)(u>>16);
}
__device__ __forceinline__ float bf2f(ushort h){ return __uint_as_float(((uint)h)<<16); }
__device__ __forceinline__ void gll16(const void* g, void* l){
  __builtin_amdgcn_global_load_lds((const __attribute__((address_space(1))) void*)g,
                                   (__attribute__((address_space(3))) void*)l, 16, 0, 0);
}

// ---- convert one float4 -> hi/lo bf16 planes ----
__device__ __forceinline__ void cvt4(const float* srcp, ushort* dsth, ushort* dstl, bool valid){
  float4 v = valid ? *(const float4*)srcp : make_float4(0,0,0,0);
  float xv[4] = {v.x,v.y,v.z,v.w};
  ushort h[4], l[4];
#pragma unroll
  for (int j=0;j<4;j++){ h[j]=bf16rn(xv[j]); l[j]=bf16rn(xv[j]-bf2f(h[j])); }
  *(uint2*)dsth = make_uint2((uint)h[0]|((uint)h[1]<<16), (uint)h[2]|((uint)h[3]<<16));
  *(uint2*)dstl = make_uint2((uint)l[0]|((uint)l[1]<<16), (uint)l[2]|((uint)l[3]<<16));
}

// ---- one kernel: split-convert u, W_in (padded), W_out; zero d_out ----
__launch_bounds__(256)
__global__ void cvt_all(const float* __restrict__ u, const float* __restrict__ W_in,
                        const float* __restrict__ W_out,
                        ushort* __restrict__ uS, ushort* __restrict__ WinS,
                        ushort* __restrict__ WoutS, float* __restrict__ out, int outN4){
  const int N1 = ML*(DM/4);
  const int N2 = NPAD1*(DM/4);
  const int N3 = DM*(DI/4);
  int idx = blockIdx.x*256 + threadIdx.x;
  if (idx < N1){
    int r = idx/(DM/4), c = (idx - r*(DM/4))<<2;
    cvt4(&u[(size_t)r*DM + c], &uS[(size_t)r*2*DM + c], &uS[(size_t)r*2*DM + DM + c], true);
  } else if (idx < N1+N2){
    int li = idx - N1;
    int r = li/(DM/4), c = (li - r*(DM/4))<<2;
    bool valid = r < DPROJ;
    cvt4(&W_in[(size_t)(valid ? r : 0)*DM + c], &WinS[(size_t)r*2*DM + c], &WinS[(size_t)r*2*DM + DM + c], valid);
  } else if (idx < N1+N2+N3){
    int li = idx - N1 - N2;
    int r = li/(DI/4), c = (li - r*(DI/4))<<2;
    cvt4(&W_out[(size_t)r*DI + c], &WoutS[(size_t)r*2*DI + c], &WoutS[(size_t)r*2*DI + DI + c], true);
  } else {
    int o = idx - (N1+N2+N3);
    if (o < outN4) *(float4*)&out[(size_t)o*4] = make_float4(0,0,0,0);
  }
}

// ---- bf16 GEMM, fused split-planes (ah*bh + ah*bl + al*bh per K-tile) ----
template<int BM,int BN,int K,int SPLITK,bool ATOMIC>
__launch_bounds__(256, 2)
__global__ void gemm4(const ushort* __restrict__ AS, const ushort* __restrict__ BS,
                      float* __restrict__ C, int Nvalid, int Nstore){
  constexpr int KS = K / SPLITK;
  constexpr int STEPS = KS / 64;
  constexpr int WM=BM/2, WN=BN/2, FM=WM/16, FN=WN/16;
  __shared__ ushort Ah[2][BM*64], Alo[2][BM*64], Bh[2][BN*64], Blo[2][BN*64];
  const int tid=threadIdx.x, lane=tid&63, w=tid>>6;
  const int WR=w>>1, WC=w&1;
  const int bm=blockIdx.x*BM, bn=blockIdx.y*BN;
  const int kbase = blockIdx.z*KS;
  const int lr=lane&15;
  const int srow=lane>>3;
  const int scol=(((lane&7) ^ (srow&7))*8);
  f32x4 acc[FM][FN] = {};

  auto stage = [&](int d, int ks){
    int k0 = kbase + ks*64;
#pragma unroll
    for (int ci=w; ci<BM/8; ci+=4){
      size_t ro = (size_t)(bm + ci*8 + srow)*(2*K);
      gll16(&AS[ro + k0 + scol],     &Ah[d][ci*512]);
      gll16(&AS[ro + K + k0 + scol], &Alo[d][ci*512]);
    }
#pragma unroll
    for (int ci=w; ci<BN/8; ci+=4){
      size_t ro = (size_t)(bn + ci*8 + srow)*(2*K);
      gll16(&BS[ro + k0 + scol],     &Bh[d][ci*512]);
      gll16(&BS[ro + K + k0 + scol], &Blo[d][ci*512]);
    }
  };

  stage(0, 0);
  __syncthreads();
  int cur = 0;
  for (int ks=0; ks<STEPS; ks++){
    if (ks+1 < STEPS) stage(cur^1, ks+1);

    bf16x8 ah[2][FM], al[2][FM], bh[2][FN], bl[2][FN];
#pragma unroll
    for (int s2=0;s2<2;s2++){
      int gslot = s2*4 + (lane>>4);
#pragma unroll
      for (int i=0;i<FM;i++){
        int R = WR*WM + i*16 + lr;
        int so = (gslot ^ (lr&7))*8;
        ah[s2][i] = *(const bf16x8*)&Ah[cur][R*64 + so];
        al[s2][i] = *(const bf16x8*)&Alo[cur][R*64 + so];
      }
#pragma unroll
      for (int j=0;j<FN;j++){
        int R = WC*WN + j*16 + lr;
        int so = (gslot ^ (lr&7))*8;
        bh[s2][j] = *(const bf16x8*)&Bh[cur][R*64 + so];
        bl[s2][j] = *(const bf16x8*)&Blo[cur][R*64 + so];
      }
    }
#pragma unroll
    for (int s2=0;s2<2;s2++)
#pragma unroll
      for (int i=0;i<FM;i++)
#pragma unroll
        for (int j=0;j<FN;j++){
          acc[i][j] = __builtin_amdgcn_mfma_f32_16x16x32_bf16(ah[s2][i], bh[s2][j], acc[i][j], 0,0,0);
          acc[i][j] = __builtin_amdgcn_mfma_f32_16x16x32_bf16(ah[s2][i], bl[s2][j], acc[i][j], 0,0,0);
          acc[i][j] = __builtin_amdgcn_mfma_f32_16x16x32_bf16(al[s2][i], bh[s2][j], acc[i][j], 0,0,0);
        }

    __syncthreads();
    cur ^= 1;
  }

#pragma unroll
  for (int i=0;i<FM;i++)
#pragma unroll
    for (int j=0;j<FN;j++){
      int n = bn + WC*WN + j*16 + lr;
      if (n < Nvalid){
#pragma unroll
        for (int e=0;e<4;e++){
          int m = bm + WR*WM + i*16 + (lane>>4)*4 + e;
          if (ATOMIC) atomicAdd(&C[(size_t)m*Nstore + n], acc[i][j][e]);
          else        C[(size_t)m*Nstore + n] = acc[i][j][e];
        }
      }
    }
}

// ---- rolling-window causal conv (width 4) + SiLU; 32 timesteps per block ----
__launch_bounds__(256)
__global__ void conv2_kernel(const float* __restrict__ zx,
                             const float* __restrict__ cw,
                             const float* __restrict__ cb,
                             float* __restrict__ xbc){
  int g = blockIdx.x;
  int c2 = blockIdx.y;
  int b = blockIdx.z;
  int t0g = c2*32;
  int ch = g*256 + threadIdx.x;
  const float* src = zx + (size_t)(b*L_ + t0g)*DPROJ + DI + ch;
  float* dst = xbc + (size_t)(b*L_ + t0g)*CONVD + ch;
  float w0=cw[ch*4],w1=cw[ch*4+1],w2=cw[ch*4+2],w3=cw[ch*4+3],bias=cb[ch];
  float x0=0.f,x1=0.f,x2=0.f;
  if (t0g > 0){
    x0 = *(src - 3*DPROJ);
    x1 = *(src - 2*DPROJ);
    x2 = *(src - 1*DPROJ);
  }
#pragma unroll 4
  for (int tt=0; tt<32; tt++){
    float xt = src[(size_t)tt*DPROJ];
    float a = bias;
    a = fmaf(w3, xt, a); a = fmaf(w2, x2, a); a = fmaf(w1, x1, a); a = fmaf(w0, x0, a);
    dst[(size_t)tt*CONVD] = a * sigmoidf_(a);
    x0 = x1; x1 = x2; x2 = xt;
  }
}

// -------- K1 (MFMA): dt/cumsum (wave 0) + S_chunk[p][n] = sum_s w[s] x[s][p] B[s][n] --------
// Stages XwT[p][s] (64x64) and BT[n][s] (128x64) split-bf16, swizzled; K=s contiguous.
__launch_bounds__(256)
__global__ void chunk_state_mfma(const float* __restrict__ zx,
                                 const float* __restrict__ xbc,
                                 const float* __restrict__ dt_bias,
                                 const float* __restrict__ A_log,
                                 float* __restrict__ dts, float* __restrict__ las,
                                 float* __restrict__ Schunk){
  constexpr int OX_HI=0, OX_LO=4096;       // XwT 64x64 ushorts
  constexpr int OB_HI=8192, OB_LO=16384;   // BT 128x64 ushorts
  __shared__ ushort L[24576];              // 48 KB
  __shared__ float Wt[64];
  int c=blockIdx.x, h=blockIdx.y, b=blockIdx.z;
  int tid=threadIdx.x;
  int bh=b*NH+h;
  const int tbase=bh*L_+c*Q;

  // phase A: dt = softplus(raw+bias), la = chunk-local cumsum(dt*A) — wave 0 only
  if (tid < 64){
    int t = c*Q + tid;
    float raw = zx[(size_t)(b*L_+t)*DPROJ + DI + CONVD + h] + dt_bias[h];
    float dtv = raw > 20.f ? raw : log1pf(__expf(raw));
    float A = -__expf(A_log[h]);
    float la = dtv*A;
#pragma unroll
    for (int off=1; off<64; off<<=1){
      float v = __shfl_up(la, off);
      if (tid >= off) la += v;
    }
    dts[tbase + tid] = dtv;
    las[tbase + tid] = la;
    float la63 = __shfl(la, 63);
    Wt[tid] = __expf(la63 - la) * dtv;
  }
  __syncthreads();

  // phase B: stage XwT[p][s] and BT[n][s] (split-bf16, swizzled scatter)
  for (int it = tid; it < 64*16; it += 256){
    int s = it >> 4, p4 = (it & 15) << 2;
    float4 v = *(const float4*)&xbc[(size_t)(b*L_ + c*Q + s)*CONVD + h*HD + p4];
    float ws = Wt[s];
    float xv[4] = {v.x*ws, v.y*ws, v.z*ws, v.w*ws};
#pragma unroll
    for (int j=0;j<4;j++){
      int p = p4 + j;
      ushort hh = bf16rn(xv[j]);
      ushort ll = bf16rn(xv[j] - bf2f(hh));
      int idx = p*64 + (((s>>3) ^ (p&7))<<3) + (s&7);
      L[OX_HI + idx] = hh; L[OX_LO + idx] = ll;
    }
  }
  for (int it = tid; it < 64*32; it += 256){
    int s = it >> 5, n4 = (it & 31) << 2;
    float4 v = *(const float4*)&xbc[(size_t)(b*L_ + c*Q + s)*CONVD + DI + n4];
    float xv[4] = {v.x,v.y,v.z,v.w};
#pragma unroll
    for (int j=0;j<4;j++){
      int n = n4 + j;
      ushort hh = bf16rn(xv[j]);
      ushort ll = bf16rn(xv[j] - bf2f(hh));
      int idx = n*64 + (((s>>3) ^ (n&7))<<3) + (s&7);
      L[OB_HI + idx] = hh; L[OB_LO + idx] = ll;
    }
  }
  __syncthreads();

  // phase C: MFMA — wave grid 2p x 2n over 64p x 128n
  const int lane = tid & 63, w = tid >> 6;
  const int wr = w >> 1, wc = w & 1;
  const int lr = lane & 15, lk = lane >> 4;
  f32x4 acc[2][4] = {};
#pragma unroll
  for (int ks=0; ks<2; ks++){
    bf16x8 ah[2], al[2], bhf[4], blf[4];
#pragma unroll
    for (int fi=0; fi<2; fi++){
      int R = wr*32 + fi*16 + lr;
      int idx = R*64 + (((ks*4 + lk) ^ (R&7))<<3);
      ah[fi] = *(const bf16x8*)&L[OX_HI + idx];
      al[fi] = *(const bf16x8*)&L[OX_LO + idx];
    }
#pragma unroll
    for (int fj=0; fj<4; fj++){
      int Rb = wc*64 + fj*16 + lr;
      int idx = Rb*64 + (((ks*4 + lk) ^ (Rb&7))<<3);
      bhf[fj] = *(const bf16x8*)&L[OB_HI + idx];
      blf[fj] = *(const bf16x8*)&L[OB_LO + idx];
    }
#pragma unroll
    for (int fi=0; fi<2; fi++)
#pragma unroll
      for (int fj=0; fj<4; fj++){
        acc[fi][fj] = __builtin_amdgcn_mfma_f32_16x16x32_bf16(ah[fi], bhf[fj], acc[fi][fj], 0,0,0);
        acc[fi][fj] = __builtin_amdgcn_mfma_f32_16x16x32_bf16(ah[fi], blf[fj], acc[fi][fj], 0,0,0);
        acc[fi][fj] = __builtin_amdgcn_mfma_f32_16x16x32_bf16(al[fi], bhf[fj], acc[fi][fj], 0,0,0);
      }
  }

  float* Sb = Schunk + ((size_t)bh*NC + c)*(HD*DS);
#pragma unroll
  for (int fi=0; fi<2; fi++)
#pragma unroll
    for (int fj=0; fj<4; fj++){
      int n = wc*64 + fj*16 + lr;
#pragma unroll
      for (int e=0; e<4; e++){
        int p = wr*32 + fi*16 + lk*4 + e;
        Sb[p*DS + n] = acc[fi][fj][e];
      }
    }
}

// -------- K2: inter-chunk scan (in-place: Schunk -> S_start) --------
__launch_bounds__(256)
__global__ void interchunk_kernel(float* __restrict__ S, const float* __restrict__ las){
  int blk = blockIdx.x;
  int slice = blk & 7; int bh = blk >> 3;
  size_t base = (size_t)bh*NC*(HD*DS) + slice*1024 + threadIdx.x*4;
  float4 run = make_float4(0,0,0,0);
#pragma unroll
  for (int c=0;c<NC;c++){
    float dec = __expf(las[bh*L_ + c*Q + 63]);
    float4 ch = *(float4*)(S + base + c*(HD*DS));
    *(float4*)(S + base + c*(HD*DS)) = run;
    run.x = fmaf(run.x, dec, ch.x);
    run.y = fmaf(run.y, dec, ch.y);
    run.z = fmaf(run.z, dec, ch.z);
    run.w = fmaf(run.w, dec, ch.w);
  }
}

// -------- K3 (MFMA): per-chunk outputs via split-bf16 matrix cores --------
__launch_bounds__(512)
__global__ void chunk_out_mfma(const float* __restrict__ zx,
                               const float* __restrict__ xbc,
                               const float* __restrict__ dts,
                               const float* __restrict__ las,
                               const float* __restrict__ Sstart,
                               const float* __restrict__ Dp,
                               ushort* __restrict__ yS){
  constexpr int OC_HI = 0,      OC_LO = 8192;
  constexpr int OP_HI = 16384,  OP_LO = 24576;
  constexpr int OX_HI = 32768,  OX_LO = 36864;
  constexpr int OG_HI = 40960,  OG_LO = 45056;
  __shared__ ushort LDSU[49152];
  __shared__ float La[64], Dt[64];

  int c = blockIdx.x, hh = blockIdx.y, b = blockIdx.z;
  int tid = threadIdx.x;
  int bh = b*NH + hh;
  const int tbase = bh*L_ + c*Q;
  const float Dh = Dp[hh];
  const int lane = tid & 63, w = tid >> 6;
  const int wr = w >> 2, wc = w & 3;
  const int lr = lane & 15, lk = lane >> 4;

  for (int it = tid; it < 64*32; it += 512){
    int t = it >> 5, n4 = (it & 31) << 2;
    float4 v = *(const float4*)&xbc[(size_t)(b*L_ + c*Q + t)*CONVD + DI + DS + n4];
    float xv[4] = {v.x,v.y,v.z,v.w};
    ushort h[4], l[4];
#pragma unroll
    for (int j=0;j<4;j++){ h[j]=bf16rn(xv[j]); l[j]=bf16rn(xv[j]-bf2f(h[j])); }
    int idx = t*128 + (((n4>>3) ^ (t&7))<<3) + (n4&7);
    *(uint2*)&LDSU[OC_HI + idx] = make_uint2((uint)h[0]|((uint)h[1]<<16), (uint)h[2]|((uint)h[3]<<16));
    *(uint2*)&LDSU[OC_LO + idx] = make_uint2((uint)l[0]|((uint)l[1]<<16), (uint)l[2]|((uint)l[3]<<16));
  }
  const float* Sb = Sstart + ((size_t)bh*NC + c)*(HD*DS);
  for (int it = tid; it < 64*32; it += 512){
    int p = it >> 5, n4 = (it & 31) << 2;
    float4 v = *(const float4*)&Sb[p*DS + n4];
    float xv[4] = {v.x,v.y,v.z,v.w};
    ushort h[4], l[4];
#pragma unroll
    for (int j=0;j<4;j++){ h[j]=bf16rn(xv[j]); l[j]=bf16rn(xv[j]-bf2f(h[j])); }
    int idx = p*128 + (((n4>>3) ^ (p&7))<<3) + (n4&7);
    *(uint2*)&LDSU[OP_HI + idx] = make_uint2((uint)h[0]|((uint)h[1]<<16), (uint)h[2]|((uint)h[3]<<16));
    *(uint2*)&LDSU[OP_LO + idx] = make_uint2((uint)l[0]|((uint)l[1]<<16), (uint)l[2]|((uint)l[3]<<16));
  }
  for (int it = tid; it < 64*16; it += 512){
    int s = it >> 4, p4 = (it & 15) << 2;
    float4 v = *(const float4*)&xbc[(size_t)(b*L_ + c*Q + s)*CONVD + hh*HD + p4];
    float xv[4] = {v.x,v.y,v.z,v.w};
#pragma unroll
    for (int j=0;j<4;j++){
      int p = p4 + j;
      ushort h = bf16rn(xv[j]);
      ushort l = bf16rn(xv[j] - bf2f(h));
      int idx = p*64 + (((s>>3) ^ (p&7))<<3) + (s&7);
      LDSU[OX_HI + idx] = h; LDSU[OX_LO + idx] = l;
    }
  }
  if (tid < 64){ La[tid] = las[tbase + tid]; Dt[tid] = dts[tbase + tid]; }
  __syncthreads();

  f32x4 yi[2] = {}, ev[2] = {}, yv[2] = {};

#pragma unroll
  for (int ks=0; ks<4; ks++){
    bf16x8 ah[2], al[2], bh, bl;
#pragma unroll
    for (int fi=0; fi<2; fi++){
      int R = wr*32 + fi*16 + lr;
      int idx = R*128 + (((ks*4 + lk) ^ (R&7))<<3);
      ah[fi] = *(const bf16x8*)&LDSU[OC_HI + idx];
      al[fi] = *(const bf16x8*)&LDSU[OC_LO + idx];
    }
    { int Rb = wc*16 + lr;
      int idx = Rb*128 + (((ks*4 + lk) ^ (Rb&7))<<3);
      bh = *(const bf16x8*)&LDSU[OP_HI + idx];
      bl = *(const bf16x8*)&LDSU[OP_LO + idx]; }
#pragma unroll
    for (int fi=0; fi<2; fi++){
      yi[fi] = __builtin_amdgcn_mfma_f32_16x16x32_bf16(ah[fi], bh, yi[fi], 0,0,0);
      yi[fi] = __builtin_amdgcn_mfma_f32_16x16x32_bf16(ah[fi], bl, yi[fi], 0,0,0);
      yi[fi] = __builtin_amdgcn_mfma_f32_16x16x32_bf16(al[fi], bh, yi[fi], 0,0,0);
    }
  }
  __syncthreads();

  for (int it = tid; it < 64*32; it += 512){
    int s = it >> 5, n4 = (it & 31) << 2;
    float4 v = *(const float4*)&xbc[(size_t)(b*L_ + c*Q + s)*CONVD + DI + n4];
    float xv[4] = {v.x,v.y,v.z,v.w};
    ushort h[4], l[4];
#pragma unroll
    for (int j=0;j<4;j++){ h[j]=bf16rn(xv[j]); l[j]=bf16rn(xv[j]-bf2f(h[j])); }
    int idx = s*128 + (((n4>>3) ^ (s&7))<<3) + (n4&7);
    *(uint2*)&LDSU[OP_HI + idx] = make_uint2((uint)h[0]|((uint)h[1]<<16), (uint)h[2]|((uint)h[3]<<16));
    *(uint2*)&LDSU[OP_LO + idx] = make_uint2((uint)l[0]|((uint)l[1]<<16), (uint)l[2]|((uint)l[3]<<16));
  }
  __syncthreads();

#pragma unroll
  for (int ks=0; ks<4; ks++){
    bf16x8 ah[2], al[2], bh, bl;
#pragma unroll
    for (int fi=0; fi<2; fi++){
      int R = wr*32 + fi*16 + lr;
      int idx = R*128 + (((ks*4 + lk) ^ (R&7))<<3);
      ah[fi] = *(const bf16x8*)&LDSU[OC_HI + idx];
      al[fi] = *(const bf16x8*)&LDSU[OC_LO + idx];
    }
    { int Rb = wc*16 + lr;
      int idx = Rb*128 + (((ks*4 + lk) ^ (Rb&7))<<3);
      bh = *(const bf16x8*)&LDSU[OP_HI + idx];
      bl = *(const bf16x8*)&LDSU[OP_LO + idx]; }
#pragma unroll
    for (int fi=0; fi<2; fi++){
      ev[fi] = __builtin_amdgcn_mfma_f32_16x16x32_bf16(ah[fi], bh, ev[fi], 0,0,0);
      ev[fi] = __builtin_amdgcn_mfma_f32_16x16x32_bf16(ah[fi], bl, ev[fi], 0,0,0);
      ev[fi] = __builtin_amdgcn_mfma_f32_16x16x32_bf16(al[fi], bh, ev[fi], 0,0,0);
    }
  }

  {
    int s_col = wc*16 + lr;
    float las_s = La[s_col], dt_s = Dt[s_col];
#pragma unroll
    for (int fi=0; fi<2; fi++)
#pragma unroll
      for (int e=0; e<4; e++){
        int t = wr*32 + fi*16 + lk*4 + e;
        float g = 0.f;
        if (s_col <= t) g = __expf(La[t] - las_s) * dt_s * ev[fi][e];
        ushort hg = bf16rn(g);
        ushort lg = bf16rn(g - bf2f(hg));
        int idx = t*64 + (((s_col>>3) ^ (t&7))<<3) + (s_col&7);
        LDSU[OG_HI + idx] = hg; LDSU[OG_LO + idx] = lg;
      }
  }
  __syncthreads();

#pragma unroll
  for (int ks=0; ks<2; ks++){
    bf16x8 ah[2], al[2], bh, bl;
#pragma unroll
    for (int fi=0; fi<2; fi++){
      int R = wr*32 + fi*16 + lr;
      int idx = R*64 + (((ks*4 + lk) ^ (R&7))<<3);
      ah[fi] = *(const bf16x8*)&LDSU[OG_HI + idx];
      al[fi] = *(const bf16x8*)&LDSU[OG_LO + idx];
    }
    { int Rb = wc*16 + lr;
      int idx = Rb*64 + (((ks*4 + lk) ^ (Rb&7))<<3);
      bh = *(const bf16x8*)&LDSU[OX_HI + idx];
      bl = *(const bf16x8*)&LDSU[OX_LO + idx]; }
#pragma unroll
    for (int fi=0; fi<2; fi++){
      yv[fi] = __builtin_amdgcn_mfma_f32_16x16x32_bf16(ah[fi], bh, yv[fi], 0,0,0);
      yv[fi] = __builtin_amdgcn_mfma_f32_16x16x32_bf16(ah[fi], bl, yv[fi], 0,0,0);
      yv[fi] = __builtin_amdgcn_mfma_f32_16x16x32_bf16(al[fi], bh, yv[fi], 0,0,0);
    }
  }
  __syncthreads();

  {
    float* Yf = (float*)&LDSU[OG_HI];
    int p = wc*16 + lr;
#pragma unroll
    for (int fi=0; fi<2; fi++)
#pragma unroll
      for (int e=0; e<4; e++){
        int t = wr*32 + fi*16 + lk*4 + e;
        Yf[t*64 + p] = __expf(La[t])*yi[fi][e] + yv[fi][e];
      }
  }
  __syncthreads();

  {
    const float* Yf = (const float*)&LDSU[OG_HI];
    for (int it = tid; it < 64*16; it += 512){
      int t = it >> 4, p4 = (it & 15) << 2;
      size_t row = (size_t)(b*L_ + c*Q + t);
      float4 x4 = *(const float4*)&xbc[row*CONVD + hh*HD + p4];
      float4 z4 = *(const float4*)&zx[row*DPROJ + hh*HD + p4];
      float xx[4] = {x4.x,x4.y,x4.z,x4.w};
      float zz[4] = {z4.x,z4.y,z4.z,z4.w};
      ushort h4[4], l4[4];
#pragma unroll
      for (int j=0;j<4;j++){
        float y = Yf[t*64 + p4 + j] + Dh*xx[j];
        float o = y * (zz[j] * sigmoidf_(zz[j]));
        h4[j] = bf16rn(o);
        l4[j] = bf16rn(o - bf2f(h4[j]));
      }
      size_t o0 = row*(size_t)(2*DI) + hh*HD + p4;
      *(uint2*)&yS[o0]      = make_uint2((uint)h4[0]|((uint)h4[1]<<16), (uint)h4[2]|((uint)h4[3]<<16));
      *(uint2*)&yS[o0 + DI] = make_uint2((uint)l4[0]|((uint)l4[1]<<16), (uint)l4[2]|((uint)l4[3]<<16));
    }
  }
}

extern "C" void kernel_launch(void* const* d_in, const int* in_sizes, int n_in,
                              void* d_out, int out_size, void* d_ws, size_t ws_size,
                              hipStream_t stream) {
  const float* u       = (const float*)d_in[0];
  const float* W_in    = (const float*)d_in[1];
  const float* conv_w  = (const float*)d_in[2];
  const float* conv_b  = (const float*)d_in[3];
  const float* dt_bias = (const float*)d_in[4];
  const float* A_log   = (const float*)d_in[5];
  const float* D_param = (const float*)d_in[6];
  const float* W_out   = (const float*)d_in[7];
  float* out = (float*)d_out;

  float* ws = (float*)d_ws;
  float* zx     = ws;                                        // 1024*3352
  float* xbc    = zx   + (size_t)ML*DPROJ;                   // 1024*1792
  float* dts    = xbc  + (size_t)ML*CONVD;                   // 24576
  float* las    = dts  + (size_t)B_*NH*L_;                   // 24576
  float* Schunk = las  + (size_t)B_*NH*L_;                   // 48*8*8192
  ushort* uS    = (ushort*)(Schunk + (size_t)B_*NH*NC*HD*DS);
  ushort* yS    = uS;                                        // aliased (uS dead after gemm1)
  ushort* WinS  = uS + (size_t)ML*2*DI;                      // after yS's full extent
  ushort* WoutS = WinS + (size_t)NPAD1*2*DM;                 // own region (converted early)

  // 1) one-shot: split-convert u, W_in, W_out; zero d_out
  {
    int outN4 = out_size/4;
    int total = ML*(DM/4) + NPAD1*(DM/4) + DM*(DI/4) + outN4;
    cvt_all<<<(total+255)/256, 256, 0, stream>>>(u, W_in, W_out, uS, WinS, WoutS, out, outN4);
  }
  // 2) in-projection GEMM (fused split-planes)
  {
    dim3 grid(ML/64, NPAD1/64, 1);
    gemm4<64,64,DM,1,false><<<grid, 256, 0, stream>>>(uS, WinS, zx, DPROJ, DPROJ);
  }
  // 3) conv + SiLU (rolling window, 32-t blocks)
  {
    dim3 grid(7, L_/32, B_);
    conv2_kernel<<<grid, 256, 0, stream>>>(zx, conv_w, conv_b, xbc);
  }
  // 4) chunk states (MFMA; wave0 computes dt + cumsum, writes dts/las)
  {
    dim3 grid(NC, NH, B_);
    chunk_state_mfma<<<grid, 256, 0, stream>>>(zx, xbc, dt_bias, A_log, dts, las, Schunk);
  }
  // 5) inter-chunk scan
  interchunk_kernel<<<B_*NH*8, 256, 0, stream>>>(Schunk, las);
  // 6) chunk outputs (MFMA) -> yS split planes
  {
    dim3 grid(NC, NH, B_);
    chunk_out_mfma<<<grid, 512, 0, stream>>>(zx, xbc, dts, las, Schunk, D_param, yS);
  }
  // 7) out-projection GEMM: split-K=4 with atomic accumulate (d_out zeroed in step 1)
  {
    dim3 grid(ML/64, DM/64, 4);
    gemm4<64,64,DI,4,true><<<grid, 256, 0, stream>>>(yS, WoutS, out, DM, DM);
  }
}

// Round 14
// 171.426 us; speedup vs baseline: 3.3182x; 1.0227x over previous
//
#include <hip/hip_runtime.h>
#include <math.h>

#define B_     2
#define L_     512
#define DM     768
#define DS     128
#define HD     64
#define DI     1536
#define NH     24
#define CONVD  1792
#define DPROJ  3352
#define ML     (B_*L_)
#define Q      64
#define NC     (L_/Q)
#define NPAD1  3456

typedef __bf16 bf16x8 __attribute__((ext_vector_type(8)));
typedef _Float16 h16x8 __attribute__((ext_vector_type(8)));
typedef float f32x4 __attribute__((ext_vector_type(4)));

__device__ __forceinline__ float sigmoidf_(float x){ return 1.f/(1.f+__expf(-x)); }
__device__ __forceinline__ ushort bf16rn(float x){
  uint u = __float_as_uint(x);
  u += 0x7fff + ((u>>16)&1);
  return (ushort)(u>>16);
}
__device__ __forceinline__ float bf2f(ushort h){ return __uint_as_float(((uint)h)<<16); }
__device__ __forceinline__ ushort f16rn(float x){
  _Float16 h = (_Float16)x;
  union { _Float16 f; ushort u; } cv; cv.f = h; return cv.u;
}
__device__ __forceinline__ void gll16(const void* g, void* l){
  __builtin_amdgcn_global_load_lds((const __attribute__((address_space(1))) void*)g,
                                   (__attribute__((address_space(3))) void*)l, 16, 0, 0);
}

// ---- convert one float4 -> hi/lo bf16 planes ----
__device__ __forceinline__ void cvt4(const float* srcp, ushort* dsth, ushort* dstl, bool valid){
  float4 v = valid ? *(const float4*)srcp : make_float4(0,0,0,0);
  float xv[4] = {v.x,v.y,v.z,v.w};
  ushort h[4], l[4];
#pragma unroll
  for (int j=0;j<4;j++){ h[j]=bf16rn(xv[j]); l[j]=bf16rn(xv[j]-bf2f(h[j])); }
  *(uint2*)dsth = make_uint2((uint)h[0]|((uint)h[1]<<16), (uint)h[2]|((uint)h[3]<<16));
  *(uint2*)dstl = make_uint2((uint)l[0]|((uint)l[1]<<16), (uint)l[2]|((uint)l[3]<<16));
}

// ---- one kernel: split-convert u, W_in (padded, bf16); W_out (fp16 single); zero d_out ----
__launch_bounds__(256)
__global__ void cvt_all(const float* __restrict__ u, const float* __restrict__ W_in,
                        const float* __restrict__ W_out,
                        ushort* __restrict__ uS, ushort* __restrict__ WinS,
                        ushort* __restrict__ WoutS, float* __restrict__ out, int outN4){
  const int N1 = ML*(DM/4);
  const int N2 = NPAD1*(DM/4);
  const int N3 = DM*(DI/4);
  int idx = blockIdx.x*256 + threadIdx.x;
  if (idx < N1){
    int r = idx/(DM/4), c = (idx - r*(DM/4))<<2;
    cvt4(&u[(size_t)r*DM + c], &uS[(size_t)r*2*DM + c], &uS[(size_t)r*2*DM + DM + c], true);
  } else if (idx < N1+N2){
    int li = idx - N1;
    int r = li/(DM/4), c = (li - r*(DM/4))<<2;
    bool valid = r < DPROJ;
    cvt4(&W_in[(size_t)(valid ? r : 0)*DM + c], &WinS[(size_t)r*2*DM + c], &WinS[(size_t)r*2*DM + DM + c], valid);
  } else if (idx < N1+N2+N3){
    int li = idx - N1 - N2;
    int r = li/(DI/4), c = (li - r*(DI/4))<<2;
    float4 v = *(const float4*)&W_out[(size_t)r*DI + c];
    ushort h[4] = {f16rn(v.x), f16rn(v.y), f16rn(v.z), f16rn(v.w)};
    *(uint2*)&WoutS[(size_t)r*DI + c] = make_uint2((uint)h[0]|((uint)h[1]<<16), (uint)h[2]|((uint)h[3]<<16));
  } else {
    int o = idx - (N1+N2+N3);
    if (o < outN4) *(float4*)&out[(size_t)o*4] = make_float4(0,0,0,0);
  }
}

// ---- bf16 GEMM, fused split-planes (ah*bh + ah*bl + al*bh per K-tile) ----
template<int BM,int BN,int K,int SPLITK,bool ATOMIC>
__launch_bounds__(256, 2)
__global__ void gemm4(const ushort* __restrict__ AS, const ushort* __restrict__ BS,
                      float* __restrict__ C, int Nvalid, int Nstore){
  constexpr int KS = K / SPLITK;
  constexpr int STEPS = KS / 64;
  constexpr int WM=BM/2, WN=BN/2, FM=WM/16, FN=WN/16;
  __shared__ ushort Ah[2][BM*64], Alo[2][BM*64], Bh[2][BN*64], Blo[2][BN*64];
  const int tid=threadIdx.x, lane=tid&63, w=tid>>6;
  const int WR=w>>1, WC=w&1;
  const int bm=blockIdx.x*BM, bn=blockIdx.y*BN;
  const int kbase = blockIdx.z*KS;
  const int lr=lane&15;
  const int srow=lane>>3;
  const int scol=(((lane&7) ^ (srow&7))*8);
  f32x4 acc[FM][FN] = {};

  auto stage = [&](int d, int ks){
    int k0 = kbase + ks*64;
#pragma unroll
    for (int ci=w; ci<BM/8; ci+=4){
      size_t ro = (size_t)(bm + ci*8 + srow)*(2*K);
      gll16(&AS[ro + k0 + scol],     &Ah[d][ci*512]);
      gll16(&AS[ro + K + k0 + scol], &Alo[d][ci*512]);
    }
#pragma unroll
    for (int ci=w; ci<BN/8; ci+=4){
      size_t ro = (size_t)(bn + ci*8 + srow)*(2*K);
      gll16(&BS[ro + k0 + scol],     &Bh[d][ci*512]);
      gll16(&BS[ro + K + k0 + scol], &Blo[d][ci*512]);
    }
  };

  stage(0, 0);
  __syncthreads();
  int cur = 0;
  for (int ks=0; ks<STEPS; ks++){
    if (ks+1 < STEPS) stage(cur^1, ks+1);

    bf16x8 ah[2][FM], al[2][FM], bh[2][FN], bl[2][FN];
#pragma unroll
    for (int s2=0;s2<2;s2++){
      int gslot = s2*4 + (lane>>4);
#pragma unroll
      for (int i=0;i<FM;i++){
        int R = WR*WM + i*16 + lr;
        int so = (gslot ^ (lr&7))*8;
        ah[s2][i] = *(const bf16x8*)&Ah[cur][R*64 + so];
        al[s2][i] = *(const bf16x8*)&Alo[cur][R*64 + so];
      }
#pragma unroll
      for (int j=0;j<FN;j++){
        int R = WC*WN + j*16 + lr;
        int so = (gslot ^ (lr&7))*8;
        bh[s2][j] = *(const bf16x8*)&Bh[cur][R*64 + so];
        bl[s2][j] = *(const bf16x8*)&Blo[cur][R*64 + so];
      }
    }
#pragma unroll
    for (int s2=0;s2<2;s2++)
#pragma unroll
      for (int i=0;i<FM;i++)
#pragma unroll
        for (int j=0;j<FN;j++){
          acc[i][j] = __builtin_amdgcn_mfma_f32_16x16x32_bf16(ah[s2][i], bh[s2][j], acc[i][j], 0,0,0);
          acc[i][j] = __builtin_amdgcn_mfma_f32_16x16x32_bf16(ah[s2][i], bl[s2][j], acc[i][j], 0,0,0);
          acc[i][j] = __builtin_amdgcn_mfma_f32_16x16x32_bf16(al[s2][i], bh[s2][j], acc[i][j], 0,0,0);
        }

    __syncthreads();
    cur ^= 1;
  }

#pragma unroll
  for (int i=0;i<FM;i++)
#pragma unroll
    for (int j=0;j<FN;j++){
      int n = bn + WC*WN + j*16 + lr;
      if (n < Nvalid){
#pragma unroll
        for (int e=0;e<4;e++){
          int m = bm + WR*WM + i*16 + (lane>>4)*4 + e;
          if (ATOMIC) atomicAdd(&C[(size_t)m*Nstore + n], acc[i][j][e]);
          else        C[(size_t)m*Nstore + n] = acc[i][j][e];
        }
      }
    }
}

// ---- fp16 single-plane GEMM (out-projection): row stride = K halfs ----
template<int BM,int BN,int K,int SPLITK,bool ATOMIC>
__launch_bounds__(256, 2)
__global__ void gemm_f16(const ushort* __restrict__ AS, const ushort* __restrict__ BS,
                         float* __restrict__ C, int Nvalid, int Nstore){
  constexpr int KS = K / SPLITK;
  constexpr int STEPS = KS / 64;
  constexpr int WM=BM/2, WN=BN/2, FM=WM/16, FN=WN/16;
  __shared__ ushort Ah[2][BM*64], Bh[2][BN*64];
  const int tid=threadIdx.x, lane=tid&63, w=tid>>6;
  const int WR=w>>1, WC=w&1;
  const int bm=blockIdx.x*BM, bn=blockIdx.y*BN;
  const int kbase = blockIdx.z*KS;
  const int lr=lane&15;
  const int srow=lane>>3;
  const int scol=(((lane&7) ^ (srow&7))*8);
  f32x4 acc[FM][FN] = {};

  auto stage = [&](int d, int ks){
    int k0 = kbase + ks*64;
#pragma unroll
    for (int ci=w; ci<BM/8; ci+=4)
      gll16(&AS[(size_t)(bm + ci*8 + srow)*K + k0 + scol], &Ah[d][ci*512]);
#pragma unroll
    for (int ci=w; ci<BN/8; ci+=4)
      gll16(&BS[(size_t)(bn + ci*8 + srow)*K + k0 + scol], &Bh[d][ci*512]);
  };

  stage(0, 0);
  __syncthreads();
  int cur = 0;
  for (int ks=0; ks<STEPS; ks++){
    if (ks+1 < STEPS) stage(cur^1, ks+1);

    h16x8 af[2][FM], bf[2][FN];
#pragma unroll
    for (int s2=0;s2<2;s2++){
      int gslot = s2*4 + (lane>>4);
#pragma unroll
      for (int i=0;i<FM;i++){
        int R = WR*WM + i*16 + lr;
        af[s2][i] = *(const h16x8*)&Ah[cur][R*64 + (gslot ^ (lr&7))*8];
      }
#pragma unroll
      for (int j=0;j<FN;j++){
        int R = WC*WN + j*16 + lr;
        bf[s2][j] = *(const h16x8*)&Bh[cur][R*64 + (gslot ^ (lr&7))*8];
      }
    }
#pragma unroll
    for (int s2=0;s2<2;s2++)
#pragma unroll
      for (int i=0;i<FM;i++)
#pragma unroll
        for (int j=0;j<FN;j++)
          acc[i][j] = __builtin_amdgcn_mfma_f32_16x16x32_f16(af[s2][i], bf[s2][j], acc[i][j], 0,0,0);

    __syncthreads();
    cur ^= 1;
  }

#pragma unroll
  for (int i=0;i<FM;i++)
#pragma unroll
    for (int j=0;j<FN;j++){
      int n = bn + WC*WN + j*16 + lr;
      if (n < Nvalid){
#pragma unroll
        for (int e=0;e<4;e++){
          int m = bm + WR*WM + i*16 + (lane>>4)*4 + e;
          if (ATOMIC) atomicAdd(&C[(size_t)m*Nstore + n], acc[i][j][e]);
          else        C[(size_t)m*Nstore + n] = acc[i][j][e];
        }
      }
    }
}

// ---- rolling-window causal conv (width 4) + SiLU; 32 timesteps per block ----
__launch_bounds__(256)
__global__ void conv2_kernel(const float* __restrict__ zx,
                             const float* __restrict__ cw,
                             const float* __restrict__ cb,
                             float* __restrict__ xbc){
  int g = blockIdx.x;
  int c2 = blockIdx.y;
  int b = blockIdx.z;
  int t0g = c2*32;
  int ch = g*256 + threadIdx.x;
  const float* src = zx + (size_t)(b*L_ + t0g)*DPROJ + DI + ch;
  float* dst = xbc + (size_t)(b*L_ + t0g)*CONVD + ch;
  float w0=cw[ch*4],w1=cw[ch*4+1],w2=cw[ch*4+2],w3=cw[ch*4+3],bias=cb[ch];
  float x0=0.f,x1=0.f,x2=0.f;
  if (t0g > 0){
    x0 = *(src - 3*DPROJ);
    x1 = *(src - 2*DPROJ);
    x2 = *(src - 1*DPROJ);
  }
#pragma unroll 4
  for (int tt=0; tt<32; tt++){
    float xt = src[(size_t)tt*DPROJ];
    float a = bias;
    a = fmaf(w3, xt, a); a = fmaf(w2, x2, a); a = fmaf(w1, x1, a); a = fmaf(w0, x0, a);
    dst[(size_t)tt*CONVD] = a * sigmoidf_(a);
    x0 = x1; x1 = x2; x2 = xt;
  }
}

// -------- K1 (MFMA): dt/cumsum (wave 0) + S_chunk[p][n] = sum_s w[s] x[s][p] B[s][n] --------
__launch_bounds__(256)
__global__ void chunk_state_mfma(const float* __restrict__ zx,
                                 const float* __restrict__ xbc,
                                 const float* __restrict__ dt_bias,
                                 const float* __restrict__ A_log,
                                 float* __restrict__ dts, float* __restrict__ las,
                                 float* __restrict__ Schunk){
  constexpr int OX_HI=0, OX_LO=4096;
  constexpr int OB_HI=8192, OB_LO=16384;
  __shared__ ushort L[24576];
  __shared__ float Wt[64];
  int c=blockIdx.x, h=blockIdx.y, b=blockIdx.z;
  int tid=threadIdx.x;
  int bh=b*NH+h;
  const int tbase=bh*L_+c*Q;

  if (tid < 64){
    int t = c*Q + tid;
    float raw = zx[(size_t)(b*L_+t)*DPROJ + DI + CONVD + h] + dt_bias[h];
    float dtv = raw > 20.f ? raw : log1pf(__expf(raw));
    float A = -__expf(A_log[h]);
    float la = dtv*A;
#pragma unroll
    for (int off=1; off<64; off<<=1){
      float v = __shfl_up(la, off);
      if (tid >= off) la += v;
    }
    dts[tbase + tid] = dtv;
    las[tbase + tid] = la;
    float la63 = __shfl(la, 63);
    Wt[tid] = __expf(la63 - la) * dtv;
  }
  __syncthreads();

  for (int it = tid; it < 64*16; it += 256){
    int s = it >> 4, p4 = (it & 15) << 2;
    float4 v = *(const float4*)&xbc[(size_t)(b*L_ + c*Q + s)*CONVD + h*HD + p4];
    float ws = Wt[s];
    float xv[4] = {v.x*ws, v.y*ws, v.z*ws, v.w*ws};
#pragma unroll
    for (int j=0;j<4;j++){
      int p = p4 + j;
      ushort hh = bf16rn(xv[j]);
      ushort ll = bf16rn(xv[j] - bf2f(hh));
      int idx = p*64 + (((s>>3) ^ (p&7))<<3) + (s&7);
      L[OX_HI + idx] = hh; L[OX_LO + idx] = ll;
    }
  }
  for (int it = tid; it < 64*32; it += 256){
    int s = it >> 5, n4 = (it & 31) << 2;
    float4 v = *(const float4*)&xbc[(size_t)(b*L_ + c*Q + s)*CONVD + DI + n4];
    float xv[4] = {v.x,v.y,v.z,v.w};
#pragma unroll
    for (int j=0;j<4;j++){
      int n = n4 + j;
      ushort hh = bf16rn(xv[j]);
      ushort ll = bf16rn(xv[j] - bf2f(hh));
      int idx = n*64 + (((s>>3) ^ (n&7))<<3) + (s&7);
      L[OB_HI + idx] = hh; L[OB_LO + idx] = ll;
    }
  }
  __syncthreads();

  const int lane = tid & 63, w = tid >> 6;
  const int wr = w >> 1, wc = w & 1;
  const int lr = lane & 15, lk = lane >> 4;
  f32x4 acc[2][4] = {};
#pragma unroll
  for (int ks=0; ks<2; ks++){
    bf16x8 ah[2], al[2], bhf[4], blf[4];
#pragma unroll
    for (int fi=0; fi<2; fi++){
      int R = wr*32 + fi*16 + lr;
      int idx = R*64 + (((ks*4 + lk) ^ (R&7))<<3);
      ah[fi] = *(const bf16x8*)&L[OX_HI + idx];
      al[fi] = *(const bf16x8*)&L[OX_LO + idx];
    }
#pragma unroll
    for (int fj=0; fj<4; fj++){
      int Rb = wc*64 + fj*16 + lr;
      int idx = Rb*64 + (((ks*4 + lk) ^ (Rb&7))<<3);
      bhf[fj] = *(const bf16x8*)&L[OB_HI + idx];
      blf[fj] = *(const bf16x8*)&L[OB_LO + idx];
    }
#pragma unroll
    for (int fi=0; fi<2; fi++)
#pragma unroll
      for (int fj=0; fj<4; fj++){
        acc[fi][fj] = __builtin_amdgcn_mfma_f32_16x16x32_bf16(ah[fi], bhf[fj], acc[fi][fj], 0,0,0);
        acc[fi][fj] = __builtin_amdgcn_mfma_f32_16x16x32_bf16(ah[fi], blf[fj], acc[fi][fj], 0,0,0);
        acc[fi][fj] = __builtin_amdgcn_mfma_f32_16x16x32_bf16(al[fi], bhf[fj], acc[fi][fj], 0,0,0);
      }
  }

  float* Sb = Schunk + ((size_t)bh*NC + c)*(HD*DS);
#pragma unroll
  for (int fi=0; fi<2; fi++)
#pragma unroll
    for (int fj=0; fj<4; fj++){
      int n = wc*64 + fj*16 + lr;
#pragma unroll
      for (int e=0; e<4; e++){
        int p = wr*32 + fi*16 + lk*4 + e;
        Sb[p*DS + n] = acc[fi][fj][e];
      }
    }
}

// -------- K2: inter-chunk scan (in-place: Schunk -> S_start) --------
__launch_bounds__(256)
__global__ void interchunk_kernel(float* __restrict__ S, const float* __restrict__ las){
  int blk = blockIdx.x;
  int slice = blk & 7; int bh = blk >> 3;
  size_t base = (size_t)bh*NC*(HD*DS) + slice*1024 + threadIdx.x*4;
  float4 run = make_float4(0,0,0,0);
#pragma unroll
  for (int c=0;c<NC;c++){
    float dec = __expf(las[bh*L_ + c*Q + 63]);
    float4 ch = *(float4*)(S + base + c*(HD*DS));
    *(float4*)(S + base + c*(HD*DS)) = run;
    run.x = fmaf(run.x, dec, ch.x);
    run.y = fmaf(run.y, dec, ch.y);
    run.z = fmaf(run.z, dec, ch.z);
    run.w = fmaf(run.w, dec, ch.w);
  }
}

// -------- K3 (MFMA): per-chunk outputs; writes y as single fp16 plane --------
__launch_bounds__(512)
__global__ void chunk_out_mfma(const float* __restrict__ zx,
                               const float* __restrict__ xbc,
                               const float* __restrict__ dts,
                               const float* __restrict__ las,
                               const float* __restrict__ Sstart,
                               const float* __restrict__ Dp,
                               ushort* __restrict__ yS){
  constexpr int OC_HI = 0,      OC_LO = 8192;
  constexpr int OP_HI = 16384,  OP_LO = 24576;
  constexpr int OX_HI = 32768,  OX_LO = 36864;
  constexpr int OG_HI = 40960,  OG_LO = 45056;
  __shared__ ushort LDSU[49152];
  __shared__ float La[64], Dt[64];

  int c = blockIdx.x, hh = blockIdx.y, b = blockIdx.z;
  int tid = threadIdx.x;
  int bh = b*NH + hh;
  const int tbase = bh*L_ + c*Q;
  const float Dh = Dp[hh];
  const int lane = tid & 63, w = tid >> 6;
  const int wr = w >> 2, wc = w & 3;
  const int lr = lane & 15, lk = lane >> 4;

  for (int it = tid; it < 64*32; it += 512){
    int t = it >> 5, n4 = (it & 31) << 2;
    float4 v = *(const float4*)&xbc[(size_t)(b*L_ + c*Q + t)*CONVD + DI + DS + n4];
    float xv[4] = {v.x,v.y,v.z,v.w};
    ushort h[4], l[4];
#pragma unroll
    for (int j=0;j<4;j++){ h[j]=bf16rn(xv[j]); l[j]=bf16rn(xv[j]-bf2f(h[j])); }
    int idx = t*128 + (((n4>>3) ^ (t&7))<<3) + (n4&7);
    *(uint2*)&LDSU[OC_HI + idx] = make_uint2((uint)h[0]|((uint)h[1]<<16), (uint)h[2]|((uint)h[3]<<16));
    *(uint2*)&LDSU[OC_LO + idx] = make_uint2((uint)l[0]|((uint)l[1]<<16), (uint)l[2]|((uint)l[3]<<16));
  }
  const float* Sb = Sstart + ((size_t)bh*NC + c)*(HD*DS);
  for (int it = tid; it < 64*32; it += 512){
    int p = it >> 5, n4 = (it & 31) << 2;
    float4 v = *(const float4*)&Sb[p*DS + n4];
    float xv[4] = {v.x,v.y,v.z,v.w};
    ushort h[4], l[4];
#pragma unroll
    for (int j=0;j<4;j++){ h[j]=bf16rn(xv[j]); l[j]=bf16rn(xv[j]-bf2f(h[j])); }
    int idx = p*128 + (((n4>>3) ^ (p&7))<<3) + (n4&7);
    *(uint2*)&LDSU[OP_HI + idx] = make_uint2((uint)h[0]|((uint)h[1]<<16), (uint)h[2]|((uint)h[3]<<16));
    *(uint2*)&LDSU[OP_LO + idx] = make_uint2((uint)l[0]|((uint)l[1]<<16), (uint)l[2]|((uint)l[3]<<16));
  }
  for (int it = tid; it < 64*16; it += 512){
    int s = it >> 4, p4 = (it & 15) << 2;
    float4 v = *(const float4*)&xbc[(size_t)(b*L_ + c*Q + s)*CONVD + hh*HD + p4];
    float xv[4] = {v.x,v.y,v.z,v.w};
#pragma unroll
    for (int j=0;j<4;j++){
      int p = p4 + j;
      ushort h = bf16rn(xv[j]);
      ushort l = bf16rn(xv[j] - bf2f(h));
      int idx = p*64 + (((s>>3) ^ (p&7))<<3) + (s&7);
      LDSU[OX_HI + idx] = h; LDSU[OX_LO + idx] = l;
    }
  }
  if (tid < 64){ La[tid] = las[tbase + tid]; Dt[tid] = dts[tbase + tid]; }
  __syncthreads();

  f32x4 yi[2] = {}, ev[2] = {}, yv[2] = {};

#pragma unroll
  for (int ks=0; ks<4; ks++){
    bf16x8 ah[2], al[2], bh, bl;
#pragma unroll
    for (int fi=0; fi<2; fi++){
      int R = wr*32 + fi*16 + lr;
      int idx = R*128 + (((ks*4 + lk) ^ (R&7))<<3);
      ah[fi] = *(const bf16x8*)&LDSU[OC_HI + idx];
      al[fi] = *(const bf16x8*)&LDSU[OC_LO + idx];
    }
    { int Rb = wc*16 + lr;
      int idx = Rb*128 + (((ks*4 + lk) ^ (Rb&7))<<3);
      bh = *(const bf16x8*)&LDSU[OP_HI + idx];
      bl = *(const bf16x8*)&LDSU[OP_LO + idx]; }
#pragma unroll
    for (int fi=0; fi<2; fi++){
      yi[fi] = __builtin_amdgcn_mfma_f32_16x16x32_bf16(ah[fi], bh, yi[fi], 0,0,0);
      yi[fi] = __builtin_amdgcn_mfma_f32_16x16x32_bf16(ah[fi], bl, yi[fi], 0,0,0);
      yi[fi] = __builtin_amdgcn_mfma_f32_16x16x32_bf16(al[fi], bh, yi[fi], 0,0,0);
    }
  }
  __syncthreads();

  for (int it = tid; it < 64*32; it += 512){
    int s = it >> 5, n4 = (it & 31) << 2;
    float4 v = *(const float4*)&xbc[(size_t)(b*L_ + c*Q + s)*CONVD + DI + n4];
    float xv[4] = {v.x,v.y,v.z,v.w};
    ushort h[4], l[4];
#pragma unroll
    for (int j=0;j<4;j++){ h[j]=bf16rn(xv[j]); l[j]=bf16rn(xv[j]-bf2f(h[j])); }
    int idx = s*128 + (((n4>>3) ^ (s&7))<<3) + (n4&7);
    *(uint2*)&LDSU[OP_HI + idx] = make_uint2((uint)h[0]|((uint)h[1]<<16), (uint)h[2]|((uint)h[3]<<16));
    *(uint2*)&LDSU[OP_LO + idx] = make_uint2((uint)l[0]|((uint)l[1]<<16), (uint)l[2]|((uint)l[3]<<16));
  }
  __syncthreads();

#pragma unroll
  for (int ks=0; ks<4; ks++){
    bf16x8 ah[2], al[2], bh, bl;
#pragma unroll
    for (int fi=0; fi<2; fi++){
      int R = wr*32 + fi*16 + lr;
      int idx = R*128 + (((ks*4 + lk) ^ (R&7))<<3);
      ah[fi] = *(const bf16x8*)&LDSU[OC_HI + idx];
      al[fi] = *(const bf16x8*)&LDSU[OC_LO + idx];
    }
    { int Rb = wc*16 + lr;
      int idx = Rb*128 + (((ks*4 + lk) ^ (Rb&7))<<3);
      bh = *(const bf16x8*)&LDSU[OP_HI + idx];
      bl = *(const bf16x8*)&LDSU[OP_LO + idx]; }
#pragma unroll
    for (int fi=0; fi<2; fi++){
      ev[fi] = __builtin_amdgcn_mfma_f32_16x16x32_bf16(ah[fi], bh, ev[fi], 0,0,0);
      ev[fi] = __builtin_amdgcn_mfma_f32_16x16x32_bf16(ah[fi], bl, ev[fi], 0,0,0);
      ev[fi] = __builtin_amdgcn_mfma_f32_16x16x32_bf16(al[fi], bh, ev[fi], 0,0,0);
    }
  }

  {
    int s_col = wc*16 + lr;
    float las_s = La[s_col], dt_s = Dt[s_col];
#pragma unroll
    for (int fi=0; fi<2; fi++)
#pragma unroll
      for (int e=0; e<4; e++){
        int t = wr*32 + fi*16 + lk*4 + e;
        float g = 0.f;
        if (s_col <= t) g = __expf(La[t] - las_s) * dt_s * ev[fi][e];
        ushort hg = bf16rn(g);
        ushort lg = bf16rn(g - bf2f(hg));
        int idx = t*64 + (((s_col>>3) ^ (t&7))<<3) + (s_col&7);
        LDSU[OG_HI + idx] = hg; LDSU[OG_LO + idx] = lg;
      }
  }
  __syncthreads();

#pragma unroll
  for (int ks=0; ks<2; ks++){
    bf16x8 ah[2], al[2], bh, bl;
#pragma unroll
    for (int fi=0; fi<2; fi++){
      int R = wr*32 + fi*16 + lr;
      int idx = R*64 + (((ks*4 + lk) ^ (R&7))<<3);
      ah[fi] = *(const bf16x8*)&LDSU[OG_HI + idx];
      al[fi] = *(const bf16x8*)&LDSU[OG_LO + idx];
    }
    { int Rb = wc*16 + lr;
      int idx = Rb*64 + (((ks*4 + lk) ^ (Rb&7))<<3);
      bh = *(const bf16x8*)&LDSU[OX_HI + idx];
      bl = *(const bf16x8*)&LDSU[OX_LO + idx]; }
#pragma unroll
    for (int fi=0; fi<2; fi++){
      yv[fi] = __builtin_amdgcn_mfma_f32_16x16x32_bf16(ah[fi], bh, yv[fi], 0,0,0);
      yv[fi] = __builtin_amdgcn_mfma_f32_16x16x32_bf16(ah[fi], bl, yv[fi], 0,0,0);
      yv[fi] = __builtin_amdgcn_mfma_f32_16x16x32_bf16(al[fi], bh, yv[fi], 0,0,0);
    }
  }
  __syncthreads();

  {
    float* Yf = (float*)&LDSU[OG_HI];
    int p = wc*16 + lr;
#pragma unroll
    for (int fi=0; fi<2; fi++)
#pragma unroll
      for (int e=0; e<4; e++){
        int t = wr*32 + fi*16 + lk*4 + e;
        Yf[t*64 + p] = __expf(La[t])*yi[fi][e] + yv[fi][e];
      }
  }
  __syncthreads();

  {
    const float* Yf = (const float*)&LDSU[OG_HI];
    for (int it = tid; it < 64*16; it += 512){
      int t = it >> 4, p4 = (it & 15) << 2;
      size_t row = (size_t)(b*L_ + c*Q + t);
      float4 x4 = *(const float4*)&xbc[row*CONVD + hh*HD + p4];
      float4 z4 = *(const float4*)&zx[row*DPROJ + hh*HD + p4];
      float xx[4] = {x4.x,x4.y,x4.z,x4.w};
      float zz[4] = {z4.x,z4.y,z4.z,z4.w};
      ushort h4[4];
#pragma unroll
      for (int j=0;j<4;j++){
        float y = Yf[t*64 + p4 + j] + Dh*xx[j];
        float o = y * (zz[j] * sigmoidf_(zz[j]));
        h4[j] = f16rn(o);
      }
      size_t o0 = row*(size_t)DI + hh*HD + p4;
      *(uint2*)&yS[o0] = make_uint2((uint)h4[0]|((uint)h4[1]<<16), (uint)h4[2]|((uint)h4[3]<<16));
    }
  }
}

extern "C" void kernel_launch(void* const* d_in, const int* in_sizes, int n_in,
                              void* d_out, int out_size, void* d_ws, size_t ws_size,
                              hipStream_t stream) {
  const float* u       = (const float*)d_in[0];
  const float* W_in    = (const float*)d_in[1];
  const float* conv_w  = (const float*)d_in[2];
  const float* conv_b  = (const float*)d_in[3];
  const float* dt_bias = (const float*)d_in[4];
  const float* A_log   = (const float*)d_in[5];
  const float* D_param = (const float*)d_in[6];
  const float* W_out   = (const float*)d_in[7];
  float* out = (float*)d_out;

  float* ws = (float*)d_ws;
  float* zx     = ws;                                        // 1024*3352
  float* xbc    = zx   + (size_t)ML*DPROJ;                   // 1024*1792
  float* dts    = xbc  + (size_t)ML*CONVD;                   // 24576
  float* las    = dts  + (size_t)B_*NH*L_;                   // 24576
  float* Schunk = las  + (size_t)B_*NH*L_;                   // 48*8*8192
  ushort* uS    = (ushort*)(Schunk + (size_t)B_*NH*NC*HD*DS);
  ushort* yS    = uS;                                        // aliased (uS dead after gemm1); fp16 plane ML*DI
  ushort* WinS  = uS + (size_t)ML*2*DI;                      // slack covers both aliases
  ushort* WoutS = WinS + (size_t)NPAD1*2*DM;                 // fp16 single plane DM*DI

  // 1) one-shot: split-convert u, W_in (bf16); W_out (fp16); zero d_out
  {
    int outN4 = out_size/4;
    int total = ML*(DM/4) + NPAD1*(DM/4) + DM*(DI/4) + outN4;
    cvt_all<<<(total+255)/256, 256, 0, stream>>>(u, W_in, W_out, uS, WinS, WoutS, out, outN4);
  }
  // 2) in-projection GEMM (fused split-planes, bf16)
  {
    dim3 grid(ML/64, NPAD1/64, 1);
    gemm4<64,64,DM,1,false><<<grid, 256, 0, stream>>>(uS, WinS, zx, DPROJ, DPROJ);
  }
  // 3) conv + SiLU (rolling window, 32-t blocks)
  {
    dim3 grid(7, L_/32, B_);
    conv2_kernel<<<grid, 256, 0, stream>>>(zx, conv_w, conv_b, xbc);
  }
  // 4) chunk states (MFMA; wave0 computes dt + cumsum)
  {
    dim3 grid(NC, NH, B_);
    chunk_state_mfma<<<grid, 256, 0, stream>>>(zx, xbc, dt_bias, A_log, dts, las, Schunk);
  }
  // 5) inter-chunk scan
  interchunk_kernel<<<B_*NH*8, 256, 0, stream>>>(Schunk, las);
  // 6) chunk outputs (MFMA) -> yS fp16 plane
  {
    dim3 grid(NC, NH, B_);
    chunk_out_mfma<<<grid, 512, 0, stream>>>(zx, xbc, dts, las, Schunk, D_param, yS);
  }
  // 7) out-projection GEMM (fp16 single-plane, split-K=4, atomic)
  {
    dim3 grid(ML/64, DM/64, 4);
    gemm_f16<64,64,DI,4,true><<<grid, 256, 0, stream>>>(yS, WoutS, out, DM, DM);
  }
}